// Round 1
// baseline (416.201 us; speedup 1.0000x reference)
//
#include <hip/hip_runtime.h>
#include <math.h>

#define NN 12288      // nodes
#define FD 128        // input feat dim
#define DD 128        // D
#define EE 393216     // edges
#define BB 64         // batch
#define LL 256        // tokens per sample
#define HH 8          // heads
#define DTD 256       // DT = 2*D
#define NTOK 16384    // B*L
#define NSEQ 16448    // B*257

__device__ __forceinline__ float relu_(float x){ return fmaxf(x, 0.0f); }

// ---------------- feats = x @ proj_w + proj_b (8 rows/block, 128 thr) -------
__global__ void k_proj(const float* __restrict__ x, const float* __restrict__ w,
                       const float* __restrict__ b, float* __restrict__ feats){
  __shared__ float sx[8][FD];
  int t = threadIdx.x;
  int r0 = blockIdx.x * 8;
  #pragma unroll
  for(int rr=0; rr<8; ++rr) sx[rr][t] = x[(size_t)(r0+rr)*FD + t];
  __syncthreads();
  float acc[8];
  float bias = b[t];
  #pragma unroll
  for(int rr=0;rr<8;++rr) acc[rr]=bias;
  for(int k=0;k<FD;++k){
    float wv = w[k*DD + t];
    #pragma unroll
    for(int rr=0;rr<8;++rr) acc[rr] += sx[rr][k]*wv;
  }
  #pragma unroll
  for(int rr=0;rr<8;++rr) feats[(size_t)(r0+rr)*DD + t] = acc[rr];
}

// ---------------- CSR build -------------------------------------------------
__global__ void k_hist(const int* __restrict__ rows, int* __restrict__ cnt){
  int e = blockIdx.x*256 + threadIdx.x;
  atomicAdd(&cnt[rows[e]], 1);
}

__global__ void k_scan(const int* __restrict__ cnt, int* __restrict__ rowptr,
                       int* __restrict__ cursor){
  __shared__ int sums[256];
  int t = threadIdx.x;
  const int CH = NN/256;  // 48
  int loc[CH];
  int run = 0;
  int base = t*CH;
  #pragma unroll
  for(int i=0;i<CH;++i){ loc[i]=run; run += cnt[base+i]; }
  sums[t]=run;
  __syncthreads();
  for(int off=1; off<256; off<<=1){
    int v = (t>=off)? sums[t-off] : 0;
    __syncthreads();
    sums[t] += v;
    __syncthreads();
  }
  int pref = (t>0)? sums[t-1] : 0;
  #pragma unroll
  for(int i=0;i<CH;++i){
    rowptr[base+i] = pref + loc[i];
    cursor[base+i] = pref + loc[i];
  }
  if(t==255) rowptr[NN] = sums[255];
}

__global__ void k_scatter(const int* __restrict__ rows, const int* __restrict__ cols,
                          const float* __restrict__ vals, int* __restrict__ cursor,
                          int* __restrict__ ccol, float* __restrict__ cval){
  int e = blockIdx.x*256 + threadIdx.x;
  int r = rows[e];
  int p = atomicAdd(&cursor[r], 1);
  ccol[p] = cols[e];
  cval[p] = vals[e];
}

// ---------------- pull SpMM: hout[i] = sum val * hin[col]; optional re_x ----
__global__ void k_spmm(const float* __restrict__ hin, float* __restrict__ hout,
                       const int* __restrict__ rowptr, const int* __restrict__ ccol,
                       const float* __restrict__ cval, const float* __restrict__ feats,
                       int finalpass){
  int i = blockIdx.x, t = threadIdx.x;
  int p0 = rowptr[i], p1 = rowptr[i+1];
  float acc = 0.f;
  for(int p=p0; p<p1; ++p){
    int c = ccol[p];
    float v = cval[p];
    acc += v * hin[(size_t)c*DD + t];
  }
  if(finalpass) acc = 0.5f*acc + 0.5f*feats[(size_t)i*DD + t];
  hout[(size_t)i*DD + t] = acc;
}

// ---------------- fold constant channels 0,1 + struct_b1 into sbias --------
__global__ void k_sbias(const float* __restrict__ enc_b1, const float* __restrict__ enc_b2,
                        const float* __restrict__ enc_w2, const float* __restrict__ sw1,
                        const float* __restrict__ sb1, float* __restrict__ sbias){
  __shared__ float h0[DD], h1[DD], e0[DD], e1[DD];
  int t = threadIdx.x;
  h0[t] = relu_(enc_b1[0*DD+t]);
  h1[t] = relu_(enc_b1[1*DD+t]);
  __syncthreads();
  float a0 = enc_b2[0*DD+t], a1 = enc_b2[1*DD+t];
  for(int d=0; d<DD; ++d){
    a0 += h0[d]*enc_w2[(0*DD+d)*DD + t];
    a1 += h1[d]*enc_w2[(1*DD+d)*DD + t];
  }
  e0[t]=a0; e1[t]=a1;
  __syncthreads();
  float sv = sb1[t];
  for(int d=0; d<DD; ++d){
    sv += e0[d]*sw1[d*DD + t] + e1[d]*sw1[(DD+d)*DD + t];
  }
  sbias[t]=sv;
}

// ---------------- fused per-token encoder+struct MLP + re_x gather ----------
// 8 tokens per block, 128 threads.
__global__ void k_tok(const int* __restrict__ sample_idx, const int* __restrict__ node_idx,
                      const int* __restrict__ srcI, const int* __restrict__ dstI,
                      const float* __restrict__ ppr, const float* __restrict__ drnl,
                      const float* __restrict__ enc_w1, const float* __restrict__ enc_b1,
                      const float* __restrict__ enc_w2, const float* __restrict__ enc_b2,
                      const float* __restrict__ sw1, const float* __restrict__ sbias,
                      const float* __restrict__ sw2, const float* __restrict__ sb2,
                      const float* __restrict__ re_x, float* __restrict__ tok){
  __shared__ float h2s[8][DD], h3s[8][DD], e2s[8][DD], e3s[8][DD];
  __shared__ float sA[8], sB[8], sDV[8];
  __shared__ int sNode[8];
  int t = threadIdx.x;
  int t0 = blockIdx.x*8;
  if(t<8){
    int tt = t0 + t;
    int s = sample_idx[tt];
    int node = node_idx[tt];
    sNode[t] = node;
    sA[t]  = ppr[(size_t)srcI[s]*NN + node];
    sB[t]  = ppr[(size_t)dstI[s]*NN + node];
    sDV[t] = drnl[(size_t)s*NN + node];
  }
  __syncthreads();
  { // hidden layers of enc channels 2,3
    float w20 = enc_w1[(2*2+0)*DD + t], w21 = enc_w1[(2*2+1)*DD + t];
    float w3s = enc_w1[(3*2+0)*DD + t] + enc_w1[(3*2+1)*DD + t];
    float b2c = enc_b1[2*DD + t], b3c = enc_b1[3*DD + t];
    #pragma unroll
    for(int r=0;r<8;++r){
      h2s[r][t] = relu_(sA[r]*w20 + sB[r]*w21 + b2c);
      h3s[r][t] = relu_(sDV[r]*w3s + b3c);
    }
  }
  __syncthreads();
  { // enc2 = h2 @ W2[2] + b2[2] ; enc3 likewise
    float a2[8], a3[8];
    float b2v = enc_b2[2*DD + t], b3v = enc_b2[3*DD + t];
    #pragma unroll
    for(int r=0;r<8;++r){ a2[r]=b2v; a3[r]=b3v; }
    for(int d=0; d<DD; ++d){
      float w2 = enc_w2[(2*DD+d)*DD + t];
      float w3 = enc_w2[(3*DD+d)*DD + t];
      #pragma unroll
      for(int r=0;r<8;++r){ a2[r] += h2s[r][d]*w2; a3[r] += h3s[r][d]*w3; }
    }
    #pragma unroll
    for(int r=0;r<8;++r){ e2s[r][t]=a2[r]; e3s[r][t]=a3[r]; }
  }
  __syncthreads();
  { // struct hidden: sbias (folded ch0,1+b1) + enc2@SW1[256:384] + enc3@SW1[384:512]
    float sp[8];
    float sbv = sbias[t];
    #pragma unroll
    for(int r=0;r<8;++r) sp[r]=sbv;
    for(int d=0; d<DD; ++d){
      float wa = sw1[(2*DD+d)*DD + t];
      float wb = sw1[(3*DD+d)*DD + t];
      #pragma unroll
      for(int r=0;r<8;++r) sp[r] += e2s[r][d]*wa + e3s[r][d]*wb;
    }
    #pragma unroll
    for(int r=0;r<8;++r) h2s[r][t] = relu_(sp[r]);  // reuse h2s for relu'd hidden
  }
  __syncthreads();
  { // struct out = hidden @ SW2 + sb2 ; write tok[:,0:128]; gather re_x into tok[:,128:256]
    float o[8];
    float bo = sb2[t];
    #pragma unroll
    for(int r=0;r<8;++r) o[r]=bo;
    for(int d=0; d<DD; ++d){
      float w = sw2[d*DD + t];
      #pragma unroll
      for(int r=0;r<8;++r) o[r] += h2s[r][d]*w;
    }
    #pragma unroll
    for(int r=0;r<8;++r){
      int tt = t0 + r;
      tok[(size_t)tt*DTD + t]      = o[r];
      tok[(size_t)tt*DTD + DD + t] = re_x[(size_t)sNode[r]*DD + t];
    }
  }
}

// ---------------- k,v for all 16448 seq rows (8 rows/block, 256 thr) --------
__global__ void k_kv(const float* __restrict__ tok, const float* __restrict__ cls_tok,
                     const float* __restrict__ wk, const float* __restrict__ wv,
                     float* __restrict__ kbuf, float* __restrict__ vbuf){
  __shared__ float sseq[8][DTD];
  int t = threadIdx.x;
  int r0 = blockIdx.x*8;
  #pragma unroll
  for(int rr=0; rr<8; ++rr){
    int r = r0+rr;
    int b = r/257, p = r - b*257;
    const float* srow = (p==0) ? cls_tok : (tok + (size_t)(b*LL + p - 1)*DTD);
    sseq[rr][t] = srow[t];
  }
  __syncthreads();
  float ak[8], av[8];
  #pragma unroll
  for(int rr=0;rr<8;++rr){ ak[rr]=0.f; av[rr]=0.f; }
  for(int d=0; d<DTD; ++d){
    float wkv = wk[d*DTD + t];
    float wvv = wv[d*DTD + t];
    #pragma unroll
    for(int rr=0;rr<8;++rr){ ak[rr]+=sseq[rr][d]*wkv; av[rr]+=sseq[rr][d]*wvv; }
  }
  #pragma unroll
  for(int rr=0;rr<8;++rr){
    int r = r0+rr;
    kbuf[(size_t)r*DTD + t] = ak[rr];
    vbuf[(size_t)r*DTD + t] = av[rr];
  }
}

// ---------------- q for seq rows 0,1,2 of each batch (192 rows) -------------
__global__ void k_q(const float* __restrict__ tok, const float* __restrict__ cls_tok,
                    const float* __restrict__ wq, float* __restrict__ qbuf){
  __shared__ float srow[DTD];
  int t = threadIdx.x;
  int r = blockIdx.x;           // 0..191
  int b = r/3, p = r - b*3;
  const float* s = (p==0)? cls_tok : (tok + (size_t)(b*LL + p - 1)*DTD);
  srow[t] = s[t];
  __syncthreads();
  float acc=0.f;
  for(int d=0; d<DTD; ++d) acc += srow[d]*wq[d*DTD + t];
  qbuf[(size_t)r*DTD + t] = acc;
}

// ---------------- attention: 3 query rows x 257 keys per (b,h) --------------
__device__ __forceinline__ float blk_rmax(float x, float* red){
  int lane = threadIdx.x & 63, wid = threadIdx.x >> 6;
  #pragma unroll
  for(int off=32; off>0; off>>=1) x = fmaxf(x, __shfl_xor(x, off));
  if(lane==0) red[wid]=x;
  __syncthreads();
  float r = fmaxf(fmaxf(red[0],red[1]), fmaxf(red[2],red[3]));
  __syncthreads();
  return r;
}
__device__ __forceinline__ float blk_rsum(float x, float* red){
  int lane = threadIdx.x & 63, wid = threadIdx.x >> 6;
  #pragma unroll
  for(int off=32; off>0; off>>=1) x += __shfl_xor(x, off);
  if(lane==0) red[wid]=x;
  __syncthreads();
  float r = red[0]+red[1]+red[2]+red[3];
  __syncthreads();
  return r;
}

__global__ void k_att(const float* __restrict__ qbuf, const float* __restrict__ kbuf,
                      const float* __restrict__ vbuf, float* __restrict__ att_o){
  __shared__ float sc[3][257];
  __shared__ float q_s[3][32];
  __shared__ float red[4];
  int t = threadIdx.x;
  int b = blockIdx.x / HH, h = blockIdx.x % HH;
  if(t < 96){
    int qi = t>>5, dd = t&31;
    q_s[qi][dd] = qbuf[(size_t)(b*3+qi)*DTD + h*32 + dd];
  }
  __syncthreads();
  const float scale = 0.17677669529663687f;  // 1/sqrt(32)
  for(int kk=t; kk<257; kk+=256){
    const float* kr = kbuf + (size_t)(b*257+kk)*DTD + h*32;
    float d0=0.f,d1=0.f,d2=0.f;
    for(int dd=0; dd<32; ++dd){
      float kvv = kr[dd];
      d0 += q_s[0][dd]*kvv; d1 += q_s[1][dd]*kvv; d2 += q_s[2][dd]*kvv;
    }
    sc[0][kk]=d0*scale; sc[1][kk]=d1*scale; sc[2][kk]=d2*scale;
  }
  __syncthreads();
  for(int qi=0; qi<3; ++qi){
    float x = sc[qi][t];
    if(t==0) x = fmaxf(x, sc[qi][256]);
    float m = blk_rmax(x, red);
    float e = expf(sc[qi][t]-m);
    float e2 = 0.f;
    if(t==0) e2 = expf(sc[qi][256]-m);
    float s = blk_rsum(e+e2, red);
    float inv = 1.0f/s;
    sc[qi][t] = e*inv;
    if(t==0) sc[qi][256] = e2*inv;
    __syncthreads();
  }
  if(t<96){
    int qi=t>>5, dd=t&31;
    float acc=0.f;
    for(int kk=0;kk<257;++kk)
      acc += sc[qi][kk]*vbuf[(size_t)(b*257+kk)*DTD + h*32 + dd];
    att_o[(size_t)(b*3+qi)*DTD + h*32 + dd] = acc;
  }
}

// ---------------- output: att_o @ wo, permuted into d_out -------------------
__global__ void k_out(const float* __restrict__ att_o, const float* __restrict__ wo,
                      float* __restrict__ out){
  __shared__ float srow[DTD];
  int t = threadIdx.x;
  int r = blockIdx.x;  // 0..191
  int b = r/3, qi = r - b*3;
  srow[t] = att_o[(size_t)r*DTD + t];
  __syncthreads();
  float acc = 0.f;
  for(int d=0; d<DTD; ++d) acc += srow[d]*wo[d*DTD + t];
  int off = (qi==1)? 0 : ((qi==2)? DTD : 2*DTD);  // [h_a, h_b, h_cls]
  out[(size_t)b*768 + off + t] = acc;
}

extern "C" void kernel_launch(void* const* d_in, const int* in_sizes, int n_in,
                              void* d_out, int out_size, void* d_ws, size_t ws_size,
                              hipStream_t stream){
  const float* x        = (const float*)d_in[0];
  const float* proj_w   = (const float*)d_in[1];
  const float* proj_b   = (const float*)d_in[2];
  const float* adj_vals = (const float*)d_in[3];
  const int*   adj_rows = (const int*)d_in[4];
  const int*   adj_cols = (const int*)d_in[5];
  const float* ppr      = (const float*)d_in[6];
  const float* drnl     = (const float*)d_in[7];
  const int*   srcI     = (const int*)d_in[8];
  const int*   dstI     = (const int*)d_in[9];
  const int*   sample_idx = (const int*)d_in[10];
  const int*   node_idx   = (const int*)d_in[11];
  const float* enc_w1   = (const float*)d_in[12];
  const float* enc_b1   = (const float*)d_in[13];
  const float* enc_w2   = (const float*)d_in[14];
  const float* enc_b2   = (const float*)d_in[15];
  const float* sw1      = (const float*)d_in[16];
  const float* sb1      = (const float*)d_in[17];
  const float* sw2      = (const float*)d_in[18];
  const float* sb2      = (const float*)d_in[19];
  const float* cls_tok  = (const float*)d_in[20];
  const float* wq       = (const float*)d_in[21];
  const float* wk       = (const float*)d_in[22];
  const float* wv       = (const float*)d_in[23];
  const float* wo       = (const float*)d_in[24];
  float* out = (float*)d_out;

  // workspace layout (all f32/int32; ~73 MB total)
  float* feats  = (float*)d_ws;
  float* hA     = feats + (size_t)NN*DD;
  float* hB     = hA    + (size_t)NN*DD;
  int*   cnt    = (int*)(hB + (size_t)NN*DD);
  int*   rowptr = cnt + NN;
  int*   cursor = rowptr + (NN+1);
  int*   csr_col= cursor + NN;
  float* csr_val= (float*)(csr_col + EE);
  float* sbias  = csr_val + EE;
  float* tok    = sbias + DD;
  float* qbuf   = tok  + (size_t)NTOK*DTD;
  float* kbuf   = qbuf + (size_t)BB*3*DTD;
  float* vbuf   = kbuf + (size_t)NSEQ*DTD;
  float* att_o  = vbuf + (size_t)NSEQ*DTD;

  hipMemsetAsync(cnt, 0, NN*sizeof(int), stream);

  k_proj   <<<NN/8,    128, 0, stream>>>(x, proj_w, proj_b, feats);
  k_hist   <<<EE/256,  256, 0, stream>>>(adj_rows, cnt);
  k_scan   <<<1,       256, 0, stream>>>(cnt, rowptr, cursor);
  k_scatter<<<EE/256,  256, 0, stream>>>(adj_rows, adj_cols, adj_vals, cursor, csr_col, csr_val);
  k_spmm   <<<NN,      128, 0, stream>>>(feats, hA, rowptr, csr_col, csr_val, feats, 0);
  k_spmm   <<<NN,      128, 0, stream>>>(hA,    hB, rowptr, csr_col, csr_val, feats, 0);
  k_spmm   <<<NN,      128, 0, stream>>>(hB,    hA, rowptr, csr_col, csr_val, feats, 1); // hA = re_x
  k_sbias  <<<1,       128, 0, stream>>>(enc_b1, enc_b2, enc_w2, sw1, sb1, sbias);
  k_tok    <<<NTOK/8,  128, 0, stream>>>(sample_idx, node_idx, srcI, dstI, ppr, drnl,
                                         enc_w1, enc_b1, enc_w2, enc_b2,
                                         sw1, sbias, sw2, sb2, hA, tok);
  k_kv     <<<NSEQ/8,  256, 0, stream>>>(tok, cls_tok, wk, wv, kbuf, vbuf);
  k_q      <<<BB*3,    256, 0, stream>>>(tok, cls_tok, wq, qbuf);
  k_att    <<<BB*HH,   256, 0, stream>>>(qbuf, kbuf, vbuf, att_o);
  k_out    <<<BB*3,    256, 0, stream>>>(att_o, wo, out);
}

// Round 2
// 311.265 us; speedup vs baseline: 1.3371x; 1.3371x over previous
//
#include <hip/hip_runtime.h>
#include <math.h>

#define NN 12288      // nodes
#define FD 128        // input feat dim
#define DD 128        // D
#define EE 393216     // edges
#define BB 64         // batch
#define LL 256        // tokens per sample
#define HH 8          // heads
#define DTD 256       // DT = 2*D
#define NTOK 16384    // B*L
#define NSEQ 16448    // B*257

typedef float f32x4 __attribute__((ext_vector_type(4)));
typedef short s16x8 __attribute__((ext_vector_type(8)));

__device__ __forceinline__ float relu_(float x){ return fmaxf(x, 0.0f); }

__device__ __forceinline__ unsigned short f2b(float f){
  unsigned int u = __float_as_uint(f);
  u += 0x7FFFu + ((u >> 16) & 1u);
  return (unsigned short)(u >> 16);
}
__device__ __forceinline__ float b2f(unsigned short h){
  return __uint_as_float(((unsigned int)h) << 16);
}

__device__ __forceinline__ f32x4 MF(s16x8 a, s16x8 b, f32x4 c){
  return __builtin_amdgcn_mfma_f32_16x16x32_bf16(a, b, c, 0, 0, 0);
}

// ---------------- feats = x @ proj_w + proj_b (8 rows/block, 128 thr) -------
__global__ void k_proj(const float* __restrict__ x, const float* __restrict__ w,
                       const float* __restrict__ b, float* __restrict__ feats){
  __shared__ float sx[8][FD];
  int t = threadIdx.x;
  int r0 = blockIdx.x * 8;
  #pragma unroll
  for(int rr=0; rr<8; ++rr) sx[rr][t] = x[(size_t)(r0+rr)*FD + t];
  __syncthreads();
  float acc[8];
  float bias = b[t];
  #pragma unroll
  for(int rr=0;rr<8;++rr) acc[rr]=bias;
  for(int k=0;k<FD;++k){
    float wv = w[k*DD + t];
    #pragma unroll
    for(int rr=0;rr<8;++rr) acc[rr] += sx[rr][k]*wv;
  }
  #pragma unroll
  for(int rr=0;rr<8;++rr) feats[(size_t)(r0+rr)*DD + t] = acc[rr];
}

// ---------------- CSR build -------------------------------------------------
__global__ void k_hist(const int* __restrict__ rows, int* __restrict__ cnt){
  int e = blockIdx.x*256 + threadIdx.x;
  atomicAdd(&cnt[rows[e]], 1);
}

__global__ void k_scan(const int* __restrict__ cnt, int* __restrict__ rowptr,
                       int* __restrict__ cursor){
  __shared__ int sums[256];
  int t = threadIdx.x;
  const int CH = NN/256;  // 48
  int loc[CH];
  int run = 0;
  int base = t*CH;
  #pragma unroll
  for(int i=0;i<CH;++i){ loc[i]=run; run += cnt[base+i]; }
  sums[t]=run;
  __syncthreads();
  for(int off=1; off<256; off<<=1){
    int v = (t>=off)? sums[t-off] : 0;
    __syncthreads();
    sums[t] += v;
    __syncthreads();
  }
  int pref = (t>0)? sums[t-1] : 0;
  #pragma unroll
  for(int i=0;i<CH;++i){
    rowptr[base+i] = pref + loc[i];
    cursor[base+i] = pref + loc[i];
  }
  if(t==255) rowptr[NN] = sums[255];
}

__global__ void k_scatter(const int* __restrict__ rows, const int* __restrict__ cols,
                          const float* __restrict__ vals, int* __restrict__ cursor,
                          int* __restrict__ ccol, float* __restrict__ cval){
  int e = blockIdx.x*256 + threadIdx.x;
  int r = rows[e];
  int p = atomicAdd(&cursor[r], 1);
  ccol[p] = cols[e];
  cval[p] = vals[e];
}

// ---------------- pull SpMM: hout[i] = sum val * hin[col]; optional re_x ----
__global__ void k_spmm(const float* __restrict__ hin, float* __restrict__ hout,
                       const int* __restrict__ rowptr, const int* __restrict__ ccol,
                       const float* __restrict__ cval, const float* __restrict__ feats,
                       int finalpass){
  int i = blockIdx.x, t = threadIdx.x;
  int p0 = rowptr[i], p1 = rowptr[i+1];
  float acc = 0.f;
  for(int p=p0; p<p1; ++p){
    int c = ccol[p];
    float v = cval[p];
    acc += v * hin[(size_t)c*DD + t];
  }
  if(finalpass) acc = 0.5f*acc + 0.5f*feats[(size_t)i*DD + t];
  hout[(size_t)i*DD + t] = acc;
}

// ---------------- fold constant channels 0,1 + struct_b1 into sbias --------
__global__ void k_sbias(const float* __restrict__ enc_b1, const float* __restrict__ enc_b2,
                        const float* __restrict__ enc_w2, const float* __restrict__ sw1,
                        const float* __restrict__ sb1, float* __restrict__ sbias){
  __shared__ float h0[DD], h1[DD], e0[DD], e1[DD];
  int t = threadIdx.x;
  h0[t] = relu_(enc_b1[0*DD+t]);
  h1[t] = relu_(enc_b1[1*DD+t]);
  __syncthreads();
  float a0 = enc_b2[0*DD+t], a1 = enc_b2[1*DD+t];
  for(int d=0; d<DD; ++d){
    a0 += h0[d]*enc_w2[(0*DD+d)*DD + t];
    a1 += h1[d]*enc_w2[(1*DD+d)*DD + t];
  }
  e0[t]=a0; e1[t]=a1;
  __syncthreads();
  float sv = sb1[t];
  for(int d=0; d<DD; ++d){
    sv += e0[d]*sw1[d*DD + t] + e1[d]*sw1[(DD+d)*DD + t];
  }
  sbias[t]=sv;
}

// ---------------- prep: transpose+convert weights to bf16 [out][k]; cls ----
__global__ void k_prep(const float* __restrict__ wk, const float* __restrict__ wv,
                       const float* __restrict__ enc_w2, const float* __restrict__ sw1,
                       const float* __restrict__ sw2, const float* __restrict__ cls_tok,
                       unsigned short* __restrict__ wkT, unsigned short* __restrict__ wvT,
                       unsigned short* __restrict__ w2T2, unsigned short* __restrict__ w2T3,
                       unsigned short* __restrict__ sw1aT, unsigned short* __restrict__ sw1bT,
                       unsigned short* __restrict__ sw2T, unsigned short* __restrict__ seqb){
  int id = blockIdx.x*256 + threadIdx.x;
  if(id < 131072){
    int m = id >> 16, e = id & 65535;
    int n = e & 255, k = e >> 8;          // read coalesced src[k*256+n]
    const float* s = m ? wv : wk;
    unsigned short* d = m ? wvT : wkT;
    d[n*256 + k] = f2b(s[k*256 + n]);
  } else if(id < 212992){
    int id2 = id - 131072;
    int m = id2 >> 14, e = id2 & 16383;
    int n = e & 127, k = e >> 7;
    const float* s;
    unsigned short* d;
    if(m==0){ s = enc_w2 + 2*16384; d = w2T2; }
    else if(m==1){ s = enc_w2 + 3*16384; d = w2T3; }
    else if(m==2){ s = sw1 + 256*128; d = sw1aT; }
    else if(m==3){ s = sw1 + 384*128; d = sw1bT; }
    else { s = sw2; d = sw2T; }
    d[n*128 + k] = f2b(s[k*128 + n]);
  } else {
    int id3 = id - 212992;                 // 64*256 cls rows
    int b = id3 >> 8, t = id3 & 255;
    seqb[(size_t)(b*257)*DTD + t] = f2b(cls_tok[t]);
  }
}

// ---------------- fused token MLP via MFMA: 64 tokens/block, 256 thr --------
__global__ void __launch_bounds__(256)
k_tok_mfma(const int* __restrict__ node_idx,
           const int* __restrict__ srcI, const int* __restrict__ dstI,
           const float* __restrict__ ppr, const float* __restrict__ drnl,
           const float* __restrict__ enc_w1, const float* __restrict__ enc_b1,
           const unsigned short* __restrict__ w2T2, const unsigned short* __restrict__ w2T3,
           const float* __restrict__ enc_b2,
           const unsigned short* __restrict__ sw1aT, const unsigned short* __restrict__ sw1bT,
           const float* __restrict__ sbias,
           const unsigned short* __restrict__ sw2T, const float* __restrict__ sb2,
           const float* __restrict__ re_x, unsigned short* __restrict__ seqb){
  __shared__ float sA[64], sB[64], sDV[64];
  __shared__ int sNode[64];
  __shared__ __align__(16) unsigned short e2[64][136];
  __shared__ __align__(16) unsigned short e3[64][136];
  __shared__ __align__(16) unsigned short hid[64][136];

  int tid = threadIdx.x;
  int lane = tid & 63;
  int w = tid >> 6;               // wave 0..3 -> col group of 32
  int lr = lane & 15;
  int lg = lane >> 4;             // 0..3
  int t0 = blockIdx.x * 64;       // 64 tokens, all within one batch sample
  int bs = t0 >> 8;               // batch
  int p0 = t0 & 255;
  int seqrow0 = bs*257 + 1 + p0;

  if(tid < 64){
    int tt = t0 + tid;
    int node = node_idx[tt];
    sNode[tid] = node;
    sA[tid]  = ppr[(size_t)srcI[bs]*NN + node];
    sB[tid]  = ppr[(size_t)dstI[bs]*NN + node];
    sDV[tid] = drnl[(size_t)bs*NN + node];
  }
  __syncthreads();

  // ---- GEMM1: enc2 = relu(h2)@W2[2]+b2 ; enc3 likewise (M=64,K=128,N=128) --
  {
    f32x4 acc2[4][2], acc3[4][2];
    #pragma unroll
    for(int nt=0;nt<2;++nt){
      int col = w*32 + nt*16 + lr;
      float b2v = enc_b2[2*DD + col];
      float b3v = enc_b2[3*DD + col];
      #pragma unroll
      for(int rt=0;rt<4;++rt){
        #pragma unroll
        for(int i=0;i<4;++i){ acc2[rt][nt][i]=b2v; acc3[rt][nt][i]=b3v; }
      }
    }
    #pragma unroll
    for(int ks=0; ks<4; ++ks){
      int kb = ks*32 + lg*8;
      float w20[8], w21[8], w3s[8], b2c[8], b3c[8];
      #pragma unroll
      for(int i=0;i<8;++i){
        int k = kb + i;
        w20[i] = enc_w1[4*DD + k];
        w21[i] = enc_w1[5*DD + k];
        w3s[i] = enc_w1[6*DD + k] + enc_w1[7*DD + k];
        b2c[i] = enc_b1[2*DD + k];
        b3c[i] = enc_b1[3*DD + k];
      }
      s16x8 B2[2], B3[2];
      #pragma unroll
      for(int nt=0;nt<2;++nt){
        int col = w*32 + nt*16 + lr;
        B2[nt] = *(const s16x8*)(w2T2 + col*DD + kb);
        B3[nt] = *(const s16x8*)(w2T3 + col*DD + kb);
      }
      #pragma unroll
      for(int rt=0;rt<4;++rt){
        int row = rt*16 + lr;
        float a = sA[row], b = sB[row], dv = sDV[row];
        s16x8 A2, A3;
        #pragma unroll
        for(int i=0;i<8;++i){
          A2[i] = (short)f2b(relu_(a*w20[i] + b*w21[i] + b2c[i]));
          A3[i] = (short)f2b(relu_(dv*w3s[i] + b3c[i]));
        }
        #pragma unroll
        for(int nt=0;nt<2;++nt){
          acc2[rt][nt] = MF(A2, B2[nt], acc2[rt][nt]);
          acc3[rt][nt] = MF(A3, B3[nt], acc3[rt][nt]);
        }
      }
    }
    #pragma unroll
    for(int rt=0;rt<4;++rt)
      #pragma unroll
      for(int nt=0;nt<2;++nt)
        #pragma unroll
        for(int i=0;i<4;++i){
          int row = rt*16 + lg*4 + i;
          int col = w*32 + nt*16 + lr;
          e2[row][col] = f2b(acc2[rt][nt][i]);
          e3[row][col] = f2b(acc3[rt][nt][i]);
        }
  }
  __syncthreads();

  // ---- GEMM2: hidden = relu(sbias + enc2@SW1a + enc3@SW1b) ----------------
  {
    f32x4 acc[4][2];
    #pragma unroll
    for(int nt=0;nt<2;++nt){
      int col = w*32 + nt*16 + lr;
      float sv = sbias[col];
      #pragma unroll
      for(int rt=0;rt<4;++rt)
        #pragma unroll
        for(int i=0;i<4;++i) acc[rt][nt][i]=sv;
    }
    #pragma unroll
    for(int ks=0; ks<4; ++ks){
      int kb = ks*32 + lg*8;
      s16x8 Ba[2], Bb[2];
      #pragma unroll
      for(int nt=0;nt<2;++nt){
        int col = w*32 + nt*16 + lr;
        Ba[nt] = *(const s16x8*)(sw1aT + col*DD + kb);
        Bb[nt] = *(const s16x8*)(sw1bT + col*DD + kb);
      }
      #pragma unroll
      for(int rt=0;rt<4;++rt){
        s16x8 A2 = *(const s16x8*)&e2[rt*16+lr][kb];
        s16x8 A3 = *(const s16x8*)&e3[rt*16+lr][kb];
        #pragma unroll
        for(int nt=0;nt<2;++nt){
          acc[rt][nt] = MF(A2, Ba[nt], acc[rt][nt]);
          acc[rt][nt] = MF(A3, Bb[nt], acc[rt][nt]);
        }
      }
    }
    __syncthreads();   // done reading e2/e3 (hid is a distinct array, but keep order clean)
    #pragma unroll
    for(int rt=0;rt<4;++rt)
      #pragma unroll
      for(int nt=0;nt<2;++nt)
        #pragma unroll
        for(int i=0;i<4;++i){
          int row = rt*16 + lg*4 + i;
          int col = w*32 + nt*16 + lr;
          hid[row][col] = f2b(relu_(acc[rt][nt][i]));
        }
  }
  __syncthreads();

  // ---- GEMM3: struct_out = hidden@SW2 + sb2 -> seqb[:,0:128] --------------
  {
    f32x4 acc[4][2];
    #pragma unroll
    for(int nt=0;nt<2;++nt){
      int col = w*32 + nt*16 + lr;
      float bv = sb2[col];
      #pragma unroll
      for(int rt=0;rt<4;++rt)
        #pragma unroll
        for(int i=0;i<4;++i) acc[rt][nt][i]=bv;
    }
    #pragma unroll
    for(int ks=0; ks<4; ++ks){
      int kb = ks*32 + lg*8;
      s16x8 Bc[2];
      #pragma unroll
      for(int nt=0;nt<2;++nt){
        int col = w*32 + nt*16 + lr;
        Bc[nt] = *(const s16x8*)(sw2T + col*DD + kb);
      }
      #pragma unroll
      for(int rt=0;rt<4;++rt){
        s16x8 A = *(const s16x8*)&hid[rt*16+lr][kb];
        #pragma unroll
        for(int nt=0;nt<2;++nt) acc[rt][nt] = MF(A, Bc[nt], acc[rt][nt]);
      }
    }
    #pragma unroll
    for(int rt=0;rt<4;++rt)
      #pragma unroll
      for(int nt=0;nt<2;++nt)
        #pragma unroll
        for(int i=0;i<4;++i){
          int row = rt*16 + lg*4 + i;
          int col = w*32 + nt*16 + lr;
          seqb[(size_t)(seqrow0 + row)*DTD + col] = f2b(acc[rt][nt][i]);
        }
  }

  // ---- re_x gather -> seqb[:,128:256] (bf16) ------------------------------
  #pragma unroll
  for(int rr=0; rr<2; ++rr){
    int row = rr*32 + (tid >> 3);
    int c0 = (tid & 7) * 16;
    int node = sNode[row];
    const float* rp = re_x + (size_t)node*DD + c0;
    unsigned short* op = seqb + (size_t)(seqrow0 + row)*DTD + DD + c0;
    #pragma unroll
    for(int j=0;j<16;++j) op[j] = f2b(rp[j]);
  }
}

// ---------------- K,V GEMM via MFMA: 64 rows x 256 cols per block ----------
__global__ void __launch_bounds__(256)
k_kv_mfma(const unsigned short* __restrict__ seqb,
          const unsigned short* __restrict__ wkT, const unsigned short* __restrict__ wvT,
          float* __restrict__ kbuf, float* __restrict__ vbuf){
  int tid = threadIdx.x;
  int lane = tid & 63;
  int w = tid >> 6;
  int lr = lane & 15;
  int lg = lane >> 4;
  int row0 = blockIdx.x * 64;     // 257 blocks * 64 = 16448 exactly
  int col0 = w * 64;

  f32x4 accK[4][4], accV[4][4];
  #pragma unroll
  for(int rt=0;rt<4;++rt)
    #pragma unroll
    for(int nt=0;nt<4;++nt)
      #pragma unroll
      for(int i=0;i<4;++i){ accK[rt][nt][i]=0.f; accV[rt][nt][i]=0.f; }

  #pragma unroll
  for(int ks=0; ks<8; ++ks){
    int kb = ks*32 + lg*8;
    s16x8 A[4], Bk[4], Bv[4];
    #pragma unroll
    for(int rt=0;rt<4;++rt)
      A[rt] = *(const s16x8*)(seqb + (size_t)(row0 + rt*16 + lr)*DTD + kb);
    #pragma unroll
    for(int nt=0;nt<4;++nt){
      int col = col0 + nt*16 + lr;
      Bk[nt] = *(const s16x8*)(wkT + (size_t)col*DTD + kb);
      Bv[nt] = *(const s16x8*)(wvT + (size_t)col*DTD + kb);
    }
    #pragma unroll
    for(int rt=0;rt<4;++rt)
      #pragma unroll
      for(int nt=0;nt<4;++nt){
        accK[rt][nt] = MF(A[rt], Bk[nt], accK[rt][nt]);
        accV[rt][nt] = MF(A[rt], Bv[nt], accV[rt][nt]);
      }
  }

  #pragma unroll
  for(int rt=0;rt<4;++rt)
    #pragma unroll
    for(int nt=0;nt<4;++nt)
      #pragma unroll
      for(int i=0;i<4;++i){
        int r = row0 + rt*16 + lg*4 + i;
        int c = col0 + nt*16 + lr;
        kbuf[(size_t)r*DTD + c] = accK[rt][nt][i];
        vbuf[(size_t)r*DTD + c] = accV[rt][nt][i];
      }
}

// ---------------- q for seq rows 0,1,2 of each batch (192 rows) -------------
__global__ void k_q2(const unsigned short* __restrict__ seqb,
                     const float* __restrict__ wq, float* __restrict__ qbuf){
  __shared__ float srow[DTD];
  int t = threadIdx.x;
  int r = blockIdx.x;           // 0..191
  int b = r/3, p = r - b*3;
  srow[t] = b2f(seqb[(size_t)(b*257 + p)*DTD + t]);
  __syncthreads();
  float acc=0.f;
  for(int d=0; d<DTD; ++d) acc += srow[d]*wq[d*DTD + t];
  qbuf[(size_t)r*DTD + t] = acc;
}

// ---------------- attention: 3 query rows x 257 keys per (b,h) --------------
__device__ __forceinline__ float blk_rmax(float x, float* red){
  int lane = threadIdx.x & 63, wid = threadIdx.x >> 6;
  #pragma unroll
  for(int off=32; off>0; off>>=1) x = fmaxf(x, __shfl_xor(x, off));
  if(lane==0) red[wid]=x;
  __syncthreads();
  float r = fmaxf(fmaxf(red[0],red[1]), fmaxf(red[2],red[3]));
  __syncthreads();
  return r;
}
__device__ __forceinline__ float blk_rsum(float x, float* red){
  int lane = threadIdx.x & 63, wid = threadIdx.x >> 6;
  #pragma unroll
  for(int off=32; off>0; off>>=1) x += __shfl_xor(x, off);
  if(lane==0) red[wid]=x;
  __syncthreads();
  float r = red[0]+red[1]+red[2]+red[3];
  __syncthreads();
  return r;
}

__global__ void k_att(const float* __restrict__ qbuf, const float* __restrict__ kbuf,
                      const float* __restrict__ vbuf, float* __restrict__ att_o){
  __shared__ float sc[3][257];
  __shared__ float q_s[3][32];
  __shared__ float red[4];
  int t = threadIdx.x;
  int b = blockIdx.x / HH, h = blockIdx.x % HH;
  if(t < 96){
    int qi = t>>5, dd = t&31;
    q_s[qi][dd] = qbuf[(size_t)(b*3+qi)*DTD + h*32 + dd];
  }
  __syncthreads();
  const float scale = 0.17677669529663687f;  // 1/sqrt(32)
  for(int kk=t; kk<257; kk+=256){
    const float* kr = kbuf + (size_t)(b*257+kk)*DTD + h*32;
    float d0=0.f,d1=0.f,d2=0.f;
    for(int dd=0; dd<32; ++dd){
      float kvv = kr[dd];
      d0 += q_s[0][dd]*kvv; d1 += q_s[1][dd]*kvv; d2 += q_s[2][dd]*kvv;
    }
    sc[0][kk]=d0*scale; sc[1][kk]=d1*scale; sc[2][kk]=d2*scale;
  }
  __syncthreads();
  for(int qi=0; qi<3; ++qi){
    float x = sc[qi][t];
    if(t==0) x = fmaxf(x, sc[qi][256]);
    float m = blk_rmax(x, red);
    float e = expf(sc[qi][t]-m);
    float e2 = 0.f;
    if(t==0) e2 = expf(sc[qi][256]-m);
    float s = blk_rsum(e+e2, red);
    float inv = 1.0f/s;
    sc[qi][t] = e*inv;
    if(t==0) sc[qi][256] = e2*inv;
    __syncthreads();
  }
  if(t<96){
    int qi=t>>5, dd=t&31;
    float acc=0.f;
    for(int kk=0;kk<257;++kk)
      acc += sc[qi][kk]*vbuf[(size_t)(b*257+kk)*DTD + h*32 + dd];
    att_o[(size_t)(b*3+qi)*DTD + h*32 + dd] = acc;
  }
}

// ---------------- output: att_o @ wo, permuted into d_out -------------------
__global__ void k_out(const float* __restrict__ att_o, const float* __restrict__ wo,
                      float* __restrict__ out){
  __shared__ float srow[DTD];
  int t = threadIdx.x;
  int r = blockIdx.x;  // 0..191
  int b = r/3, qi = r - b*3;
  srow[t] = att_o[(size_t)r*DTD + t];
  __syncthreads();
  float acc = 0.f;
  for(int d=0; d<DTD; ++d) acc += srow[d]*wo[d*DTD + t];
  int off = (qi==1)? 0 : ((qi==2)? DTD : 2*DTD);  // [h_a, h_b, h_cls]
  out[(size_t)b*768 + off + t] = acc;
}

extern "C" void kernel_launch(void* const* d_in, const int* in_sizes, int n_in,
                              void* d_out, int out_size, void* d_ws, size_t ws_size,
                              hipStream_t stream){
  const float* x        = (const float*)d_in[0];
  const float* proj_w   = (const float*)d_in[1];
  const float* proj_b   = (const float*)d_in[2];
  const float* adj_vals = (const float*)d_in[3];
  const int*   adj_rows = (const int*)d_in[4];
  const int*   adj_cols = (const int*)d_in[5];
  const float* ppr      = (const float*)d_in[6];
  const float* drnl     = (const float*)d_in[7];
  const int*   srcI     = (const int*)d_in[8];
  const int*   dstI     = (const int*)d_in[9];
  const int*   node_idx   = (const int*)d_in[11];
  const float* enc_w1   = (const float*)d_in[12];
  const float* enc_b1   = (const float*)d_in[13];
  const float* enc_w2   = (const float*)d_in[14];
  const float* enc_b2   = (const float*)d_in[15];
  const float* sw1      = (const float*)d_in[16];
  const float* sb1      = (const float*)d_in[17];
  const float* sw2      = (const float*)d_in[18];
  const float* sb2      = (const float*)d_in[19];
  const float* cls_tok  = (const float*)d_in[20];
  const float* wq       = (const float*)d_in[21];
  const float* wk       = (const float*)d_in[22];
  const float* wv       = (const float*)d_in[23];
  const float* wo       = (const float*)d_in[24];
  float* out = (float*)d_out;

  // workspace carve-up, 64B aligned chunks
  char* p = (char*)d_ws;
  auto alloc = [&](size_t bytes)->void*{ void* r = (void*)p; p += (bytes + 63) & ~(size_t)63; return r; };
  float* feats   = (float*)alloc((size_t)NN*DD*4);
  float* hA      = (float*)alloc((size_t)NN*DD*4);
  float* hB      = (float*)alloc((size_t)NN*DD*4);
  int*   cnt     = (int*)  alloc((size_t)NN*4);
  int*   rowptr  = (int*)  alloc((size_t)(NN+1)*4);
  int*   cursor  = (int*)  alloc((size_t)NN*4);
  int*   csr_col = (int*)  alloc((size_t)EE*4);
  float* csr_val = (float*)alloc((size_t)EE*4);
  float* sbias   = (float*)alloc((size_t)DD*4);
  float* qbuf    = (float*)alloc((size_t)BB*3*DTD*4);
  float* kbuf    = (float*)alloc((size_t)NSEQ*DTD*4);
  float* vbuf    = (float*)alloc((size_t)NSEQ*DTD*4);
  float* att_o   = (float*)alloc((size_t)BB*3*DTD*4);
  unsigned short* seqb  = (unsigned short*)alloc((size_t)NSEQ*DTD*2);
  unsigned short* wkT   = (unsigned short*)alloc((size_t)DTD*DTD*2);
  unsigned short* wvT   = (unsigned short*)alloc((size_t)DTD*DTD*2);
  unsigned short* w2T2  = (unsigned short*)alloc((size_t)DD*DD*2);
  unsigned short* w2T3  = (unsigned short*)alloc((size_t)DD*DD*2);
  unsigned short* sw1aT = (unsigned short*)alloc((size_t)DD*DD*2);
  unsigned short* sw1bT = (unsigned short*)alloc((size_t)DD*DD*2);
  unsigned short* sw2T  = (unsigned short*)alloc((size_t)DD*DD*2);

  hipMemsetAsync(cnt, 0, NN*sizeof(int), stream);

  k_proj   <<<NN/8,    128, 0, stream>>>(x, proj_w, proj_b, feats);
  k_hist   <<<EE/256,  256, 0, stream>>>(adj_rows, cnt);
  k_scan   <<<1,       256, 0, stream>>>(cnt, rowptr, cursor);
  k_scatter<<<EE/256,  256, 0, stream>>>(adj_rows, adj_cols, adj_vals, cursor, csr_col, csr_val);
  k_spmm   <<<NN,      128, 0, stream>>>(feats, hA, rowptr, csr_col, csr_val, feats, 0);
  k_spmm   <<<NN,      128, 0, stream>>>(hA,    hB, rowptr, csr_col, csr_val, feats, 0);
  k_spmm   <<<NN,      128, 0, stream>>>(hB,    hA, rowptr, csr_col, csr_val, feats, 1); // hA = re_x
  k_sbias  <<<1,       128, 0, stream>>>(enc_b1, enc_b2, enc_w2, sw1, sb1, sbias);
  k_prep   <<<896,     256, 0, stream>>>(wk, wv, enc_w2, sw1, sw2, cls_tok,
                                         wkT, wvT, w2T2, w2T3, sw1aT, sw1bT, sw2T, seqb);
  k_tok_mfma<<<NTOK/64,256, 0, stream>>>(node_idx, srcI, dstI, ppr, drnl,
                                         enc_w1, enc_b1, w2T2, w2T3, enc_b2,
                                         sw1aT, sw1bT, sbias, sw2T, sb2, hA, seqb);
  k_kv_mfma<<<NSEQ/64, 256, 0, stream>>>(seqb, wkT, wvT, kbuf, vbuf);
  k_q2     <<<BB*3,    256, 0, stream>>>(seqb, wq, qbuf);
  k_att    <<<BB*HH,   256, 0, stream>>>(qbuf, kbuf, vbuf, att_o);
  k_out    <<<BB*3,    256, 0, stream>>>(att_o, wo, out);
}

// Round 3
// 234.347 us; speedup vs baseline: 1.7760x; 1.3282x over previous
//
#include <hip/hip_runtime.h>
#include <math.h>

#define NN 12288      // nodes
#define FD 128        // input feat dim
#define DD 128        // D
#define EE 393216     // edges
#define BB 64         // batch
#define LL 256        // tokens per sample
#define HH 8          // heads
#define DTD 256       // DT = 2*D
#define NTOK 16384    // B*L
#define NSEQ 16448    // B*257

typedef float f32x4 __attribute__((ext_vector_type(4)));
typedef short s16x8 __attribute__((ext_vector_type(8)));

__device__ __forceinline__ float relu_(float x){ return fmaxf(x, 0.0f); }

__device__ __forceinline__ unsigned short f2b(float f){
  unsigned int u = __float_as_uint(f);
  u += 0x7FFFu + ((u >> 16) & 1u);
  return (unsigned short)(u >> 16);
}
__device__ __forceinline__ float b2f(unsigned short h){
  return __uint_as_float(((unsigned int)h) << 16);
}

__device__ __forceinline__ f32x4 MF(s16x8 a, s16x8 b, f32x4 c){
  return __builtin_amdgcn_mfma_f32_16x16x32_bf16(a, b, c, 0, 0, 0);
}

// ============ kernel A: proj (blocks 0..767) + prep (768..1663) ============
__global__ void __launch_bounds__(256)
k_setup(const float* __restrict__ x, const float* __restrict__ proj_w,
        const float* __restrict__ proj_b, float* __restrict__ feats,
        unsigned short* __restrict__ featsb,
        const float* __restrict__ wk, const float* __restrict__ wv,
        const float* __restrict__ enc_w2, const float* __restrict__ sw1,
        const float* __restrict__ sw2, const float* __restrict__ cls_tok,
        unsigned short* __restrict__ wkT, unsigned short* __restrict__ wvT,
        unsigned short* __restrict__ w2T2, unsigned short* __restrict__ w2T3,
        unsigned short* __restrict__ sw1aT, unsigned short* __restrict__ sw1bT,
        unsigned short* __restrict__ sw2T, unsigned short* __restrict__ seqb){
  int t = threadIdx.x;
  if(blockIdx.x < 768){
    __shared__ float sx[16][FD];
    int r0 = blockIdx.x * 16;
    #pragma unroll
    for(int i=0;i<8;++i){
      int idx = t + i*256;
      sx[idx>>7][idx&127] = x[(size_t)r0*FD + idx];
    }
    __syncthreads();
    int col = t & 127, rh = t >> 7;
    float acc[8];
    float bias = proj_b[col];
    #pragma unroll
    for(int rr=0;rr<8;++rr) acc[rr]=bias;
    for(int k=0;k<FD;++k){
      float wv_ = proj_w[k*DD + col];
      #pragma unroll
      for(int rr=0;rr<8;++rr) acc[rr] += sx[rh*8+rr][k]*wv_;
    }
    #pragma unroll
    for(int rr=0;rr<8;++rr){
      int r = r0 + rh*8 + rr;
      feats [(size_t)r*DD + col] = acc[rr];
      featsb[(size_t)r*DD + col] = f2b(acc[rr]);
    }
  } else {
    int id = (blockIdx.x - 768)*256 + t;
    if(id < 131072){
      int m = id >> 16, e = id & 65535;
      int n = e & 255, k = e >> 8;
      const float* s = m ? wv : wk;
      unsigned short* d = m ? wvT : wkT;
      d[n*256 + k] = f2b(s[k*256 + n]);
    } else if(id < 212992){
      int id2 = id - 131072;
      int m = id2 >> 14, e = id2 & 16383;
      int n = e & 127, k = e >> 7;
      const float* s;
      unsigned short* d;
      if(m==0){ s = enc_w2 + 2*16384; d = w2T2; }
      else if(m==1){ s = enc_w2 + 3*16384; d = w2T3; }
      else if(m==2){ s = sw1 + 256*128; d = sw1aT; }
      else if(m==3){ s = sw1 + 384*128; d = sw1bT; }
      else { s = sw2; d = sw2T; }
      d[n*128 + k] = f2b(s[k*128 + n]);
    } else {
      int id3 = id - 212992;
      int b = id3 >> 8, tt = id3 & 255;
      seqb[(size_t)(b*257)*DTD + tt] = f2b(cls_tok[tt]);
    }
  }
}

// ============ CSR build =====================================================
__global__ void k_hist(const int* __restrict__ rows, int* __restrict__ cnt){
  int e = blockIdx.x*256 + threadIdx.x;
  atomicAdd(&cnt[rows[e]], 1);
}

__global__ void k_scan_sbias(const int* __restrict__ cnt, int* __restrict__ rowptr,
                             int* __restrict__ cursor,
                             const float* __restrict__ enc_b1, const float* __restrict__ enc_b2,
                             const float* __restrict__ enc_w2, const float* __restrict__ sw1,
                             const float* __restrict__ sb1, float* __restrict__ sbias){
  int t = threadIdx.x;
  if(blockIdx.x == 0){
    __shared__ int sums[256];
    const int CH = NN/256;  // 48
    int loc[CH];
    int run = 0;
    int base = t*CH;
    #pragma unroll
    for(int i=0;i<CH;++i){ loc[i]=run; run += cnt[base+i]; }
    sums[t]=run;
    __syncthreads();
    for(int off=1; off<256; off<<=1){
      int v = (t>=off)? sums[t-off] : 0;
      __syncthreads();
      sums[t] += v;
      __syncthreads();
    }
    int pref = (t>0)? sums[t-1] : 0;
    #pragma unroll
    for(int i=0;i<CH;++i){
      rowptr[base+i] = pref + loc[i];
      cursor[base+i] = pref + loc[i];
    }
    if(t==255) rowptr[NN] = sums[255];
  } else {
    __shared__ float h0[DD], h1[DD], e0[DD], e1[DD];
    if(t < DD){
      h0[t] = relu_(enc_b1[0*DD+t]);
      h1[t] = relu_(enc_b1[1*DD+t]);
    }
    __syncthreads();
    if(t < DD){
      float a0 = enc_b2[0*DD+t], a1 = enc_b2[1*DD+t];
      for(int d=0; d<DD; ++d){
        a0 += h0[d]*enc_w2[(0*DD+d)*DD + t];
        a1 += h1[d]*enc_w2[(1*DD+d)*DD + t];
      }
      e0[t]=a0; e1[t]=a1;
    }
    __syncthreads();
    if(t < DD){
      float sv = sb1[t];
      for(int d=0; d<DD; ++d)
        sv += e0[d]*sw1[d*DD + t] + e1[d]*sw1[(DD+d)*DD + t];
      sbias[t]=sv;
    }
  }
}

__global__ void k_scatter(const int* __restrict__ rows, const int* __restrict__ cols,
                          const float* __restrict__ vals, int* __restrict__ cursor,
                          int* __restrict__ ccol, float* __restrict__ cval){
  int e = blockIdx.x*256 + threadIdx.x;
  int r = rows[e];
  int p = atomicAdd(&cursor[r], 1);
  ccol[p] = cols[e];
  cval[p] = vals[e];
}

// ============ pull SpMM, bf16 in/out, 16 rows/block, ushort8/lane ==========
__global__ void __launch_bounds__(256)
k_spmm_b(const unsigned short* __restrict__ hin, unsigned short* __restrict__ hout,
         const int* __restrict__ rowptr, const int* __restrict__ ccol,
         const float* __restrict__ cval, const float* __restrict__ feats,
         int finalpass){
  int t = threadIdx.x;
  int r = blockIdx.x*16 + (t>>4);
  int c0 = (t&15)*8;
  int p0 = rowptr[r], p1 = rowptr[r+1];
  float acc[8] = {0,0,0,0,0,0,0,0};
  for(int p=p0; p<p1; ++p){
    int c = ccol[p];
    float v = cval[p];
    s16x8 u = *(const s16x8*)(hin + (size_t)c*DD + c0);
    #pragma unroll
    for(int j=0;j<8;++j) acc[j] += v * b2f((unsigned short)u[j]);
  }
  if(finalpass){
    const float* fp = feats + (size_t)r*DD + c0;
    #pragma unroll
    for(int j=0;j<8;++j) acc[j] = 0.5f*acc[j] + 0.5f*fp[j];
  }
  unsigned short o[8];
  #pragma unroll
  for(int j=0;j<8;++j) o[j] = f2b(acc[j]);
  *(s16x8*)(hout + (size_t)r*DD + c0) = *(const s16x8*)o;
}

// ============ fused token MLP via MFMA: 64 tokens/block ====================
__global__ void __launch_bounds__(256)
k_tok_mfma(const int* __restrict__ node_idx,
           const int* __restrict__ srcI, const int* __restrict__ dstI,
           const float* __restrict__ ppr, const float* __restrict__ drnl,
           const float* __restrict__ enc_w1, const float* __restrict__ enc_b1,
           const unsigned short* __restrict__ w2T2, const unsigned short* __restrict__ w2T3,
           const float* __restrict__ enc_b2,
           const unsigned short* __restrict__ sw1aT, const unsigned short* __restrict__ sw1bT,
           const float* __restrict__ sbias,
           const unsigned short* __restrict__ sw2T, const float* __restrict__ sb2,
           const unsigned short* __restrict__ rexb, unsigned short* __restrict__ seqb){
  __shared__ float sA[64], sB[64], sDV[64];
  __shared__ int sNode[64];
  __shared__ __align__(16) unsigned short e2[64][136];
  __shared__ __align__(16) unsigned short e3[64][136];
  __shared__ __align__(16) unsigned short hid[64][136];

  int tid = threadIdx.x;
  int lane = tid & 63;
  int w = tid >> 6;
  int lr = lane & 15;
  int lg = lane >> 4;
  int t0 = blockIdx.x * 64;
  int bs = t0 >> 8;
  int p0 = t0 & 255;
  int seqrow0 = bs*257 + 1 + p0;

  if(tid < 64){
    int tt = t0 + tid;
    int node = node_idx[tt];
    sNode[tid] = node;
    sA[tid]  = ppr[(size_t)srcI[bs]*NN + node];
    sB[tid]  = ppr[(size_t)dstI[bs]*NN + node];
    sDV[tid] = drnl[(size_t)bs*NN + node];
  }
  __syncthreads();

  // GEMM1: enc2/enc3
  {
    f32x4 acc2[4][2], acc3[4][2];
    #pragma unroll
    for(int nt=0;nt<2;++nt){
      int col = w*32 + nt*16 + lr;
      float b2v = enc_b2[2*DD + col];
      float b3v = enc_b2[3*DD + col];
      #pragma unroll
      for(int rt=0;rt<4;++rt)
        #pragma unroll
        for(int i=0;i<4;++i){ acc2[rt][nt][i]=b2v; acc3[rt][nt][i]=b3v; }
    }
    #pragma unroll
    for(int ks=0; ks<4; ++ks){
      int kb = ks*32 + lg*8;
      float w20[8], w21[8], w3s[8], b2c[8], b3c[8];
      #pragma unroll
      for(int i=0;i<8;++i){
        int k = kb + i;
        w20[i] = enc_w1[4*DD + k];
        w21[i] = enc_w1[5*DD + k];
        w3s[i] = enc_w1[6*DD + k] + enc_w1[7*DD + k];
        b2c[i] = enc_b1[2*DD + k];
        b3c[i] = enc_b1[3*DD + k];
      }
      s16x8 B2[2], B3[2];
      #pragma unroll
      for(int nt=0;nt<2;++nt){
        int col = w*32 + nt*16 + lr;
        B2[nt] = *(const s16x8*)(w2T2 + col*DD + kb);
        B3[nt] = *(const s16x8*)(w2T3 + col*DD + kb);
      }
      #pragma unroll
      for(int rt=0;rt<4;++rt){
        int row = rt*16 + lr;
        float a = sA[row], b = sB[row], dv = sDV[row];
        s16x8 A2, A3;
        #pragma unroll
        for(int i=0;i<8;++i){
          A2[i] = (short)f2b(relu_(a*w20[i] + b*w21[i] + b2c[i]));
          A3[i] = (short)f2b(relu_(dv*w3s[i] + b3c[i]));
        }
        #pragma unroll
        for(int nt=0;nt<2;++nt){
          acc2[rt][nt] = MF(A2, B2[nt], acc2[rt][nt]);
          acc3[rt][nt] = MF(A3, B3[nt], acc3[rt][nt]);
        }
      }
    }
    #pragma unroll
    for(int rt=0;rt<4;++rt)
      #pragma unroll
      for(int nt=0;nt<2;++nt)
        #pragma unroll
        for(int i=0;i<4;++i){
          int row = rt*16 + lg*4 + i;
          int col = w*32 + nt*16 + lr;
          e2[row][col] = f2b(acc2[rt][nt][i]);
          e3[row][col] = f2b(acc3[rt][nt][i]);
        }
  }
  __syncthreads();

  // GEMM2: hidden
  {
    f32x4 acc[4][2];
    #pragma unroll
    for(int nt=0;nt<2;++nt){
      int col = w*32 + nt*16 + lr;
      float sv = sbias[col];
      #pragma unroll
      for(int rt=0;rt<4;++rt)
        #pragma unroll
        for(int i=0;i<4;++i) acc[rt][nt][i]=sv;
    }
    #pragma unroll
    for(int ks=0; ks<4; ++ks){
      int kb = ks*32 + lg*8;
      s16x8 Ba[2], Bb[2];
      #pragma unroll
      for(int nt=0;nt<2;++nt){
        int col = w*32 + nt*16 + lr;
        Ba[nt] = *(const s16x8*)(sw1aT + col*DD + kb);
        Bb[nt] = *(const s16x8*)(sw1bT + col*DD + kb);
      }
      #pragma unroll
      for(int rt=0;rt<4;++rt){
        s16x8 A2 = *(const s16x8*)&e2[rt*16+lr][kb];
        s16x8 A3 = *(const s16x8*)&e3[rt*16+lr][kb];
        #pragma unroll
        for(int nt=0;nt<2;++nt){
          acc[rt][nt] = MF(A2, Ba[nt], acc[rt][nt]);
          acc[rt][nt] = MF(A3, Bb[nt], acc[rt][nt]);
        }
      }
    }
    __syncthreads();
    #pragma unroll
    for(int rt=0;rt<4;++rt)
      #pragma unroll
      for(int nt=0;nt<2;++nt)
        #pragma unroll
        for(int i=0;i<4;++i){
          int row = rt*16 + lg*4 + i;
          int col = w*32 + nt*16 + lr;
          hid[row][col] = f2b(relu_(acc[rt][nt][i]));
        }
  }
  __syncthreads();

  // GEMM3 -> seqb[:,0:128]
  {
    f32x4 acc[4][2];
    #pragma unroll
    for(int nt=0;nt<2;++nt){
      int col = w*32 + nt*16 + lr;
      float bv = sb2[col];
      #pragma unroll
      for(int rt=0;rt<4;++rt)
        #pragma unroll
        for(int i=0;i<4;++i) acc[rt][nt][i]=bv;
    }
    #pragma unroll
    for(int ks=0; ks<4; ++ks){
      int kb = ks*32 + lg*8;
      s16x8 Bc[2];
      #pragma unroll
      for(int nt=0;nt<2;++nt){
        int col = w*32 + nt*16 + lr;
        Bc[nt] = *(const s16x8*)(sw2T + col*DD + kb);
      }
      #pragma unroll
      for(int rt=0;rt<4;++rt){
        s16x8 A = *(const s16x8*)&hid[rt*16+lr][kb];
        #pragma unroll
        for(int nt=0;nt<2;++nt) acc[rt][nt] = MF(A, Bc[nt], acc[rt][nt]);
      }
    }
    #pragma unroll
    for(int rt=0;rt<4;++rt)
      #pragma unroll
      for(int nt=0;nt<2;++nt)
        #pragma unroll
        for(int i=0;i<4;++i){
          int row = rt*16 + lg*4 + i;
          int col = w*32 + nt*16 + lr;
          seqb[(size_t)(seqrow0 + row)*DTD + col] = f2b(acc[rt][nt][i]);
        }
  }

  // re_x gather (bf16 -> bf16 copy): 64 rows x 128 cols
  {
    int row = tid >> 2, l4 = tid & 3;
    int c = l4 * 32;
    int node = sNode[row];
    const unsigned short* rp = rexb + (size_t)node*DD + c;
    unsigned short* op = seqb + (size_t)(seqrow0 + row)*DTD + DD + c;
    #pragma unroll
    for(int j=0;j<4;++j)
      *(s16x8*)(op + j*8) = *(const s16x8*)(rp + j*8);
  }
}

// ============ K,V GEMM via MFMA, bf16 out via LDS bounce ===================
__global__ void __launch_bounds__(256)
k_kv_mfma(const unsigned short* __restrict__ seqb,
          const unsigned short* __restrict__ wkT, const unsigned short* __restrict__ wvT,
          unsigned short* __restrict__ kbuf, unsigned short* __restrict__ vbuf){
  __shared__ __align__(16) unsigned short stile[64][276];
  int tid = threadIdx.x;
  int lane = tid & 63;
  int w = tid >> 6;
  int lr = lane & 15;
  int lg = lane >> 4;
  int row0 = blockIdx.x * 64;
  int col0 = w * 64;

  f32x4 accK[4][4], accV[4][4];
  #pragma unroll
  for(int rt=0;rt<4;++rt)
    #pragma unroll
    for(int nt=0;nt<4;++nt)
      #pragma unroll
      for(int i=0;i<4;++i){ accK[rt][nt][i]=0.f; accV[rt][nt][i]=0.f; }

  #pragma unroll
  for(int ks=0; ks<8; ++ks){
    int kb = ks*32 + lg*8;
    s16x8 A[4], Bk[4], Bv[4];
    #pragma unroll
    for(int rt=0;rt<4;++rt)
      A[rt] = *(const s16x8*)(seqb + (size_t)(row0 + rt*16 + lr)*DTD + kb);
    #pragma unroll
    for(int nt=0;nt<4;++nt){
      int col = col0 + nt*16 + lr;
      Bk[nt] = *(const s16x8*)(wkT + (size_t)col*DTD + kb);
      Bv[nt] = *(const s16x8*)(wvT + (size_t)col*DTD + kb);
    }
    #pragma unroll
    for(int rt=0;rt<4;++rt)
      #pragma unroll
      for(int nt=0;nt<4;++nt){
        accK[rt][nt] = MF(A[rt], Bk[nt], accK[rt][nt]);
        accV[rt][nt] = MF(A[rt], Bv[nt], accV[rt][nt]);
      }
  }

  // K: stage -> coalesced store
  #pragma unroll
  for(int rt=0;rt<4;++rt)
    #pragma unroll
    for(int nt=0;nt<4;++nt)
      #pragma unroll
      for(int i=0;i<4;++i)
        stile[rt*16 + lg*4 + i][col0 + nt*16 + lr] = f2b(accK[rt][nt][i]);
  __syncthreads();
  {
    int row = tid >> 2, c = (tid & 3)*64;
    #pragma unroll
    for(int j=0;j<8;++j)
      *(s16x8*)(kbuf + (size_t)(row0+row)*DTD + c + j*8) = *(const s16x8*)&stile[row][c + j*8];
  }
  __syncthreads();
  // V
  #pragma unroll
  for(int rt=0;rt<4;++rt)
    #pragma unroll
    for(int nt=0;nt<4;++nt)
      #pragma unroll
      for(int i=0;i<4;++i)
        stile[rt*16 + lg*4 + i][col0 + nt*16 + lr] = f2b(accV[rt][nt][i]);
  __syncthreads();
  {
    int row = tid >> 2, c = (tid & 3)*64;
    #pragma unroll
    for(int j=0;j<8;++j)
      *(s16x8*)(vbuf + (size_t)(row0+row)*DTD + c + j*8) = *(const s16x8*)&stile[row][c + j*8];
  }
}

// ============ fused q + attention ==========================================
__device__ __forceinline__ float blk_rmax(float x, float* red){
  int lane = threadIdx.x & 63, wid = threadIdx.x >> 6;
  #pragma unroll
  for(int off=32; off>0; off>>=1) x = fmaxf(x, __shfl_xor(x, off));
  if(lane==0) red[wid]=x;
  __syncthreads();
  float r = fmaxf(fmaxf(red[0],red[1]), fmaxf(red[2],red[3]));
  __syncthreads();
  return r;
}
__device__ __forceinline__ float blk_rsum(float x, float* red){
  int lane = threadIdx.x & 63, wid = threadIdx.x >> 6;
  #pragma unroll
  for(int off=32; off>0; off>>=1) x += __shfl_xor(x, off);
  if(lane==0) red[wid]=x;
  __syncthreads();
  float r = red[0]+red[1]+red[2]+red[3];
  __syncthreads();
  return r;
}

__global__ void __launch_bounds__(256)
k_att2(const unsigned short* __restrict__ seqb, const float* __restrict__ wq,
       const unsigned short* __restrict__ kbuf, const unsigned short* __restrict__ vbuf,
       float* __restrict__ att_o){
  __shared__ float sseq[3][DTD];
  __shared__ float q_s[3][32];
  __shared__ float sc[3][257];
  __shared__ float ppv[8][3][32];
  __shared__ float red[4];
  int t = threadIdx.x;
  int b = blockIdx.x >> 3, h = blockIdx.x & 7;

  for(int i=t; i<3*DTD; i+=256){
    int qi = i >> 8, d = i & 255;
    sseq[qi][d] = b2f(seqb[(size_t)(b*257+qi)*DTD + d]);
  }
  __syncthreads();
  if(t < 96){
    int qi = t>>5, dd = t&31;
    float a = 0.f;
    for(int d=0; d<DTD; ++d) a += sseq[qi][d] * wq[d*DTD + h*32 + dd];
    q_s[qi][dd] = a;
  }
  __syncthreads();
  const float scale = 0.17677669529663687f;  // 1/sqrt(32)
  for(int kk=t; kk<257; kk+=256){
    const unsigned short* kr = kbuf + (size_t)(b*257+kk)*DTD + h*32;
    float kv[32];
    #pragma unroll
    for(int j=0;j<4;++j){
      s16x8 u = *(const s16x8*)(kr + j*8);
      #pragma unroll
      for(int m=0;m<8;++m) kv[j*8+m] = b2f((unsigned short)u[m]);
    }
    float d0=0.f,d1=0.f,d2=0.f;
    #pragma unroll
    for(int dd=0;dd<32;++dd){
      d0 += q_s[0][dd]*kv[dd]; d1 += q_s[1][dd]*kv[dd]; d2 += q_s[2][dd]*kv[dd];
    }
    sc[0][kk]=d0*scale; sc[1][kk]=d1*scale; sc[2][kk]=d2*scale;
  }
  __syncthreads();
  for(int qi=0; qi<3; ++qi){
    float x = sc[qi][t];
    if(t==0) x = fmaxf(x, sc[qi][256]);
    float m = blk_rmax(x, red);
    float e = expf(sc[qi][t]-m);
    float e2 = 0.f;
    if(t==0) e2 = expf(sc[qi][256]-m);
    float s = blk_rsum(e+e2, red);
    float inv = 1.0f/s;
    sc[qi][t] = e*inv;
    if(t==0) sc[qi][256] = e2*inv;
    __syncthreads();
  }
  // PV: all 256 threads, 8 kk-groups
  {
    int dd = t & 31, g = t >> 5;
    float a0=0.f, a1=0.f, a2=0.f;
    for(int kk=g; kk<257; kk+=8){
      float v = b2f(vbuf[(size_t)(b*257+kk)*DTD + h*32 + dd]);
      a0 += sc[0][kk]*v; a1 += sc[1][kk]*v; a2 += sc[2][kk]*v;
    }
    ppv[g][0][dd]=a0; ppv[g][1][dd]=a1; ppv[g][2][dd]=a2;
  }
  __syncthreads();
  if(t < 96){
    int qi = t>>5, dd = t&31;
    float s = 0.f;
    #pragma unroll
    for(int gg=0; gg<8; ++gg) s += ppv[gg][qi][dd];
    att_o[(size_t)(b*3+qi)*DTD + h*32 + dd] = s;
  }
}

// ============ output: att_o @ wo, permuted =================================
__global__ void k_out(const float* __restrict__ att_o, const float* __restrict__ wo,
                      float* __restrict__ out){
  __shared__ float srow[DTD];
  int t = threadIdx.x;
  int r = blockIdx.x;
  int b = r/3, qi = r - b*3;
  srow[t] = att_o[(size_t)r*DTD + t];
  __syncthreads();
  float acc = 0.f;
  for(int d=0; d<DTD; ++d) acc += srow[d]*wo[d*DTD + t];
  int off = (qi==1)? 0 : ((qi==2)? DTD : 2*DTD);
  out[(size_t)b*768 + off + t] = acc;
}

extern "C" void kernel_launch(void* const* d_in, const int* in_sizes, int n_in,
                              void* d_out, int out_size, void* d_ws, size_t ws_size,
                              hipStream_t stream){
  const float* x        = (const float*)d_in[0];
  const float* proj_w   = (const float*)d_in[1];
  const float* proj_b   = (const float*)d_in[2];
  const float* adj_vals = (const float*)d_in[3];
  const int*   adj_rows = (const int*)d_in[4];
  const int*   adj_cols = (const int*)d_in[5];
  const float* ppr      = (const float*)d_in[6];
  const float* drnl     = (const float*)d_in[7];
  const int*   srcI     = (const int*)d_in[8];
  const int*   dstI     = (const int*)d_in[9];
  const int*   node_idx   = (const int*)d_in[11];
  const float* enc_w1   = (const float*)d_in[12];
  const float* enc_b1   = (const float*)d_in[13];
  const float* enc_w2   = (const float*)d_in[14];
  const float* enc_b2   = (const float*)d_in[15];
  const float* sw1      = (const float*)d_in[16];
  const float* sb1      = (const float*)d_in[17];
  const float* sw2      = (const float*)d_in[18];
  const float* sb2      = (const float*)d_in[19];
  const float* cls_tok  = (const float*)d_in[20];
  const float* wq       = (const float*)d_in[21];
  const float* wk       = (const float*)d_in[22];
  const float* wv       = (const float*)d_in[23];
  const float* wo       = (const float*)d_in[24];
  float* out = (float*)d_out;

  char* p = (char*)d_ws;
  auto alloc = [&](size_t bytes)->void*{ void* r = (void*)p; p += (bytes + 63) & ~(size_t)63; return r; };
  float* feats   = (float*)alloc((size_t)NN*DD*4);
  unsigned short* featsb = (unsigned short*)alloc((size_t)NN*DD*2);
  unsigned short* h1b    = (unsigned short*)alloc((size_t)NN*DD*2);
  unsigned short* h2b    = (unsigned short*)alloc((size_t)NN*DD*2);
  unsigned short* rexb   = (unsigned short*)alloc((size_t)NN*DD*2);
  int*   cnt     = (int*)  alloc((size_t)NN*4);
  int*   rowptr  = (int*)  alloc((size_t)(NN+1)*4);
  int*   cursor  = (int*)  alloc((size_t)NN*4);
  int*   csr_col = (int*)  alloc((size_t)EE*4);
  float* csr_val = (float*)alloc((size_t)EE*4);
  float* sbias   = (float*)alloc((size_t)DD*4);
  unsigned short* kbuf = (unsigned short*)alloc((size_t)NSEQ*DTD*2);
  unsigned short* vbuf = (unsigned short*)alloc((size_t)NSEQ*DTD*2);
  float* att_o   = (float*)alloc((size_t)BB*3*DTD*4);
  unsigned short* seqb  = (unsigned short*)alloc((size_t)NSEQ*DTD*2);
  unsigned short* wkT   = (unsigned short*)alloc((size_t)DTD*DTD*2);
  unsigned short* wvT   = (unsigned short*)alloc((size_t)DTD*DTD*2);
  unsigned short* w2T2  = (unsigned short*)alloc((size_t)DD*DD*2);
  unsigned short* w2T3  = (unsigned short*)alloc((size_t)DD*DD*2);
  unsigned short* sw1aT = (unsigned short*)alloc((size_t)DD*DD*2);
  unsigned short* sw1bT = (unsigned short*)alloc((size_t)DD*DD*2);
  unsigned short* sw2T  = (unsigned short*)alloc((size_t)DD*DD*2);

  hipMemsetAsync(cnt, 0, NN*sizeof(int), stream);

  k_setup     <<<1664,   256, 0, stream>>>(x, proj_w, proj_b, feats, featsb,
                                           wk, wv, enc_w2, sw1, sw2, cls_tok,
                                           wkT, wvT, w2T2, w2T3, sw1aT, sw1bT, sw2T, seqb);
  k_hist      <<<EE/256, 256, 0, stream>>>(adj_rows, cnt);
  k_scan_sbias<<<2,      256, 0, stream>>>(cnt, rowptr, cursor, enc_b1, enc_b2, enc_w2, sw1, sb1, sbias);
  k_scatter   <<<EE/256, 256, 0, stream>>>(adj_rows, adj_cols, adj_vals, cursor, csr_col, csr_val);
  k_spmm_b    <<<NN/16,  256, 0, stream>>>(featsb, h1b, rowptr, csr_col, csr_val, feats, 0);
  k_spmm_b    <<<NN/16,  256, 0, stream>>>(h1b,    h2b, rowptr, csr_col, csr_val, feats, 0);
  k_spmm_b    <<<NN/16,  256, 0, stream>>>(h2b,    rexb, rowptr, csr_col, csr_val, feats, 1);
  k_tok_mfma  <<<NTOK/64,256, 0, stream>>>(node_idx, srcI, dstI, ppr, drnl,
                                           enc_w1, enc_b1, w2T2, w2T3, enc_b2,
                                           sw1aT, sw1bT, sbias, sw2T, sb2, rexb, seqb);
  k_kv_mfma   <<<NSEQ/64,256, 0, stream>>>(seqb, wkT, wvT, kbuf, vbuf);
  k_att2      <<<BB*HH,  256, 0, stream>>>(seqb, wq, kbuf, vbuf, att_o);
  k_out       <<<BB*3,   256, 0, stream>>>(att_o, wo, out);
}

// Round 4
// 215.778 us; speedup vs baseline: 1.9288x; 1.0861x over previous
//
#include <hip/hip_runtime.h>
#include <math.h>

#define NN 12288      // nodes
#define FD 128        // input feat dim
#define DD 128        // D
#define EE 393216     // edges
#define BB 64         // batch
#define LL 256        // tokens per sample
#define HH 8          // heads
#define DTD 256       // DT = 2*D
#define NTOK 16384    // B*L
#define NSEQ 16448    // B*257

typedef float f32x4 __attribute__((ext_vector_type(4)));
typedef short s16x8 __attribute__((ext_vector_type(8)));

__device__ __forceinline__ float relu_(float x){ return fmaxf(x, 0.0f); }

__device__ __forceinline__ unsigned short f2b(float f){
  unsigned int u = __float_as_uint(f);
  u += 0x7FFFu + ((u >> 16) & 1u);
  return (unsigned short)(u >> 16);
}
__device__ __forceinline__ float b2f(unsigned short h){
  return __uint_as_float(((unsigned int)h) << 16);
}

__device__ __forceinline__ f32x4 MF(s16x8 a, s16x8 b, f32x4 c){
  return __builtin_amdgcn_mfma_f32_16x16x32_bf16(a, b, c, 0, 0, 0);
}

// ============ kernel A: proj | weight prep | heur gather | hist ============
// blocks 0..767: proj ; 768..1663: prep ; 1664..1727: heur ; 1728..3263: hist
__global__ void __launch_bounds__(256)
k_setup(const float* __restrict__ x, const float* __restrict__ proj_w,
        const float* __restrict__ proj_b, unsigned short* __restrict__ featsb,
        const float* __restrict__ wk, const float* __restrict__ wv,
        const float* __restrict__ enc_w2, const float* __restrict__ sw1,
        const float* __restrict__ sw2, const float* __restrict__ cls_tok,
        unsigned short* __restrict__ wkT, unsigned short* __restrict__ wvT,
        unsigned short* __restrict__ w2T2, unsigned short* __restrict__ w2T3,
        unsigned short* __restrict__ sw1aT, unsigned short* __restrict__ sw1bT,
        unsigned short* __restrict__ sw2T, unsigned short* __restrict__ seqb,
        const int* __restrict__ node_idx, const int* __restrict__ srcI,
        const int* __restrict__ dstI, const float* __restrict__ ppr,
        const float* __restrict__ drnl, float* __restrict__ heurA,
        float* __restrict__ heurB, float* __restrict__ heurD,
        const int* __restrict__ adj_rows, int* __restrict__ cnt){
  int t = threadIdx.x;
  if(blockIdx.x < 768){
    __shared__ float sx[16][FD];
    int r0 = blockIdx.x * 16;
    #pragma unroll
    for(int i=0;i<8;++i){
      int idx = t + i*256;
      sx[idx>>7][idx&127] = x[(size_t)r0*FD + idx];
    }
    __syncthreads();
    int col = t & 127, rh = t >> 7;
    float acc[8];
    float bias = proj_b[col];
    #pragma unroll
    for(int rr=0;rr<8;++rr) acc[rr]=bias;
    for(int k=0;k<FD;++k){
      float wv_ = proj_w[k*DD + col];
      #pragma unroll
      for(int rr=0;rr<8;++rr) acc[rr] += sx[rh*8+rr][k]*wv_;
    }
    #pragma unroll
    for(int rr=0;rr<8;++rr){
      int r = r0 + rh*8 + rr;
      featsb[(size_t)r*DD + col] = f2b(acc[rr]);
    }
  } else if(blockIdx.x < 1664){
    int id = (blockIdx.x - 768)*256 + t;
    if(id < 131072){
      int m = id >> 16, e = id & 65535;
      int n = e & 255, k = e >> 8;
      const float* s = m ? wv : wk;
      unsigned short* d = m ? wvT : wkT;
      d[n*256 + k] = f2b(s[k*256 + n]);
    } else if(id < 212992){
      int id2 = id - 131072;
      int m = id2 >> 14, e = id2 & 16383;
      int n = e & 127, k = e >> 7;
      const float* s;
      unsigned short* d;
      if(m==0){ s = enc_w2 + 2*16384; d = w2T2; }
      else if(m==1){ s = enc_w2 + 3*16384; d = w2T3; }
      else if(m==2){ s = sw1 + 256*128; d = sw1aT; }
      else if(m==3){ s = sw1 + 384*128; d = sw1bT; }
      else { s = sw2; d = sw2T; }
      d[n*128 + k] = f2b(s[k*128 + n]);
    } else {
      int id3 = id - 212992;
      int b = id3 >> 8, tt = id3 & 255;
      seqb[(size_t)(b*257)*DTD + tt] = f2b(cls_tok[tt]);
    }
  } else if(blockIdx.x < 1728){
    int tt = (blockIdx.x - 1664)*256 + t;
    int s = tt >> 8;                 // uniform per block
    int node = node_idx[tt];
    heurA[tt] = ppr[(size_t)srcI[s]*NN + node];
    heurB[tt] = ppr[(size_t)dstI[s]*NN + node];
    heurD[tt] = drnl[(size_t)s*NN + node];
  } else {
    int e = (blockIdx.x - 1728)*256 + t;
    atomicAdd(&cnt[adj_rows[e]], 1);
  }
}

// ============ scan (block0) + sbias fold (block1) ==========================
__global__ void k_scan_sbias(const int* __restrict__ cnt, int* __restrict__ rowptr,
                             int* __restrict__ cursor,
                             const float* __restrict__ enc_b1, const float* __restrict__ enc_b2,
                             const float* __restrict__ enc_w2, const float* __restrict__ sw1,
                             const float* __restrict__ sb1, float* __restrict__ sbias){
  int t = threadIdx.x;
  if(blockIdx.x == 0){
    __shared__ int sums[256];
    const int CH = NN/256;  // 48
    int loc[CH];
    int run = 0;
    int base = t*CH;
    #pragma unroll
    for(int i=0;i<CH;++i){ loc[i]=run; run += cnt[base+i]; }
    sums[t]=run;
    __syncthreads();
    for(int off=1; off<256; off<<=1){
      int v = (t>=off)? sums[t-off] : 0;
      __syncthreads();
      sums[t] += v;
      __syncthreads();
    }
    int pref = (t>0)? sums[t-1] : 0;
    #pragma unroll
    for(int i=0;i<CH;++i){
      rowptr[base+i] = pref + loc[i];
      cursor[base+i] = pref + loc[i];
    }
    if(t==255) rowptr[NN] = sums[255];
  } else {
    __shared__ float h0[DD], h1[DD], e0[DD], e1[DD];
    if(t < DD){
      h0[t] = relu_(enc_b1[0*DD+t]);
      h1[t] = relu_(enc_b1[1*DD+t]);
    }
    __syncthreads();
    if(t < DD){
      float a0 = enc_b2[0*DD+t], a1 = enc_b2[1*DD+t];
      for(int d=0; d<DD; ++d){
        a0 += h0[d]*enc_w2[(0*DD+d)*DD + t];
        a1 += h1[d]*enc_w2[(1*DD+d)*DD + t];
      }
      e0[t]=a0; e1[t]=a1;
    }
    __syncthreads();
    if(t < DD){
      float sv = sb1[t];
      for(int d=0; d<DD; ++d)
        sv += e0[d]*sw1[d*DD + t] + e1[d]*sw1[(DD+d)*DD + t];
      sbias[t]=sv;
    }
  }
}

// ============ scatter: packed (col,val) 8B per edge ========================
__global__ void k_scatter(const int* __restrict__ rows, const int* __restrict__ cols,
                          const float* __restrict__ vals, int* __restrict__ cursor,
                          uint2* __restrict__ ccv){
  int e = blockIdx.x*256 + threadIdx.x;
  int r = rows[e];
  int p = atomicAdd(&cursor[r], 1);
  ccv[p] = make_uint2((unsigned)cols[e], __float_as_uint(vals[e]));
}

// ============ pull SpMM: one wave per row, 2 bf16 per lane =================
__global__ void __launch_bounds__(256)
k_spmm_w(const unsigned int* __restrict__ hin32, unsigned int* __restrict__ hout32,
         const int* __restrict__ rowptr, const uint2* __restrict__ ccv,
         const unsigned int* __restrict__ featsb32, int finalpass){
  int lane = threadIdx.x & 63;
  int r = blockIdx.x*4 + (threadIdx.x>>6);
  int p0 = rowptr[r], p1 = rowptr[r+1];
  float a0=0.f, a1=0.f, b0=0.f, b1=0.f;
  int p = p0;
  for(; p+2 <= p1; p += 2){
    uint2 cv0 = ccv[p];
    uint2 cv1 = ccv[p+1];
    unsigned u0 = hin32[(size_t)cv0.x*64 + lane];
    unsigned u1 = hin32[(size_t)cv1.x*64 + lane];
    float v0 = __uint_as_float(cv0.y), v1 = __uint_as_float(cv1.y);
    a0 += v0 * b2f((unsigned short)(u0 & 0xffffu));
    a1 += v0 * b2f((unsigned short)(u0 >> 16));
    b0 += v1 * b2f((unsigned short)(u1 & 0xffffu));
    b1 += v1 * b2f((unsigned short)(u1 >> 16));
  }
  if(p < p1){
    uint2 cv0 = ccv[p];
    unsigned u0 = hin32[(size_t)cv0.x*64 + lane];
    float v0 = __uint_as_float(cv0.y);
    a0 += v0 * b2f((unsigned short)(u0 & 0xffffu));
    a1 += v0 * b2f((unsigned short)(u0 >> 16));
  }
  a0 += b0; a1 += b1;
  if(finalpass){
    unsigned f = featsb32[(size_t)r*64 + lane];
    a0 = 0.5f*a0 + 0.5f*b2f((unsigned short)(f & 0xffffu));
    a1 = 0.5f*a1 + 0.5f*b2f((unsigned short)(f >> 16));
  }
  hout32[(size_t)r*64 + lane] = (unsigned)f2b(a0) | ((unsigned)f2b(a1) << 16);
}

// ============ fused token MLP via MFMA: 64 tokens/block ====================
__global__ void __launch_bounds__(256)
k_tok_mfma(const int* __restrict__ node_idx,
           const float* __restrict__ heurA, const float* __restrict__ heurB,
           const float* __restrict__ heurD,
           const float* __restrict__ enc_w1, const float* __restrict__ enc_b1,
           const unsigned short* __restrict__ w2T2, const unsigned short* __restrict__ w2T3,
           const float* __restrict__ enc_b2,
           const unsigned short* __restrict__ sw1aT, const unsigned short* __restrict__ sw1bT,
           const float* __restrict__ sbias,
           const unsigned short* __restrict__ sw2T, const float* __restrict__ sb2,
           const unsigned short* __restrict__ rexb, unsigned short* __restrict__ seqb){
  __shared__ float sA[64], sB[64], sDV[64];
  __shared__ int sNode[64];
  __shared__ __align__(16) unsigned short e2[64][136];
  __shared__ __align__(16) unsigned short e3[64][136];
  __shared__ __align__(16) unsigned short hid[64][136];

  int tid = threadIdx.x;
  int lane = tid & 63;
  int w = tid >> 6;
  int lr = lane & 15;
  int lg = lane >> 4;
  int t0 = blockIdx.x * 64;
  int bs = t0 >> 8;
  int p0 = t0 & 255;
  int seqrow0 = bs*257 + 1 + p0;

  if(tid < 64){
    int tt = t0 + tid;
    sNode[tid] = node_idx[tt];
    sA[tid]  = heurA[tt];
    sB[tid]  = heurB[tt];
    sDV[tid] = heurD[tt];
  }
  __syncthreads();

  // GEMM1: enc2/enc3
  {
    f32x4 acc2[4][2], acc3[4][2];
    #pragma unroll
    for(int nt=0;nt<2;++nt){
      int col = w*32 + nt*16 + lr;
      float b2v = enc_b2[2*DD + col];
      float b3v = enc_b2[3*DD + col];
      #pragma unroll
      for(int rt=0;rt<4;++rt)
        #pragma unroll
        for(int i=0;i<4;++i){ acc2[rt][nt][i]=b2v; acc3[rt][nt][i]=b3v; }
    }
    #pragma unroll
    for(int ks=0; ks<4; ++ks){
      int kb = ks*32 + lg*8;
      float w20[8], w21[8], w3s[8], b2c[8], b3c[8];
      #pragma unroll
      for(int i=0;i<8;++i){
        int k = kb + i;
        w20[i] = enc_w1[4*DD + k];
        w21[i] = enc_w1[5*DD + k];
        w3s[i] = enc_w1[6*DD + k] + enc_w1[7*DD + k];
        b2c[i] = enc_b1[2*DD + k];
        b3c[i] = enc_b1[3*DD + k];
      }
      s16x8 B2[2], B3[2];
      #pragma unroll
      for(int nt=0;nt<2;++nt){
        int col = w*32 + nt*16 + lr;
        B2[nt] = *(const s16x8*)(w2T2 + col*DD + kb);
        B3[nt] = *(const s16x8*)(w2T3 + col*DD + kb);
      }
      #pragma unroll
      for(int rt=0;rt<4;++rt){
        int row = rt*16 + lr;
        float a = sA[row], b = sB[row], dv = sDV[row];
        s16x8 A2, A3;
        #pragma unroll
        for(int i=0;i<8;++i){
          A2[i] = (short)f2b(relu_(a*w20[i] + b*w21[i] + b2c[i]));
          A3[i] = (short)f2b(relu_(dv*w3s[i] + b3c[i]));
        }
        #pragma unroll
        for(int nt=0;nt<2;++nt){
          acc2[rt][nt] = MF(A2, B2[nt], acc2[rt][nt]);
          acc3[rt][nt] = MF(A3, B3[nt], acc3[rt][nt]);
        }
      }
    }
    #pragma unroll
    for(int rt=0;rt<4;++rt)
      #pragma unroll
      for(int nt=0;nt<2;++nt)
        #pragma unroll
        for(int i=0;i<4;++i){
          int row = rt*16 + lg*4 + i;
          int col = w*32 + nt*16 + lr;
          e2[row][col] = f2b(acc2[rt][nt][i]);
          e3[row][col] = f2b(acc3[rt][nt][i]);
        }
  }
  __syncthreads();

  // GEMM2: hidden
  {
    f32x4 acc[4][2];
    #pragma unroll
    for(int nt=0;nt<2;++nt){
      int col = w*32 + nt*16 + lr;
      float sv = sbias[col];
      #pragma unroll
      for(int rt=0;rt<4;++rt)
        #pragma unroll
        for(int i=0;i<4;++i) acc[rt][nt][i]=sv;
    }
    #pragma unroll
    for(int ks=0; ks<4; ++ks){
      int kb = ks*32 + lg*8;
      s16x8 Ba[2], Bb[2];
      #pragma unroll
      for(int nt=0;nt<2;++nt){
        int col = w*32 + nt*16 + lr;
        Ba[nt] = *(const s16x8*)(sw1aT + col*DD + kb);
        Bb[nt] = *(const s16x8*)(sw1bT + col*DD + kb);
      }
      #pragma unroll
      for(int rt=0;rt<4;++rt){
        s16x8 A2 = *(const s16x8*)&e2[rt*16+lr][kb];
        s16x8 A3 = *(const s16x8*)&e3[rt*16+lr][kb];
        #pragma unroll
        for(int nt=0;nt<2;++nt){
          acc[rt][nt] = MF(A2, Ba[nt], acc[rt][nt]);
          acc[rt][nt] = MF(A3, Bb[nt], acc[rt][nt]);
        }
      }
    }
    __syncthreads();
    #pragma unroll
    for(int rt=0;rt<4;++rt)
      #pragma unroll
      for(int nt=0;nt<2;++nt)
        #pragma unroll
        for(int i=0;i<4;++i){
          int row = rt*16 + lg*4 + i;
          int col = w*32 + nt*16 + lr;
          hid[row][col] = f2b(relu_(acc[rt][nt][i]));
        }
  }
  __syncthreads();

  // GEMM3 -> seqb[:,0:128]
  {
    f32x4 acc[4][2];
    #pragma unroll
    for(int nt=0;nt<2;++nt){
      int col = w*32 + nt*16 + lr;
      float bv = sb2[col];
      #pragma unroll
      for(int rt=0;rt<4;++rt)
        #pragma unroll
        for(int i=0;i<4;++i) acc[rt][nt][i]=bv;
    }
    #pragma unroll
    for(int ks=0; ks<4; ++ks){
      int kb = ks*32 + lg*8;
      s16x8 Bc[2];
      #pragma unroll
      for(int nt=0;nt<2;++nt){
        int col = w*32 + nt*16 + lr;
        Bc[nt] = *(const s16x8*)(sw2T + col*DD + kb);
      }
      #pragma unroll
      for(int rt=0;rt<4;++rt){
        s16x8 A = *(const s16x8*)&hid[rt*16+lr][kb];
        #pragma unroll
        for(int nt=0;nt<2;++nt) acc[rt][nt] = MF(A, Bc[nt], acc[rt][nt]);
      }
    }
    #pragma unroll
    for(int rt=0;rt<4;++rt)
      #pragma unroll
      for(int nt=0;nt<2;++nt)
        #pragma unroll
        for(int i=0;i<4;++i){
          int row = rt*16 + lg*4 + i;
          int col = w*32 + nt*16 + lr;
          seqb[(size_t)(seqrow0 + row)*DTD + col] = f2b(acc[rt][nt][i]);
        }
  }

  // re_x gather (bf16 -> bf16 copy)
  {
    int row = tid >> 2, l4 = tid & 3;
    int c = l4 * 32;
    int node = sNode[row];
    const unsigned short* rp = rexb + (size_t)node*DD + c;
    unsigned short* op = seqb + (size_t)(seqrow0 + row)*DTD + DD + c;
    #pragma unroll
    for(int j=0;j<4;++j)
      *(s16x8*)(op + j*8) = *(const s16x8*)(rp + j*8);
  }
}

// ============ K,V GEMM via MFMA, bf16 out via LDS bounce ===================
__global__ void __launch_bounds__(256)
k_kv_mfma(const unsigned short* __restrict__ seqb,
          const unsigned short* __restrict__ wkT, const unsigned short* __restrict__ wvT,
          unsigned short* __restrict__ kbuf, unsigned short* __restrict__ vbuf){
  __shared__ __align__(16) unsigned short stile[64][276];
  int tid = threadIdx.x;
  int lane = tid & 63;
  int w = tid >> 6;
  int lr = lane & 15;
  int lg = lane >> 4;
  int row0 = blockIdx.x * 64;
  int col0 = w * 64;

  f32x4 accK[4][4], accV[4][4];
  #pragma unroll
  for(int rt=0;rt<4;++rt)
    #pragma unroll
    for(int nt=0;nt<4;++nt)
      #pragma unroll
      for(int i=0;i<4;++i){ accK[rt][nt][i]=0.f; accV[rt][nt][i]=0.f; }

  #pragma unroll
  for(int ks=0; ks<8; ++ks){
    int kb = ks*32 + lg*8;
    s16x8 A[4], Bk[4], Bv[4];
    #pragma unroll
    for(int rt=0;rt<4;++rt)
      A[rt] = *(const s16x8*)(seqb + (size_t)(row0 + rt*16 + lr)*DTD + kb);
    #pragma unroll
    for(int nt=0;nt<4;++nt){
      int col = col0 + nt*16 + lr;
      Bk[nt] = *(const s16x8*)(wkT + (size_t)col*DTD + kb);
      Bv[nt] = *(const s16x8*)(wvT + (size_t)col*DTD + kb);
    }
    #pragma unroll
    for(int rt=0;rt<4;++rt)
      #pragma unroll
      for(int nt=0;nt<4;++nt){
        accK[rt][nt] = MF(A[rt], Bk[nt], accK[rt][nt]);
        accV[rt][nt] = MF(A[rt], Bv[nt], accV[rt][nt]);
      }
  }

  #pragma unroll
  for(int rt=0;rt<4;++rt)
    #pragma unroll
    for(int nt=0;nt<4;++nt)
      #pragma unroll
      for(int i=0;i<4;++i)
        stile[rt*16 + lg*4 + i][col0 + nt*16 + lr] = f2b(accK[rt][nt][i]);
  __syncthreads();
  {
    int row = tid >> 2, c = (tid & 3)*64;
    #pragma unroll
    for(int j=0;j<8;++j)
      *(s16x8*)(kbuf + (size_t)(row0+row)*DTD + c + j*8) = *(const s16x8*)&stile[row][c + j*8];
  }
  __syncthreads();
  #pragma unroll
  for(int rt=0;rt<4;++rt)
    #pragma unroll
    for(int nt=0;nt<4;++nt)
      #pragma unroll
      for(int i=0;i<4;++i)
        stile[rt*16 + lg*4 + i][col0 + nt*16 + lr] = f2b(accV[rt][nt][i]);
  __syncthreads();
  {
    int row = tid >> 2, c = (tid & 3)*64;
    #pragma unroll
    for(int j=0;j<8;++j)
      *(s16x8*)(vbuf + (size_t)(row0+row)*DTD + c + j*8) = *(const s16x8*)&stile[row][c + j*8];
  }
}

// ============ fused q + attention ==========================================
__global__ void __launch_bounds__(256)
k_att2(const unsigned short* __restrict__ seqb, const float* __restrict__ wq,
       const unsigned short* __restrict__ kbuf, const unsigned short* __restrict__ vbuf,
       float* __restrict__ att_o){
  __shared__ float sseq[3][DTD];
  __shared__ float qpart[2][3][32];
  __shared__ float q_s[3][32];
  __shared__ float sc[3][257];
  __shared__ float ppv[8][3][32];
  int t = threadIdx.x;
  int b = blockIdx.x >> 3, h = blockIdx.x & 7;

  for(int i=t; i<3*DTD; i+=256){
    int qi = i >> 8, d = i & 255;
    sseq[qi][d] = b2f(seqb[(size_t)(b*257+qi)*DTD + d]);
  }
  __syncthreads();
  if(t < 192){
    int qi = t>>6, l = t&63, half = l>>5, dd = l&31;
    float a = 0.f;
    int d0 = half*128;
    for(int d=d0; d<d0+128; ++d) a += sseq[qi][d] * wq[d*DTD + h*32 + dd];
    qpart[half][qi][dd] = a;
  }
  __syncthreads();
  if(t < 96){
    int qi = t>>5, dd = t&31;
    q_s[qi][dd] = qpart[0][qi][dd] + qpart[1][qi][dd];
  }
  __syncthreads();
  const float scale = 0.17677669529663687f;  // 1/sqrt(32)
  for(int kk=t; kk<257; kk+=256){
    const unsigned short* kr = kbuf + (size_t)(b*257+kk)*DTD + h*32;
    float kv[32];
    #pragma unroll
    for(int j=0;j<4;++j){
      s16x8 u = *(const s16x8*)(kr + j*8);
      #pragma unroll
      for(int m2=0;m2<8;++m2) kv[j*8+m2] = b2f((unsigned short)u[m2]);
    }
    float d0=0.f,d1=0.f,d2=0.f;
    #pragma unroll
    for(int dd=0;dd<32;++dd){
      d0 += q_s[0][dd]*kv[dd]; d1 += q_s[1][dd]*kv[dd]; d2 += q_s[2][dd]*kv[dd];
    }
    sc[0][kk]=d0*scale; sc[1][kk]=d1*scale; sc[2][kk]=d2*scale;
  }
  __syncthreads();
  { // softmax: wave w handles qi=w, no extra barriers
    int wv = t>>6, lane = t&63;
    if(wv < 3){
      int qi = wv;
      float x0=sc[qi][lane], x1=sc[qi][lane+64], x2=sc[qi][lane+128], x3=sc[qi][lane+192];
      float x4 = (lane==0)? sc[qi][256] : -1e30f;
      float m = fmaxf(fmaxf(fmaxf(x0,x1),fmaxf(x2,x3)),x4);
      #pragma unroll
      for(int off=32; off>0; off>>=1) m = fmaxf(m, __shfl_xor(m, off));
      float e0=expf(x0-m), e1=expf(x1-m), e2v=expf(x2-m), e3v=expf(x3-m);
      float e4=(lane==0)? expf(x4-m) : 0.f;
      float s = e0+e1+e2v+e3v+e4;
      #pragma unroll
      for(int off=32; off>0; off>>=1) s += __shfl_xor(s, off);
      float inv = 1.0f/s;
      sc[qi][lane]=e0*inv; sc[qi][lane+64]=e1*inv;
      sc[qi][lane+128]=e2v*inv; sc[qi][lane+192]=e3v*inv;
      if(lane==0) sc[qi][256]=e4*inv;
    }
  }
  __syncthreads();
  { // PV: 8 kk-groups
    int dd = t & 31, g = t >> 5;
    float a0=0.f, a1=0.f, a2=0.f;
    for(int kk=g; kk<257; kk+=8){
      float v = b2f(vbuf[(size_t)(b*257+kk)*DTD + h*32 + dd]);
      a0 += sc[0][kk]*v; a1 += sc[1][kk]*v; a2 += sc[2][kk]*v;
    }
    ppv[g][0][dd]=a0; ppv[g][1][dd]=a1; ppv[g][2][dd]=a2;
  }
  __syncthreads();
  if(t < 96){
    int qi = t>>5, dd = t&31;
    float s = 0.f;
    #pragma unroll
    for(int gg=0; gg<8; ++gg) s += ppv[gg][qi][dd];
    att_o[(size_t)(b*3+qi)*DTD + h*32 + dd] = s;
  }
}

// ============ output: att_o @ wo, permuted =================================
__global__ void k_out(const float* __restrict__ att_o, const float* __restrict__ wo,
                      float* __restrict__ out){
  __shared__ float srow[DTD];
  int t = threadIdx.x;
  int r = blockIdx.x;
  int b = r/3, qi = r - b*3;
  srow[t] = att_o[(size_t)r*DTD + t];
  __syncthreads();
  float acc = 0.f;
  for(int d=0; d<DTD; ++d) acc += srow[d]*wo[d*DTD + t];
  int off = (qi==1)? 0 : ((qi==2)? DTD : 2*DTD);
  out[(size_t)b*768 + off + t] = acc;
}

extern "C" void kernel_launch(void* const* d_in, const int* in_sizes, int n_in,
                              void* d_out, int out_size, void* d_ws, size_t ws_size,
                              hipStream_t stream){
  const float* x        = (const float*)d_in[0];
  const float* proj_w   = (const float*)d_in[1];
  const float* proj_b   = (const float*)d_in[2];
  const float* adj_vals = (const float*)d_in[3];
  const int*   adj_rows = (const int*)d_in[4];
  const int*   adj_cols = (const int*)d_in[5];
  const float* ppr      = (const float*)d_in[6];
  const float* drnl     = (const float*)d_in[7];
  const int*   srcI     = (const int*)d_in[8];
  const int*   dstI     = (const int*)d_in[9];
  const int*   node_idx   = (const int*)d_in[11];
  const float* enc_w1   = (const float*)d_in[12];
  const float* enc_b1   = (const float*)d_in[13];
  const float* enc_w2   = (const float*)d_in[14];
  const float* enc_b2   = (const float*)d_in[15];
  const float* sw1      = (const float*)d_in[16];
  const float* sb1      = (const float*)d_in[17];
  const float* sw2      = (const float*)d_in[18];
  const float* sb2      = (const float*)d_in[19];
  const float* cls_tok  = (const float*)d_in[20];
  const float* wq       = (const float*)d_in[21];
  const float* wk       = (const float*)d_in[22];
  const float* wv       = (const float*)d_in[23];
  const float* wo       = (const float*)d_in[24];
  float* out = (float*)d_out;

  char* p = (char*)d_ws;
  auto alloc = [&](size_t bytes)->void*{ void* r = (void*)p; p += (bytes + 63) & ~(size_t)63; return r; };
  unsigned short* featsb = (unsigned short*)alloc((size_t)NN*DD*2);
  unsigned short* h1b    = (unsigned short*)alloc((size_t)NN*DD*2);
  unsigned short* h2b    = (unsigned short*)alloc((size_t)NN*DD*2);
  unsigned short* rexb   = (unsigned short*)alloc((size_t)NN*DD*2);
  int*   cnt     = (int*)  alloc((size_t)NN*4);
  int*   rowptr  = (int*)  alloc((size_t)(NN+1)*4);
  int*   cursor  = (int*)  alloc((size_t)NN*4);
  uint2* ccv     = (uint2*)alloc((size_t)EE*8);
  float* sbias   = (float*)alloc((size_t)DD*4);
  float* heurA   = (float*)alloc((size_t)NTOK*4);
  float* heurB   = (float*)alloc((size_t)NTOK*4);
  float* heurD   = (float*)alloc((size_t)NTOK*4);
  unsigned short* kbuf = (unsigned short*)alloc((size_t)NSEQ*DTD*2);
  unsigned short* vbuf = (unsigned short*)alloc((size_t)NSEQ*DTD*2);
  float* att_o   = (float*)alloc((size_t)BB*3*DTD*4);
  unsigned short* seqb  = (unsigned short*)alloc((size_t)NSEQ*DTD*2);
  unsigned short* wkT   = (unsigned short*)alloc((size_t)DTD*DTD*2);
  unsigned short* wvT   = (unsigned short*)alloc((size_t)DTD*DTD*2);
  unsigned short* w2T2  = (unsigned short*)alloc((size_t)DD*DD*2);
  unsigned short* w2T3  = (unsigned short*)alloc((size_t)DD*DD*2);
  unsigned short* sw1aT = (unsigned short*)alloc((size_t)DD*DD*2);
  unsigned short* sw1bT = (unsigned short*)alloc((size_t)DD*DD*2);
  unsigned short* sw2T  = (unsigned short*)alloc((size_t)DD*DD*2);

  hipMemsetAsync(cnt, 0, NN*sizeof(int), stream);

  k_setup     <<<3264,   256, 0, stream>>>(x, proj_w, proj_b, featsb,
                                           wk, wv, enc_w2, sw1, sw2, cls_tok,
                                           wkT, wvT, w2T2, w2T3, sw1aT, sw1bT, sw2T, seqb,
                                           node_idx, srcI, dstI, ppr, drnl,
                                           heurA, heurB, heurD, adj_rows, cnt);
  k_scan_sbias<<<2,      256, 0, stream>>>(cnt, rowptr, cursor, enc_b1, enc_b2, enc_w2, sw1, sb1, sbias);
  k_scatter   <<<EE/256, 256, 0, stream>>>(adj_rows, adj_cols, adj_vals, cursor, ccv);
  k_spmm_w    <<<NN/4,   256, 0, stream>>>((const unsigned*)featsb, (unsigned*)h1b, rowptr, ccv, (const unsigned*)featsb, 0);
  k_spmm_w    <<<NN/4,   256, 0, stream>>>((const unsigned*)h1b, (unsigned*)h2b, rowptr, ccv, (const unsigned*)featsb, 0);
  k_spmm_w    <<<NN/4,   256, 0, stream>>>((const unsigned*)h2b, (unsigned*)rexb, rowptr, ccv, (const unsigned*)featsb, 1);
  k_tok_mfma  <<<NTOK/64,256, 0, stream>>>(node_idx, heurA, heurB, heurD,
                                           enc_w1, enc_b1, w2T2, w2T3, enc_b2,
                                           sw1aT, sw1bT, sbias, sw2T, sb2, rexb, seqb);
  k_kv_mfma   <<<NSEQ/64,256, 0, stream>>>(seqb, wkT, wvT, kbuf, vbuf);
  k_att2      <<<BB*HH,  256, 0, stream>>>(seqb, wq, kbuf, vbuf, att_o);
  k_out       <<<BB*3,   256, 0, stream>>>(att_o, wo, out);
}

// Round 5
// 165.567 us; speedup vs baseline: 2.5138x; 1.3033x over previous
//
#include <hip/hip_runtime.h>
#include <math.h>

#define NN 12288      // nodes
#define FD 128        // input feat dim
#define DD 128        // D
#define EE 393216     // edges
#define BB 64         // batch
#define LL 256        // tokens per sample
#define HH 8          // heads
#define DTD 256       // DT = 2*D
#define NTOK 16384    // B*L
#define NSEQ 16448    // B*257
#define CAP 128       // max row degree capacity (mean 32, Poisson tail ~0 at 128)

// k_setup block ranges
#define SC_B0   0      // scatter: [0,1536)
#define PROJ_B0 1536   // proj MFMA: [1536,1728)
#define PREP_B0 1728   // weight prep: [1728,2880)
#define HEUR_B0 2880   // heur gather: [2880,2944)
#define SBIAS_B 2944   // sbias fold: block 2944
#define SETUP_GRID 2945

typedef float f32x4 __attribute__((ext_vector_type(4)));
typedef short s16x8 __attribute__((ext_vector_type(8)));

__device__ __forceinline__ float relu_(float x){ return fmaxf(x, 0.0f); }

__device__ __forceinline__ unsigned short f2b(float f){
  unsigned int u = __float_as_uint(f);
  u += 0x7FFFu + ((u >> 16) & 1u);
  return (unsigned short)(u >> 16);
}
__device__ __forceinline__ float b2f(unsigned short h){
  return __uint_as_float(((unsigned int)h) << 16);
}

__device__ __forceinline__ f32x4 MF(s16x8 a, s16x8 b, f32x4 c){
  return __builtin_amdgcn_mfma_f32_16x16x32_bf16(a, b, c, 0, 0, 0);
}

// ============ kernel A: scatter | proj(MFMA) | prep | heur | sbias ==========
__global__ void __launch_bounds__(256)
k_setup(const float* __restrict__ x, const float* __restrict__ proj_w,
        const float* __restrict__ proj_b, unsigned short* __restrict__ featsb,
        const float* __restrict__ wq, const float* __restrict__ wk,
        const float* __restrict__ wv,
        const float* __restrict__ enc_w2, const float* __restrict__ sw1,
        const float* __restrict__ sw2, const float* __restrict__ cls_tok,
        unsigned short* __restrict__ wqT, unsigned short* __restrict__ wkT,
        unsigned short* __restrict__ wvT,
        unsigned short* __restrict__ w2T2, unsigned short* __restrict__ w2T3,
        unsigned short* __restrict__ sw1aT, unsigned short* __restrict__ sw1bT,
        unsigned short* __restrict__ sw2T, unsigned short* __restrict__ seqb,
        const int* __restrict__ node_idx, const int* __restrict__ srcI,
        const int* __restrict__ dstI, const float* __restrict__ ppr,
        const float* __restrict__ drnl, float* __restrict__ heurA,
        float* __restrict__ heurB, float* __restrict__ heurD,
        const int* __restrict__ adj_rows, const int* __restrict__ adj_cols,
        const float* __restrict__ adj_vals, int* __restrict__ cnt,
        uint2* __restrict__ ccv,
        const float* __restrict__ enc_b1, const float* __restrict__ enc_b2,
        const float* __restrict__ sb1, float* __restrict__ sbias){
  int t = threadIdx.x;
  if(blockIdx.x < PROJ_B0){
    // ---- scatter: bump-allocate edges into row buckets ----
    int e = blockIdx.x*256 + t;
    int r = adj_rows[e];
    int p = atomicAdd(&cnt[r], 1);
    ccv[(size_t)r*CAP + p] = make_uint2((unsigned)adj_cols[e], __float_as_uint(adj_vals[e]));
  } else if(blockIdx.x < PREP_B0){
    // ---- proj: feats = x @ proj_w + b via MFMA, on-the-fly bf16 ----
    int bid = blockIdx.x - PROJ_B0;
    int row0 = bid * 64;
    int lane = t & 63, w = t >> 6;
    int lr = lane & 15, lg = lane >> 4;
    f32x4 acc[4][2];
    #pragma unroll
    for(int nt=0;nt<2;++nt){
      int col = w*32 + nt*16 + lr;
      float bv = proj_b[col];
      #pragma unroll
      for(int rt=0;rt<4;++rt)
        #pragma unroll
        for(int i=0;i<4;++i) acc[rt][nt][i]=bv;
    }
    #pragma unroll
    for(int ks=0; ks<4; ++ks){
      int kb = ks*32 + lg*8;
      s16x8 Bf[2];
      #pragma unroll
      for(int nt=0;nt<2;++nt){
        int col = w*32 + nt*16 + lr;
        #pragma unroll
        for(int i=0;i<8;++i) Bf[nt][i] = (short)f2b(proj_w[(kb+i)*DD + col]);
      }
      #pragma unroll
      for(int rt=0;rt<4;++rt){
        int row = row0 + rt*16 + lr;
        const f32x4* xp = (const f32x4*)(x + (size_t)row*FD + kb);
        f32x4 v0 = xp[0], v1 = xp[1];
        s16x8 Af;
        #pragma unroll
        for(int i=0;i<4;++i){ Af[i] = (short)f2b(v0[i]); Af[4+i] = (short)f2b(v1[i]); }
        #pragma unroll
        for(int nt=0;nt<2;++nt) acc[rt][nt] = MF(Af, Bf[nt], acc[rt][nt]);
      }
    }
    #pragma unroll
    for(int rt=0;rt<4;++rt)
      #pragma unroll
      for(int nt=0;nt<2;++nt)
        #pragma unroll
        for(int i=0;i<4;++i){
          int row = row0 + rt*16 + lg*4 + i;
          int col = w*32 + nt*16 + lr;
          featsb[(size_t)row*DD + col] = f2b(acc[rt][nt][i]);
        }
  } else if(blockIdx.x < HEUR_B0){
    // ---- prep: weight transposes to bf16 [out][k], cls rows ----
    int id = (blockIdx.x - PREP_B0)*256 + t;
    if(id < 196608){
      int m = id >> 16, e = id & 65535;
      int n = e & 255, k = e >> 8;
      const float* s = (m==0)? wq : (m==1)? wk : wv;
      unsigned short* d = (m==0)? wqT : (m==1)? wkT : wvT;
      d[n*256 + k] = f2b(s[k*256 + n]);
    } else if(id < 278528){
      int id2 = id - 196608;
      int m = id2 >> 14, e = id2 & 16383;
      int n = e & 127, k = e >> 7;
      const float* s;
      unsigned short* d;
      if(m==0){ s = enc_w2 + 2*16384; d = w2T2; }
      else if(m==1){ s = enc_w2 + 3*16384; d = w2T3; }
      else if(m==2){ s = sw1 + 256*128; d = sw1aT; }
      else if(m==3){ s = sw1 + 384*128; d = sw1bT; }
      else { s = sw2; d = sw2T; }
      d[n*128 + k] = f2b(s[k*128 + n]);
    } else {
      int id3 = id - 278528;
      int b = id3 >> 8, tt = id3 & 255;
      seqb[(size_t)(b*257)*DTD + tt] = f2b(cls_tok[tt]);
    }
  } else if(blockIdx.x < SBIAS_B){
    // ---- heur gathers ----
    int tt = (blockIdx.x - HEUR_B0)*256 + t;
    int s = tt >> 8;
    int node = node_idx[tt];
    heurA[tt] = ppr[(size_t)srcI[s]*NN + node];
    heurB[tt] = ppr[(size_t)dstI[s]*NN + node];
    heurD[tt] = drnl[(size_t)s*NN + node];
  } else {
    // ---- sbias fold (constant enc channels 0,1 + struct_b1) ----
    __shared__ float h0[DD], h1[DD], e0[DD], e1[DD];
    if(t < DD){
      h0[t] = relu_(enc_b1[0*DD+t]);
      h1[t] = relu_(enc_b1[1*DD+t]);
    }
    __syncthreads();
    if(t < DD){
      float a0 = enc_b2[0*DD+t], a1 = enc_b2[1*DD+t];
      for(int d=0; d<DD; ++d){
        a0 += h0[d]*enc_w2[(0*DD+d)*DD + t];
        a1 += h1[d]*enc_w2[(1*DD+d)*DD + t];
      }
      e0[t]=a0; e1[t]=a1;
    }
    __syncthreads();
    if(t < DD){
      float sv = sb1[t];
      for(int d=0; d<DD; ++d)
        sv += e0[d]*sw1[d*DD + t] + e1[d]*sw1[(DD+d)*DD + t];
      sbias[t]=sv;
    }
  }
}

// ============ pull SpMM: one wave per row, unroll-4, bucketed CSR ==========
__global__ void __launch_bounds__(256)
k_spmm_w(const unsigned int* __restrict__ hin32, unsigned int* __restrict__ hout32,
         const int* __restrict__ cnt, const uint2* __restrict__ ccv,
         const unsigned int* __restrict__ featsb32, int finalpass){
  int lane = threadIdx.x & 63;
  int r = blockIdx.x*4 + (threadIdx.x>>6);
  int deg = cnt[r];
  const uint2* base = ccv + (size_t)r*CAP;
  float a0=0.f,a1=0.f,b0=0.f,b1=0.f,c0=0.f,c1=0.f,d0=0.f,d1=0.f;
  int p = 0;
  for(; p+4 <= deg; p += 4){
    uint2 q0 = base[p], q1 = base[p+1], q2 = base[p+2], q3 = base[p+3];
    unsigned u0 = hin32[(size_t)q0.x*64 + lane];
    unsigned u1 = hin32[(size_t)q1.x*64 + lane];
    unsigned u2 = hin32[(size_t)q2.x*64 + lane];
    unsigned u3 = hin32[(size_t)q3.x*64 + lane];
    float v0=__uint_as_float(q0.y), v1=__uint_as_float(q1.y);
    float v2=__uint_as_float(q2.y), v3=__uint_as_float(q3.y);
    a0 += v0*b2f((unsigned short)(u0&0xffffu)); a1 += v0*b2f((unsigned short)(u0>>16));
    b0 += v1*b2f((unsigned short)(u1&0xffffu)); b1 += v1*b2f((unsigned short)(u1>>16));
    c0 += v2*b2f((unsigned short)(u2&0xffffu)); c1 += v2*b2f((unsigned short)(u2>>16));
    d0 += v3*b2f((unsigned short)(u3&0xffffu)); d1 += v3*b2f((unsigned short)(u3>>16));
  }
  for(; p < deg; ++p){
    uint2 q0 = base[p];
    unsigned u0 = hin32[(size_t)q0.x*64 + lane];
    float v0 = __uint_as_float(q0.y);
    a0 += v0*b2f((unsigned short)(u0&0xffffu)); a1 += v0*b2f((unsigned short)(u0>>16));
  }
  a0 += b0 + c0 + d0;
  a1 += b1 + c1 + d1;
  if(finalpass){
    unsigned f = featsb32[(size_t)r*64 + lane];
    a0 = 0.5f*a0 + 0.5f*b2f((unsigned short)(f & 0xffffu));
    a1 = 0.5f*a1 + 0.5f*b2f((unsigned short)(f >> 16));
  }
  hout32[(size_t)r*64 + lane] = (unsigned)f2b(a0) | ((unsigned)f2b(a1) << 16);
}

// ============ fused token MLP via MFMA: 64 tokens/block ====================
__global__ void __launch_bounds__(256)
k_tok_mfma(const int* __restrict__ node_idx,
           const float* __restrict__ heurA, const float* __restrict__ heurB,
           const float* __restrict__ heurD,
           const float* __restrict__ enc_w1, const float* __restrict__ enc_b1,
           const unsigned short* __restrict__ w2T2, const unsigned short* __restrict__ w2T3,
           const float* __restrict__ enc_b2,
           const unsigned short* __restrict__ sw1aT, const unsigned short* __restrict__ sw1bT,
           const float* __restrict__ sbias,
           const unsigned short* __restrict__ sw2T, const float* __restrict__ sb2,
           const unsigned short* __restrict__ rexb, unsigned short* __restrict__ seqb){
  __shared__ float sA[64], sB[64], sDV[64];
  __shared__ int sNode[64];
  __shared__ __align__(16) unsigned short e2[64][136];
  __shared__ __align__(16) unsigned short e3[64][136];
  __shared__ __align__(16) unsigned short hid[64][136];

  int tid = threadIdx.x;
  int lane = tid & 63;
  int w = tid >> 6;
  int lr = lane & 15;
  int lg = lane >> 4;
  int t0 = blockIdx.x * 64;
  int bs = t0 >> 8;
  int p0 = t0 & 255;
  int seqrow0 = bs*257 + 1 + p0;

  if(tid < 64){
    int tt = t0 + tid;
    sNode[tid] = node_idx[tt];
    sA[tid]  = heurA[tt];
    sB[tid]  = heurB[tt];
    sDV[tid] = heurD[tt];
  }
  __syncthreads();

  // GEMM1: enc2/enc3
  {
    f32x4 acc2[4][2], acc3[4][2];
    #pragma unroll
    for(int nt=0;nt<2;++nt){
      int col = w*32 + nt*16 + lr;
      float b2v = enc_b2[2*DD + col];
      float b3v = enc_b2[3*DD + col];
      #pragma unroll
      for(int rt=0;rt<4;++rt)
        #pragma unroll
        for(int i=0;i<4;++i){ acc2[rt][nt][i]=b2v; acc3[rt][nt][i]=b3v; }
    }
    #pragma unroll
    for(int ks=0; ks<4; ++ks){
      int kb = ks*32 + lg*8;
      float w20[8], w21[8], w3s[8], b2c[8], b3c[8];
      #pragma unroll
      for(int i=0;i<8;++i){
        int k = kb + i;
        w20[i] = enc_w1[4*DD + k];
        w21[i] = enc_w1[5*DD + k];
        w3s[i] = enc_w1[6*DD + k] + enc_w1[7*DD + k];
        b2c[i] = enc_b1[2*DD + k];
        b3c[i] = enc_b1[3*DD + k];
      }
      s16x8 B2[2], B3[2];
      #pragma unroll
      for(int nt=0;nt<2;++nt){
        int col = w*32 + nt*16 + lr;
        B2[nt] = *(const s16x8*)(w2T2 + col*DD + kb);
        B3[nt] = *(const s16x8*)(w2T3 + col*DD + kb);
      }
      #pragma unroll
      for(int rt=0;rt<4;++rt){
        int row = rt*16 + lr;
        float a = sA[row], b = sB[row], dv = sDV[row];
        s16x8 A2, A3;
        #pragma unroll
        for(int i=0;i<8;++i){
          A2[i] = (short)f2b(relu_(a*w20[i] + b*w21[i] + b2c[i]));
          A3[i] = (short)f2b(relu_(dv*w3s[i] + b3c[i]));
        }
        #pragma unroll
        for(int nt=0;nt<2;++nt){
          acc2[rt][nt] = MF(A2, B2[nt], acc2[rt][nt]);
          acc3[rt][nt] = MF(A3, B3[nt], acc3[rt][nt]);
        }
      }
    }
    #pragma unroll
    for(int rt=0;rt<4;++rt)
      #pragma unroll
      for(int nt=0;nt<2;++nt)
        #pragma unroll
        for(int i=0;i<4;++i){
          int row = rt*16 + lg*4 + i;
          int col = w*32 + nt*16 + lr;
          e2[row][col] = f2b(acc2[rt][nt][i]);
          e3[row][col] = f2b(acc3[rt][nt][i]);
        }
  }
  __syncthreads();

  // GEMM2: hidden
  {
    f32x4 acc[4][2];
    #pragma unroll
    for(int nt=0;nt<2;++nt){
      int col = w*32 + nt*16 + lr;
      float sv = sbias[col];
      #pragma unroll
      for(int rt=0;rt<4;++rt)
        #pragma unroll
        for(int i=0;i<4;++i) acc[rt][nt][i]=sv;
    }
    #pragma unroll
    for(int ks=0; ks<4; ++ks){
      int kb = ks*32 + lg*8;
      s16x8 Ba[2], Bb[2];
      #pragma unroll
      for(int nt=0;nt<2;++nt){
        int col = w*32 + nt*16 + lr;
        Ba[nt] = *(const s16x8*)(sw1aT + col*DD + kb);
        Bb[nt] = *(const s16x8*)(sw1bT + col*DD + kb);
      }
      #pragma unroll
      for(int rt=0;rt<4;++rt){
        s16x8 A2 = *(const s16x8*)&e2[rt*16+lr][kb];
        s16x8 A3 = *(const s16x8*)&e3[rt*16+lr][kb];
        #pragma unroll
        for(int nt=0;nt<2;++nt){
          acc[rt][nt] = MF(A2, Ba[nt], acc[rt][nt]);
          acc[rt][nt] = MF(A3, Bb[nt], acc[rt][nt]);
        }
      }
    }
    __syncthreads();
    #pragma unroll
    for(int rt=0;rt<4;++rt)
      #pragma unroll
      for(int nt=0;nt<2;++nt)
        #pragma unroll
        for(int i=0;i<4;++i){
          int row = rt*16 + lg*4 + i;
          int col = w*32 + nt*16 + lr;
          hid[row][col] = f2b(relu_(acc[rt][nt][i]));
        }
  }
  __syncthreads();

  // GEMM3 -> seqb[:,0:128]
  {
    f32x4 acc[4][2];
    #pragma unroll
    for(int nt=0;nt<2;++nt){
      int col = w*32 + nt*16 + lr;
      float bv = sb2[col];
      #pragma unroll
      for(int rt=0;rt<4;++rt)
        #pragma unroll
        for(int i=0;i<4;++i) acc[rt][nt][i]=bv;
    }
    #pragma unroll
    for(int ks=0; ks<4; ++ks){
      int kb = ks*32 + lg*8;
      s16x8 Bc[2];
      #pragma unroll
      for(int nt=0;nt<2;++nt){
        int col = w*32 + nt*16 + lr;
        Bc[nt] = *(const s16x8*)(sw2T + col*DD + kb);
      }
      #pragma unroll
      for(int rt=0;rt<4;++rt){
        s16x8 A = *(const s16x8*)&hid[rt*16+lr][kb];
        #pragma unroll
        for(int nt=0;nt<2;++nt) acc[rt][nt] = MF(A, Bc[nt], acc[rt][nt]);
      }
    }
    #pragma unroll
    for(int rt=0;rt<4;++rt)
      #pragma unroll
      for(int nt=0;nt<2;++nt)
        #pragma unroll
        for(int i=0;i<4;++i){
          int row = rt*16 + lg*4 + i;
          int col = w*32 + nt*16 + lr;
          seqb[(size_t)(seqrow0 + row)*DTD + col] = f2b(acc[rt][nt][i]);
        }
  }

  // re_x gather (bf16 -> bf16 copy)
  {
    int row = tid >> 2, l4 = tid & 3;
    int c = l4 * 32;
    int node = sNode[row];
    const unsigned short* rp = rexb + (size_t)node*DD + c;
    unsigned short* op = seqb + (size_t)(seqrow0 + row)*DTD + DD + c;
    #pragma unroll
    for(int j=0;j<4;++j)
      *(s16x8*)(op + j*8) = *(const s16x8*)(rp + j*8);
  }
}

// ============ K,V (blocks 0..256) + Q (blocks 257..259) GEMM via MFMA ======
__global__ void __launch_bounds__(256)
k_kv_mfma(const unsigned short* __restrict__ seqb,
          const unsigned short* __restrict__ wkT, const unsigned short* __restrict__ wvT,
          const unsigned short* __restrict__ wqT,
          unsigned short* __restrict__ kbuf, unsigned short* __restrict__ vbuf,
          float* __restrict__ qbuf){
  __shared__ __align__(16) unsigned short stile[64][276];
  int tid = threadIdx.x;
  int lane = tid & 63;
  int w = tid >> 6;
  int lr = lane & 15;
  int lg = lane >> 4;

  if(blockIdx.x < 257){
    int row0 = blockIdx.x * 64;
    int col0 = w * 64;
    f32x4 accK[4][4], accV[4][4];
    #pragma unroll
    for(int rt=0;rt<4;++rt)
      #pragma unroll
      for(int nt=0;nt<4;++nt)
        #pragma unroll
        for(int i=0;i<4;++i){ accK[rt][nt][i]=0.f; accV[rt][nt][i]=0.f; }

    #pragma unroll
    for(int ks=0; ks<8; ++ks){
      int kb = ks*32 + lg*8;
      s16x8 A[4], Bk[4], Bv[4];
      #pragma unroll
      for(int rt=0;rt<4;++rt)
        A[rt] = *(const s16x8*)(seqb + (size_t)(row0 + rt*16 + lr)*DTD + kb);
      #pragma unroll
      for(int nt=0;nt<4;++nt){
        int col = col0 + nt*16 + lr;
        Bk[nt] = *(const s16x8*)(wkT + (size_t)col*DTD + kb);
        Bv[nt] = *(const s16x8*)(wvT + (size_t)col*DTD + kb);
      }
      #pragma unroll
      for(int rt=0;rt<4;++rt)
        #pragma unroll
        for(int nt=0;nt<4;++nt){
          accK[rt][nt] = MF(A[rt], Bk[nt], accK[rt][nt]);
          accV[rt][nt] = MF(A[rt], Bv[nt], accV[rt][nt]);
        }
    }

    #pragma unroll
    for(int rt=0;rt<4;++rt)
      #pragma unroll
      for(int nt=0;nt<4;++nt)
        #pragma unroll
        for(int i=0;i<4;++i)
          stile[rt*16 + lg*4 + i][col0 + nt*16 + lr] = f2b(accK[rt][nt][i]);
    __syncthreads();
    {
      int row = tid >> 2, c = (tid & 3)*64;
      #pragma unroll
      for(int j=0;j<8;++j)
        *(s16x8*)(kbuf + (size_t)(row0+row)*DTD + c + j*8) = *(const s16x8*)&stile[row][c + j*8];
    }
    __syncthreads();
    #pragma unroll
    for(int rt=0;rt<4;++rt)
      #pragma unroll
      for(int nt=0;nt<4;++nt)
        #pragma unroll
        for(int i=0;i<4;++i)
          stile[rt*16 + lg*4 + i][col0 + nt*16 + lr] = f2b(accV[rt][nt][i]);
    __syncthreads();
    {
      int row = tid >> 2, c = (tid & 3)*64;
      #pragma unroll
      for(int j=0;j<8;++j)
        *(s16x8*)(vbuf + (size_t)(row0+row)*DTD + c + j*8) = *(const s16x8*)&stile[row][c + j*8];
    }
  } else {
    // Q path: 192 q-rows (3 per batch), 64 rows per block
    int qrow0 = (blockIdx.x - 257) * 64;
    int col0 = w * 64;
    int srow[4];
    #pragma unroll
    for(int rt=0;rt<4;++rt){
      int qr = qrow0 + rt*16 + lr;
      int bb = (qr * 21846) >> 16;   // qr/3 for qr<192
      int pp = qr - bb*3;
      srow[rt] = bb*257 + pp;
    }
    f32x4 acc[4][4];
    #pragma unroll
    for(int rt=0;rt<4;++rt)
      #pragma unroll
      for(int nt=0;nt<4;++nt)
        #pragma unroll
        for(int i=0;i<4;++i) acc[rt][nt][i]=0.f;
    #pragma unroll
    for(int ks=0; ks<8; ++ks){
      int kb = ks*32 + lg*8;
      s16x8 A[4], Bq[4];
      #pragma unroll
      for(int rt=0;rt<4;++rt)
        A[rt] = *(const s16x8*)(seqb + (size_t)srow[rt]*DTD + kb);
      #pragma unroll
      for(int nt=0;nt<4;++nt){
        int col = col0 + nt*16 + lr;
        Bq[nt] = *(const s16x8*)(wqT + (size_t)col*DTD + kb);
      }
      #pragma unroll
      for(int rt=0;rt<4;++rt)
        #pragma unroll
        for(int nt=0;nt<4;++nt)
          acc[rt][nt] = MF(A[rt], Bq[nt], acc[rt][nt]);
    }
    #pragma unroll
    for(int rt=0;rt<4;++rt)
      #pragma unroll
      for(int nt=0;nt<4;++nt)
        #pragma unroll
        for(int i=0;i<4;++i){
          int qr = qrow0 + rt*16 + lg*4 + i;
          int col = col0 + nt*16 + lr;
          qbuf[(size_t)qr*DTD + col] = acc[rt][nt][i];
        }
  }
}

// ============ attention: q from qbuf, QK, softmax, PV ======================
__global__ void __launch_bounds__(256)
k_att2(const float* __restrict__ qbuf,
       const unsigned short* __restrict__ kbuf, const unsigned short* __restrict__ vbuf,
       float* __restrict__ att_o){
  __shared__ float q_s[3][32];
  __shared__ float sc[3][257];
  __shared__ float ppv[8][3][32];
  int t = threadIdx.x;
  int b = blockIdx.x >> 3, h = blockIdx.x & 7;

  if(t < 96){
    int qi = t>>5, dd = t&31;
    q_s[qi][dd] = qbuf[(size_t)(b*3+qi)*DTD + h*32 + dd];
  }
  __syncthreads();
  const float scale = 0.17677669529663687f;  // 1/sqrt(32)
  for(int kk=t; kk<257; kk+=256){
    const unsigned short* kr = kbuf + (size_t)(b*257+kk)*DTD + h*32;
    float kv[32];
    #pragma unroll
    for(int j=0;j<4;++j){
      s16x8 u = *(const s16x8*)(kr + j*8);
      #pragma unroll
      for(int m2=0;m2<8;++m2) kv[j*8+m2] = b2f((unsigned short)u[m2]);
    }
    float d0=0.f,d1=0.f,d2=0.f;
    #pragma unroll
    for(int dd=0;dd<32;++dd){
      d0 += q_s[0][dd]*kv[dd]; d1 += q_s[1][dd]*kv[dd]; d2 += q_s[2][dd]*kv[dd];
    }
    sc[0][kk]=d0*scale; sc[1][kk]=d1*scale; sc[2][kk]=d2*scale;
  }
  __syncthreads();
  { // softmax: wave w handles qi=w
    int wv = t>>6, lane = t&63;
    if(wv < 3){
      int qi = wv;
      float x0=sc[qi][lane], x1=sc[qi][lane+64], x2=sc[qi][lane+128], x3=sc[qi][lane+192];
      float x4 = (lane==0)? sc[qi][256] : -1e30f;
      float m = fmaxf(fmaxf(fmaxf(x0,x1),fmaxf(x2,x3)),x4);
      #pragma unroll
      for(int off=32; off>0; off>>=1) m = fmaxf(m, __shfl_xor(m, off));
      float e0=expf(x0-m), e1=expf(x1-m), e2v=expf(x2-m), e3v=expf(x3-m);
      float e4=(lane==0)? expf(x4-m) : 0.f;
      float s = e0+e1+e2v+e3v+e4;
      #pragma unroll
      for(int off=32; off>0; off>>=1) s += __shfl_xor(s, off);
      float inv = 1.0f/s;
      sc[qi][lane]=e0*inv; sc[qi][lane+64]=e1*inv;
      sc[qi][lane+128]=e2v*inv; sc[qi][lane+192]=e3v*inv;
      if(lane==0) sc[qi][256]=e4*inv;
    }
  }
  __syncthreads();
  { // PV: 8 kk-groups
    int dd = t & 31, g = t >> 5;
    float a0=0.f, a1=0.f, a2=0.f;
    for(int kk=g; kk<257; kk+=8){
      float v = b2f(vbuf[(size_t)(b*257+kk)*DTD + h*32 + dd]);
      a0 += sc[0][kk]*v; a1 += sc[1][kk]*v; a2 += sc[2][kk]*v;
    }
    ppv[g][0][dd]=a0; ppv[g][1][dd]=a1; ppv[g][2][dd]=a2;
  }
  __syncthreads();
  if(t < 96){
    int qi = t>>5, dd = t&31;
    float s = 0.f;
    #pragma unroll
    for(int gg=0; gg<8; ++gg) s += ppv[gg][qi][dd];
    att_o[(size_t)(b*3+qi)*DTD + h*32 + dd] = s;
  }
}

// ============ output: att_o @ wo, permuted =================================
__global__ void k_out(const float* __restrict__ att_o, const float* __restrict__ wo,
                      float* __restrict__ out){
  __shared__ float srow[DTD];
  int t = threadIdx.x;
  int r = blockIdx.x;
  int b = r/3, qi = r - b*3;
  srow[t] = att_o[(size_t)r*DTD + t];
  __syncthreads();
  float acc = 0.f;
  for(int d=0; d<DTD; ++d) acc += srow[d]*wo[d*DTD + t];
  int off = (qi==1)? 0 : ((qi==2)? DTD : 2*DTD);
  out[(size_t)b*768 + off + t] = acc;
}

extern "C" void kernel_launch(void* const* d_in, const int* in_sizes, int n_in,
                              void* d_out, int out_size, void* d_ws, size_t ws_size,
                              hipStream_t stream){
  const float* x        = (const float*)d_in[0];
  const float* proj_w   = (const float*)d_in[1];
  const float* proj_b   = (const float*)d_in[2];
  const float* adj_vals = (const float*)d_in[3];
  const int*   adj_rows = (const int*)d_in[4];
  const int*   adj_cols = (const int*)d_in[5];
  const float* ppr      = (const float*)d_in[6];
  const float* drnl     = (const float*)d_in[7];
  const int*   srcI     = (const int*)d_in[8];
  const int*   dstI     = (const int*)d_in[9];
  const int*   node_idx   = (const int*)d_in[11];
  const float* enc_w1   = (const float*)d_in[12];
  const float* enc_b1   = (const float*)d_in[13];
  const float* enc_w2   = (const float*)d_in[14];
  const float* enc_b2   = (const float*)d_in[15];
  const float* sw1      = (const float*)d_in[16];
  const float* sb1      = (const float*)d_in[17];
  const float* sw2      = (const float*)d_in[18];
  const float* sb2      = (const float*)d_in[19];
  const float* cls_tok  = (const float*)d_in[20];
  const float* wq       = (const float*)d_in[21];
  const float* wk       = (const float*)d_in[22];
  const float* wv       = (const float*)d_in[23];
  const float* wo       = (const float*)d_in[24];
  float* out = (float*)d_out;

  char* p = (char*)d_ws;
  auto alloc = [&](size_t bytes)->void*{ void* r = (void*)p; p += (bytes + 63) & ~(size_t)63; return r; };
  unsigned short* featsb = (unsigned short*)alloc((size_t)NN*DD*2);
  unsigned short* h1b    = (unsigned short*)alloc((size_t)NN*DD*2);
  unsigned short* h2b    = (unsigned short*)alloc((size_t)NN*DD*2);
  unsigned short* rexb   = (unsigned short*)alloc((size_t)NN*DD*2);
  int*   cnt     = (int*)  alloc((size_t)NN*4);
  uint2* ccv     = (uint2*)alloc((size_t)NN*CAP*8);
  float* sbias   = (float*)alloc((size_t)DD*4);
  float* heurA   = (float*)alloc((size_t)NTOK*4);
  float* heurB   = (float*)alloc((size_t)NTOK*4);
  float* heurD   = (float*)alloc((size_t)NTOK*4);
  unsigned short* kbuf = (unsigned short*)alloc((size_t)NSEQ*DTD*2);
  unsigned short* vbuf = (unsigned short*)alloc((size_t)NSEQ*DTD*2);
  float* qbuf    = (float*)alloc((size_t)BB*3*DTD*4);
  float* att_o   = (float*)alloc((size_t)BB*3*DTD*4);
  unsigned short* seqb  = (unsigned short*)alloc((size_t)NSEQ*DTD*2);
  unsigned short* wqT   = (unsigned short*)alloc((size_t)DTD*DTD*2);
  unsigned short* wkT   = (unsigned short*)alloc((size_t)DTD*DTD*2);
  unsigned short* wvT   = (unsigned short*)alloc((size_t)DTD*DTD*2);
  unsigned short* w2T2  = (unsigned short*)alloc((size_t)DD*DD*2);
  unsigned short* w2T3  = (unsigned short*)alloc((size_t)DD*DD*2);
  unsigned short* sw1aT = (unsigned short*)alloc((size_t)DD*DD*2);
  unsigned short* sw1bT = (unsigned short*)alloc((size_t)DD*DD*2);
  unsigned short* sw2T  = (unsigned short*)alloc((size_t)DD*DD*2);

  hipMemsetAsync(cnt, 0, NN*sizeof(int), stream);

  k_setup   <<<SETUP_GRID, 256, 0, stream>>>(x, proj_w, proj_b, featsb,
                                             wq, wk, wv, enc_w2, sw1, sw2, cls_tok,
                                             wqT, wkT, wvT, w2T2, w2T3, sw1aT, sw1bT, sw2T, seqb,
                                             node_idx, srcI, dstI, ppr, drnl,
                                             heurA, heurB, heurD,
                                             adj_rows, adj_cols, adj_vals, cnt, ccv,
                                             enc_b1, enc_b2, sb1, sbias);
  k_spmm_w  <<<NN/4,   256, 0, stream>>>((const unsigned*)featsb, (unsigned*)h1b, cnt, ccv, (const unsigned*)featsb, 0);
  k_spmm_w  <<<NN/4,   256, 0, stream>>>((const unsigned*)h1b, (unsigned*)h2b, cnt, ccv, (const unsigned*)featsb, 0);
  k_spmm_w  <<<NN/4,   256, 0, stream>>>((const unsigned*)h2b, (unsigned*)rexb, cnt, ccv, (const unsigned*)featsb, 1);
  k_tok_mfma<<<NTOK/64,256, 0, stream>>>(node_idx, heurA, heurB, heurD,
                                         enc_w1, enc_b1, w2T2, w2T3, enc_b2,
                                         sw1aT, sw1bT, sbias, sw2T, sb2, rexb, seqb);
  k_kv_mfma <<<260,    256, 0, stream>>>(seqb, wkT, wvT, wqT, kbuf, vbuf, qbuf);
  k_att2    <<<BB*HH,  256, 0, stream>>>(qbuf, kbuf, vbuf, att_o);
  k_out     <<<BB*3,   256, 0, stream>>>(att_o, wo, out);
}

// Round 8
// 155.745 us; speedup vs baseline: 2.6723x; 1.0631x over previous
//
#include <hip/hip_runtime.h>
#include <math.h>

#define NN 12288      // nodes
#define FD 128        // input feat dim
#define DD 128        // D
#define EE 393216     // edges
#define BB 64         // batch
#define LL 256        // tokens per sample
#define HH 8          // heads
#define DTD 256       // DT = 2*D
#define NTOK 16384    // B*L
#define CAP 128       // max row degree capacity (mean 32)

// k_setup block ranges
#define PROJ_B0 1536   // scatter: [0,1536)
#define PREP_B0 1728   // proj MFMA: [1536,1728)
#define HEUR_B0 2816   // prep: [1728,2816)
#define SBIAS_B 2880   // heur: [2816,2880); sbias: 2880; cls: 2881
#define CLS_B   2881
#define SETUP_GRID 2882

// LDS strides in u16 — multiples of 8 (16 B) so every s16x8 access is
// 16-B aligned (ds_*_b128).
#define SEQ_ST 272
#define STG_ST 272

typedef float f32x4 __attribute__((ext_vector_type(4)));
typedef short s16x8 __attribute__((ext_vector_type(8)));

__device__ __forceinline__ float relu_(float x){ return fmaxf(x, 0.0f); }

__device__ __forceinline__ unsigned short f2b(float f){
  unsigned int u = __float_as_uint(f);
  u += 0x7FFFu + ((u >> 16) & 1u);
  return (unsigned short)(u >> 16);
}
__device__ __forceinline__ float b2f(unsigned short h){
  return __uint_as_float(((unsigned int)h) << 16);
}

__device__ __forceinline__ f32x4 MF(s16x8 a, s16x8 b, f32x4 c){
  return __builtin_amdgcn_mfma_f32_16x16x32_bf16(a, b, c, 0, 0, 0);
}

// ===== kernel A: scatter | proj(MFMA) | prep | heur | sbias | cls qkv ======
__global__ void __launch_bounds__(256)
k_setup(const float* __restrict__ x, const float* __restrict__ proj_w,
        const float* __restrict__ proj_b, unsigned short* __restrict__ featsb,
        const float* __restrict__ wq, const float* __restrict__ wk,
        const float* __restrict__ wv,
        const float* __restrict__ enc_w2, const float* __restrict__ sw1,
        const float* __restrict__ sw2, const float* __restrict__ cls_tok,
        unsigned short* __restrict__ wqT, unsigned short* __restrict__ wkT,
        unsigned short* __restrict__ wvT,
        unsigned short* __restrict__ w2T2, unsigned short* __restrict__ w2T3,
        unsigned short* __restrict__ sw1aT, unsigned short* __restrict__ sw1bT,
        unsigned short* __restrict__ sw2T,
        const int* __restrict__ node_idx, const int* __restrict__ srcI,
        const int* __restrict__ dstI, const float* __restrict__ ppr,
        const float* __restrict__ drnl, float* __restrict__ heurA,
        float* __restrict__ heurB, float* __restrict__ heurD,
        const int* __restrict__ adj_rows, const int* __restrict__ adj_cols,
        const float* __restrict__ adj_vals, int* __restrict__ cnt,
        uint2* __restrict__ ccv,
        const float* __restrict__ enc_b1, const float* __restrict__ enc_b2,
        const float* __restrict__ sb1, float* __restrict__ sbias,
        float* __restrict__ qcls, unsigned short* __restrict__ kcls,
        unsigned short* __restrict__ vcls){
  int t = threadIdx.x;
  if(blockIdx.x < PROJ_B0){
    // ---- scatter: bump-allocate edges into row buckets ----
    int e = blockIdx.x*256 + t;
    int r = adj_rows[e];
    int p = atomicAdd(&cnt[r], 1);
    ccv[(size_t)r*CAP + p] = make_uint2((unsigned)adj_cols[e], __float_as_uint(adj_vals[e]));
  } else if(blockIdx.x < PREP_B0){
    // ---- proj via MFMA ----
    int bid = blockIdx.x - PROJ_B0;
    int row0 = bid * 64;
    int lane = t & 63, w = t >> 6;
    int lr = lane & 15, lg = lane >> 4;
    f32x4 acc[4][2];
    #pragma unroll
    for(int nt=0;nt<2;++nt){
      int col = w*32 + nt*16 + lr;
      float bv = proj_b[col];
      #pragma unroll
      for(int rt=0;rt<4;++rt)
        #pragma unroll
        for(int i=0;i<4;++i) acc[rt][nt][i]=bv;
    }
    #pragma unroll
    for(int ks=0; ks<4; ++ks){
      int kb = ks*32 + lg*8;
      s16x8 Bf[2];
      #pragma unroll
      for(int nt=0;nt<2;++nt){
        int col = w*32 + nt*16 + lr;
        #pragma unroll
        for(int i=0;i<8;++i) Bf[nt][i] = (short)f2b(proj_w[(kb+i)*DD + col]);
      }
      #pragma unroll
      for(int rt=0;rt<4;++rt){
        int row = row0 + rt*16 + lr;
        const f32x4* xp = (const f32x4*)(x + (size_t)row*FD + kb);
        f32x4 v0 = xp[0], v1 = xp[1];
        s16x8 Af;
        #pragma unroll
        for(int i=0;i<4;++i){ Af[i] = (short)f2b(v0[i]); Af[4+i] = (short)f2b(v1[i]); }
        #pragma unroll
        for(int nt=0;nt<2;++nt) acc[rt][nt] = MF(Af, Bf[nt], acc[rt][nt]);
      }
    }
    #pragma unroll
    for(int rt=0;rt<4;++rt)
      #pragma unroll
      for(int nt=0;nt<2;++nt)
        #pragma unroll
        for(int i=0;i<4;++i){
          int row = row0 + rt*16 + lg*4 + i;
          int col = w*32 + nt*16 + lr;
          featsb[(size_t)row*DD + col] = f2b(acc[rt][nt][i]);
        }
  } else if(blockIdx.x < HEUR_B0){
    // ---- prep: weight transposes to bf16 [out][k] ----
    int id = (blockIdx.x - PREP_B0)*256 + t;
    if(id < 196608){
      int m = id >> 16, e = id & 65535;
      int n = e & 255, k = e >> 8;
      const float* s = (m==0)? wq : (m==1)? wk : wv;
      unsigned short* d = (m==0)? wqT : (m==1)? wkT : wvT;
      d[n*256 + k] = f2b(s[k*256 + n]);
    } else {
      int id2 = id - 196608;
      int m = id2 >> 14, e = id2 & 16383;
      int n = e & 127, k = e >> 7;
      const float* s;
      unsigned short* d;
      if(m==0){ s = enc_w2 + 2*16384; d = w2T2; }
      else if(m==1){ s = enc_w2 + 3*16384; d = w2T3; }
      else if(m==2){ s = sw1 + 256*128; d = sw1aT; }
      else if(m==3){ s = sw1 + 384*128; d = sw1bT; }
      else { s = sw2; d = sw2T; }
      d[n*128 + k] = f2b(s[k*128 + n]);
    }
  } else if(blockIdx.x < SBIAS_B){
    // ---- heur gathers ----
    int tt = (blockIdx.x - HEUR_B0)*256 + t;
    int s = tt >> 8;
    int node = node_idx[tt];
    heurA[tt] = ppr[(size_t)srcI[s]*NN + node];
    heurB[tt] = ppr[(size_t)dstI[s]*NN + node];
    heurD[tt] = drnl[(size_t)s*NN + node];
  } else if(blockIdx.x == SBIAS_B){
    // ---- sbias fold ----
    __shared__ float h0[DD], h1[DD], e0[DD], e1[DD];
    if(t < DD){
      h0[t] = relu_(enc_b1[0*DD+t]);
      h1[t] = relu_(enc_b1[1*DD+t]);
    }
    __syncthreads();
    if(t < DD){
      float a0 = enc_b2[0*DD+t], a1 = enc_b2[1*DD+t];
      for(int d=0; d<DD; ++d){
        a0 += h0[d]*enc_w2[(0*DD+d)*DD + t];
        a1 += h1[d]*enc_w2[(1*DD+d)*DD + t];
      }
      e0[t]=a0; e1[t]=a1;
    }
    __syncthreads();
    if(t < DD){
      float sv = sb1[t];
      for(int d=0; d<DD; ++d)
        sv += e0[d]*sw1[d*DD + t] + e1[d]*sw1[(DD+d)*DD + t];
      sbias[t]=sv;
    }
  } else {
    // ---- cls q/k/v (batch-independent, computed once) ----
    __shared__ float scls[DTD];
    scls[t] = cls_tok[t];
    __syncthreads();
    float aq=0.f, ak=0.f, av=0.f;
    for(int d=0; d<DTD; ++d){
      float cv = scls[d];
      aq += cv*wq[d*DTD + t];
      ak += cv*wk[d*DTD + t];
      av += cv*wv[d*DTD + t];
    }
    qcls[t] = aq;
    kcls[t] = f2b(ak);
    vcls[t] = f2b(av);
  }
}

// ============ pull SpMM: one wave per row, unroll-4, bucketed CSR ==========
__global__ void __launch_bounds__(256)
k_spmm_w(const unsigned int* __restrict__ hin32, unsigned int* __restrict__ hout32,
         const int* __restrict__ cnt, const uint2* __restrict__ ccv,
         const unsigned int* __restrict__ featsb32, int finalpass){
  int lane = threadIdx.x & 63;
  int r = blockIdx.x*4 + (threadIdx.x>>6);
  int deg = cnt[r];
  const uint2* base = ccv + (size_t)r*CAP;
  float a0=0.f,a1=0.f,b0=0.f,b1=0.f,c0=0.f,c1=0.f,d0=0.f,d1=0.f;
  int p = 0;
  for(; p+4 <= deg; p += 4){
    uint2 q0 = base[p], q1 = base[p+1], q2 = base[p+2], q3 = base[p+3];
    unsigned u0 = hin32[(size_t)q0.x*64 + lane];
    unsigned u1 = hin32[(size_t)q1.x*64 + lane];
    unsigned u2 = hin32[(size_t)q2.x*64 + lane];
    unsigned u3 = hin32[(size_t)q3.x*64 + lane];
    float v0=__uint_as_float(q0.y), v1=__uint_as_float(q1.y);
    float v2=__uint_as_float(q2.y), v3=__uint_as_float(q3.y);
    a0 += v0*b2f((unsigned short)(u0&0xffffu)); a1 += v0*b2f((unsigned short)(u0>>16));
    b0 += v1*b2f((unsigned short)(u1&0xffffu)); b1 += v1*b2f((unsigned short)(u1>>16));
    c0 += v2*b2f((unsigned short)(u2&0xffffu)); c1 += v2*b2f((unsigned short)(u2>>16));
    d0 += v3*b2f((unsigned short)(u3&0xffffu)); d1 += v3*b2f((unsigned short)(u3>>16));
  }
  for(; p < deg; ++p){
    uint2 q0 = base[p];
    unsigned u0 = hin32[(size_t)q0.x*64 + lane];
    float v0 = __uint_as_float(q0.y);
    a0 += v0*b2f((unsigned short)(u0&0xffffu)); a1 += v0*b2f((unsigned short)(u0>>16));
  }
  a0 += b0 + c0 + d0;
  a1 += b1 + c1 + d1;
  if(finalpass){
    unsigned f = featsb32[(size_t)r*64 + lane];
    a0 = 0.5f*a0 + 0.5f*b2f((unsigned short)(f & 0xffffu));
    a1 = 0.5f*a1 + 0.5f*b2f((unsigned short)(f >> 16));
  }
  hout32[(size_t)r*64 + lane] = (unsigned)f2b(a0) | ((unsigned)f2b(a1) << 16);
}

// ====== fused token MLP + K/V GEMM + Q (src/dst): 64 tokens/block ==========
__global__ void __launch_bounds__(256)
k_tok_kv(const int* __restrict__ node_idx,
         const float* __restrict__ heurA, const float* __restrict__ heurB,
         const float* __restrict__ heurD,
         const float* __restrict__ enc_w1, const float* __restrict__ enc_b1,
         const unsigned short* __restrict__ w2T2, const unsigned short* __restrict__ w2T3,
         const float* __restrict__ enc_b2,
         const unsigned short* __restrict__ sw1aT, const unsigned short* __restrict__ sw1bT,
         const float* __restrict__ sbias,
         const unsigned short* __restrict__ sw2T, const float* __restrict__ sb2,
         const unsigned short* __restrict__ rexb,
         const unsigned short* __restrict__ wkT, const unsigned short* __restrict__ wvT,
         const unsigned short* __restrict__ wqT,
         unsigned short* __restrict__ kbuf, unsigned short* __restrict__ vbuf,
         float* __restrict__ qbuf){
  __shared__ float sA[64], sB[64], sDV[64];
  __shared__ int sNode[64];
  // hid is FLAT (bug fix: R6/R7 mixed 2-D decl with flat indexing in the
  // GEMM3 read -> OOB LDS read -> NaN)
  __shared__ __align__(16) unsigned short hid[64*136];
  // union region: e2[64][136] + e3[64][136] | seq[64][272] | stage[64][272]
  __shared__ __align__(16) unsigned short uni[64*STG_ST];
  unsigned short* pe2 = uni;            // flat [64*136]
  unsigned short* pe3 = uni + 64*136;   // flat [64*136]
  unsigned short* seq = uni;            // flat [64*SEQ_ST]
  unsigned short* stg = uni;            // flat [64*STG_ST]

  int tid = threadIdx.x;
  int lane = tid & 63;
  int w = tid >> 6;
  int lr = lane & 15;
  int lg = lane >> 4;
  int t0 = blockIdx.x * 64;     // global token base
  int bs = t0 >> 8;
  int p0 = t0 & 255;

  if(tid < 64){
    int tt = t0 + tid;
    sNode[tid] = node_idx[tt];
    sA[tid]  = heurA[tt];
    sB[tid]  = heurB[tt];
    sDV[tid] = heurD[tt];
  }
  __syncthreads();

  // GEMM1: enc2/enc3
  {
    f32x4 acc2[4][2], acc3[4][2];
    #pragma unroll
    for(int nt=0;nt<2;++nt){
      int col = w*32 + nt*16 + lr;
      float b2v = enc_b2[2*DD + col];
      float b3v = enc_b2[3*DD + col];
      #pragma unroll
      for(int rt=0;rt<4;++rt)
        #pragma unroll
        for(int i=0;i<4;++i){ acc2[rt][nt][i]=b2v; acc3[rt][nt][i]=b3v; }
    }
    #pragma unroll
    for(int ks=0; ks<4; ++ks){
      int kb = ks*32 + lg*8;
      float w20[8], w21[8], w3s[8], b2c[8], b3c[8];
      #pragma unroll
      for(int i=0;i<8;++i){
        int k = kb + i;
        w20[i] = enc_w1[4*DD + k];
        w21[i] = enc_w1[5*DD + k];
        w3s[i] = enc_w1[6*DD + k] + enc_w1[7*DD + k];
        b2c[i] = enc_b1[2*DD + k];
        b3c[i] = enc_b1[3*DD + k];
      }
      s16x8 B2[2], B3[2];
      #pragma unroll
      for(int nt=0;nt<2;++nt){
        int col = w*32 + nt*16 + lr;
        B2[nt] = *(const s16x8*)(w2T2 + col*DD + kb);
        B3[nt] = *(const s16x8*)(w2T3 + col*DD + kb);
      }
      #pragma unroll
      for(int rt=0;rt<4;++rt){
        int row = rt*16 + lr;
        float a = sA[row], b = sB[row], dv = sDV[row];
        s16x8 A2, A3;
        #pragma unroll
        for(int i=0;i<8;++i){
          A2[i] = (short)f2b(relu_(a*w20[i] + b*w21[i] + b2c[i]));
          A3[i] = (short)f2b(relu_(dv*w3s[i] + b3c[i]));
        }
        #pragma unroll
        for(int nt=0;nt<2;++nt){
          acc2[rt][nt] = MF(A2, B2[nt], acc2[rt][nt]);
          acc3[rt][nt] = MF(A3, B3[nt], acc3[rt][nt]);
        }
      }
    }
    #pragma unroll
    for(int rt=0;rt<4;++rt)
      #pragma unroll
      for(int nt=0;nt<2;++nt)
        #pragma unroll
        for(int i=0;i<4;++i){
          int row = rt*16 + lg*4 + i;
          int col = w*32 + nt*16 + lr;
          pe2[row*136 + col] = f2b(acc2[rt][nt][i]);
          pe3[row*136 + col] = f2b(acc3[rt][nt][i]);
        }
  }
  __syncthreads();

  // GEMM2: hidden = relu(sbias + e2@SW1a + e3@SW1b)
  {
    f32x4 acc[4][2];
    #pragma unroll
    for(int nt=0;nt<2;++nt){
      int col = w*32 + nt*16 + lr;
      float sv = sbias[col];
      #pragma unroll
      for(int rt=0;rt<4;++rt)
        #pragma unroll
        for(int i=0;i<4;++i) acc[rt][nt][i]=sv;
    }
    #pragma unroll
    for(int ks=0; ks<4; ++ks){
      int kb = ks*32 + lg*8;
      s16x8 Ba[2], Bb[2];
      #pragma unroll
      for(int nt=0;nt<2;++nt){
        int col = w*32 + nt*16 + lr;
        Ba[nt] = *(const s16x8*)(sw1aT + col*DD + kb);
        Bb[nt] = *(const s16x8*)(sw1bT + col*DD + kb);
      }
      #pragma unroll
      for(int rt=0;rt<4;++rt){
        s16x8 A2 = *(const s16x8*)&pe2[(rt*16+lr)*136 + kb];
        s16x8 A3 = *(const s16x8*)&pe3[(rt*16+lr)*136 + kb];
        #pragma unroll
        for(int nt=0;nt<2;++nt){
          acc[rt][nt] = MF(A2, Ba[nt], acc[rt][nt]);
          acc[rt][nt] = MF(A3, Bb[nt], acc[rt][nt]);
        }
      }
    }
    __syncthreads();   // e2/e3 reads complete -> union region reusable
    #pragma unroll
    for(int rt=0;rt<4;++rt)
      #pragma unroll
      for(int nt=0;nt<2;++nt)
        #pragma unroll
        for(int i=0;i<4;++i){
          int row = rt*16 + lg*4 + i;
          int col = w*32 + nt*16 + lr;
          hid[row*136 + col] = f2b(relu_(acc[rt][nt][i]));
        }
  }
  __syncthreads();

  // GEMM3: struct_out -> seq[:,0:128] ; re_x gather -> seq[:,128:256]
  {
    f32x4 acc[4][2];
    #pragma unroll
    for(int nt=0;nt<2;++nt){
      int col = w*32 + nt*16 + lr;
      float bv = sb2[col];
      #pragma unroll
      for(int rt=0;rt<4;++rt)
        #pragma unroll
        for(int i=0;i<4;++i) acc[rt][nt][i]=bv;
    }
    #pragma unroll
    for(int ks=0; ks<4; ++ks){
      int kb = ks*32 + lg*8;
      s16x8 Bc[2];
      #pragma unroll
      for(int nt=0;nt<2;++nt){
        int col = w*32 + nt*16 + lr;
        Bc[nt] = *(const s16x8*)(sw2T + col*DD + kb);
      }
      #pragma unroll
      for(int rt=0;rt<4;++rt){
        s16x8 A = *(const s16x8*)&hid[(rt*16+lr)*136 + kb];
        #pragma unroll
        for(int nt=0;nt<2;++nt) acc[rt][nt] = MF(A, Bc[nt], acc[rt][nt]);
      }
    }
    #pragma unroll
    for(int rt=0;rt<4;++rt)
      #pragma unroll
      for(int nt=0;nt<2;++nt)
        #pragma unroll
        for(int i=0;i<4;++i){
          int row = rt*16 + lg*4 + i;
          int col = w*32 + nt*16 + lr;
          seq[row*SEQ_ST + col] = f2b(acc[rt][nt][i]);
        }
    // re_x gather (16-B aligned: row*544 + 256 + 16k)
    int row = tid >> 2, l4 = tid & 3;
    int c = l4 * 32;
    int node = sNode[row];
    const unsigned short* rp = rexb + (size_t)node*DD + c;
    #pragma unroll
    for(int j=0;j<4;++j)
      *(s16x8*)(seq + row*SEQ_ST + DD + c + j*8) = *(const s16x8*)(rp + j*8);
  }
  __syncthreads();

  // K,V GEMM from LDS seq; Q for rows 0,1 if this block owns tokens 0,1
  f32x4 accK[4][4], accV[4][4];
  {
    #pragma unroll
    for(int rt=0;rt<4;++rt)
      #pragma unroll
      for(int nt=0;nt<4;++nt)
        #pragma unroll
        for(int i=0;i<4;++i){ accK[rt][nt][i]=0.f; accV[rt][nt][i]=0.f; }
    int col0 = w * 64;
    #pragma unroll
    for(int ks=0; ks<8; ++ks){
      int kb = ks*32 + lg*8;
      s16x8 A[4], Bk[4], Bv[4];
      #pragma unroll
      for(int rt=0;rt<4;++rt)
        A[rt] = *(const s16x8*)&seq[(rt*16+lr)*SEQ_ST + kb];
      #pragma unroll
      for(int nt=0;nt<4;++nt){
        int col = col0 + nt*16 + lr;
        Bk[nt] = *(const s16x8*)(wkT + (size_t)col*DTD + kb);
        Bv[nt] = *(const s16x8*)(wvT + (size_t)col*DTD + kb);
      }
      #pragma unroll
      for(int rt=0;rt<4;++rt)
        #pragma unroll
        for(int nt=0;nt<4;++nt){
          accK[rt][nt] = MF(A[rt], Bk[nt], accK[rt][nt]);
          accV[rt][nt] = MF(A[rt], Bv[nt], accV[rt][nt]);
        }
    }
  }
  if(p0 == 0){
    // Q for src (row0) and dst (row1): q = seq_row @ wq
    #pragma unroll
    for(int qi=0; qi<2; ++qi){
      int col = w*64 + lane;
      float acc = 0.f;
      for(int d=0; d<DTD; d+=8){
        s16x8 wv8 = *(const s16x8*)(wqT + (size_t)col*DTD + d);
        #pragma unroll
        for(int j=0;j<8;++j)
          acc += b2f(seq[qi*SEQ_ST + d + j]) * b2f((unsigned short)wv8[j]);
      }
      qbuf[(size_t)(bs*2+qi)*DTD + col] = acc;
    }
  }
  __syncthreads();   // all seq reads done -> stage region reusable

  // stage K -> coalesced store
  {
    int col0 = w * 64;
    #pragma unroll
    for(int rt=0;rt<4;++rt)
      #pragma unroll
      for(int nt=0;nt<4;++nt)
        #pragma unroll
        for(int i=0;i<4;++i)
          stg[(rt*16 + lg*4 + i)*STG_ST + col0 + nt*16 + lr] = f2b(accK[rt][nt][i]);
  }
  __syncthreads();
  {
    int row = tid >> 2, c = (tid & 3)*64;
    #pragma unroll
    for(int j=0;j<8;++j)
      *(s16x8*)(kbuf + (size_t)(t0+row)*DTD + c + j*8) = *(const s16x8*)&stg[row*STG_ST + c + j*8];
  }
  __syncthreads();
  {
    int col0 = w * 64;
    #pragma unroll
    for(int rt=0;rt<4;++rt)
      #pragma unroll
      for(int nt=0;nt<4;++nt)
        #pragma unroll
        for(int i=0;i<4;++i)
          stg[(rt*16 + lg*4 + i)*STG_ST + col0 + nt*16 + lr] = f2b(accV[rt][nt][i]);
  }
  __syncthreads();
  {
    int row = tid >> 2, c = (tid & 3)*64;
    #pragma unroll
    for(int j=0;j<8;++j)
      *(s16x8*)(vbuf + (size_t)(t0+row)*DTD + c + j*8) = *(const s16x8*)&stg[row*STG_ST + c + j*8];
  }
}

// ============ attention: kk=0 is cls (from cls bufs), 1..256 tokens ========
__global__ void __launch_bounds__(256)
k_att2(const float* __restrict__ qcls, const float* __restrict__ qbuf,
       const unsigned short* __restrict__ kcls, const unsigned short* __restrict__ vcls,
       const unsigned short* __restrict__ kbuf, const unsigned short* __restrict__ vbuf,
       float* __restrict__ att_o){
  __shared__ float q_s[3][32];
  __shared__ float sc[3][257];
  __shared__ float ppv[8][3][32];
  int t = threadIdx.x;
  int b = blockIdx.x >> 3, h = blockIdx.x & 7;

  if(t < 96){
    int qi = t>>5, dd = t&31;
    q_s[qi][dd] = (qi==0) ? qcls[h*32 + dd]
                          : qbuf[(size_t)(b*2+qi-1)*DTD + h*32 + dd];
  }
  __syncthreads();
  const float scale = 0.17677669529663687f;  // 1/sqrt(32)
  for(int kk=t; kk<257; kk+=256){
    const unsigned short* kr = (kk==0) ? (kcls + h*32)
                                       : (kbuf + (size_t)(b*256+kk-1)*DTD + h*32);
    float kv[32];
    #pragma unroll
    for(int j=0;j<4;++j){
      s16x8 u = *(const s16x8*)(kr + j*8);
      #pragma unroll
      for(int m2=0;m2<8;++m2) kv[j*8+m2] = b2f((unsigned short)u[m2]);
    }
    float d0=0.f,d1=0.f,d2=0.f;
    #pragma unroll
    for(int dd=0;dd<32;++dd){
      d0 += q_s[0][dd]*kv[dd]; d1 += q_s[1][dd]*kv[dd]; d2 += q_s[2][dd]*kv[dd];
    }
    sc[0][kk]=d0*scale; sc[1][kk]=d1*scale; sc[2][kk]=d2*scale;
  }
  __syncthreads();
  { // softmax: wave w handles qi=w
    int wv = t>>6, lane = t&63;
    if(wv < 3){
      int qi = wv;
      float x0=sc[qi][lane], x1=sc[qi][lane+64], x2=sc[qi][lane+128], x3=sc[qi][lane+192];
      float x4 = (lane==0)? sc[qi][256] : -1e30f;
      float m = fmaxf(fmaxf(fmaxf(x0,x1),fmaxf(x2,x3)),x4);
      #pragma unroll
      for(int off=32; off>0; off>>=1) m = fmaxf(m, __shfl_xor(m, off));
      float e0=expf(x0-m), e1=expf(x1-m), e2v=expf(x2-m), e3v=expf(x3-m);
      float e4=(lane==0)? expf(x4-m) : 0.f;
      float s = e0+e1+e2v+e3v+e4;
      #pragma unroll
      for(int off=32; off>0; off>>=1) s += __shfl_xor(s, off);
      float inv = 1.0f/s;
      sc[qi][lane]=e0*inv; sc[qi][lane+64]=e1*inv;
      sc[qi][lane+128]=e2v*inv; sc[qi][lane+192]=e3v*inv;
      if(lane==0) sc[qi][256]=e4*inv;
    }
  }
  __syncthreads();
  { // PV: 8 kk-groups
    int dd = t & 31, g = t >> 5;
    float a0=0.f, a1=0.f, a2=0.f;
    for(int kk=g; kk<257; kk+=8){
      const unsigned short* vr = (kk==0) ? (vcls + h*32)
                                         : (vbuf + (size_t)(b*256+kk-1)*DTD + h*32);
      float v = b2f(vr[dd]);
      a0 += sc[0][kk]*v; a1 += sc[1][kk]*v; a2 += sc[2][kk]*v;
    }
    ppv[g][0][dd]=a0; ppv[g][1][dd]=a1; ppv[g][2][dd]=a2;
  }
  __syncthreads();
  if(t < 96){
    int qi = t>>5, dd = t&31;
    float s = 0.f;
    #pragma unroll
    for(int gg=0; gg<8; ++gg) s += ppv[gg][qi][dd];
    att_o[(size_t)(b*3+qi)*DTD + h*32 + dd] = s;
  }
}

// ============ output: att_o @ wo, permuted =================================
__global__ void k_out(const float* __restrict__ att_o, const float* __restrict__ wo,
                      float* __restrict__ out){
  __shared__ float srow[DTD];
  int t = threadIdx.x;
  int r = blockIdx.x;
  int b = r/3, qi = r - b*3;
  srow[t] = att_o[(size_t)r*DTD + t];
  __syncthreads();
  float acc = 0.f;
  for(int d=0; d<DTD; ++d) acc += srow[d]*wo[d*DTD + t];
  int off = (qi==1)? 0 : ((qi==2)? DTD : 2*DTD);
  out[(size_t)b*768 + off + t] = acc;
}

extern "C" void kernel_launch(void* const* d_in, const int* in_sizes, int n_in,
                              void* d_out, int out_size, void* d_ws, size_t ws_size,
                              hipStream_t stream){
  const float* x        = (const float*)d_in[0];
  const float* proj_w   = (const float*)d_in[1];
  const float* proj_b   = (const float*)d_in[2];
  const float* adj_vals = (const float*)d_in[3];
  const int*   adj_rows = (const int*)d_in[4];
  const int*   adj_cols = (const int*)d_in[5];
  const float* ppr      = (const float*)d_in[6];
  const float* drnl     = (const float*)d_in[7];
  const int*   srcI     = (const int*)d_in[8];
  const int*   dstI     = (const int*)d_in[9];
  const int*   node_idx   = (const int*)d_in[11];
  const float* enc_w1   = (const float*)d_in[12];
  const float* enc_b1   = (const float*)d_in[13];
  const float* enc_w2   = (const float*)d_in[14];
  const float* enc_b2   = (const float*)d_in[15];
  const float* sw1      = (const float*)d_in[16];
  const float* sb1      = (const float*)d_in[17];
  const float* sw2      = (const float*)d_in[18];
  const float* sb2      = (const float*)d_in[19];
  const float* cls_tok  = (const float*)d_in[20];
  const float* wq       = (const float*)d_in[21];
  const float* wk       = (const float*)d_in[22];
  const float* wv       = (const float*)d_in[23];
  const float* wo       = (const float*)d_in[24];
  float* out = (float*)d_out;

  char* p = (char*)d_ws;
  auto alloc = [&](size_t bytes)->void*{ void* r = (void*)p; p += (bytes + 63) & ~(size_t)63; return r; };
  unsigned short* featsb = (unsigned short*)alloc((size_t)NN*DD*2);
  unsigned short* h1b    = (unsigned short*)alloc((size_t)NN*DD*2);
  unsigned short* h2b    = (unsigned short*)alloc((size_t)NN*DD*2);
  unsigned short* rexb   = (unsigned short*)alloc((size_t)NN*DD*2);
  int*   cnt     = (int*)  alloc((size_t)NN*4);
  uint2* ccv     = (uint2*)alloc((size_t)NN*CAP*8);
  float* sbias   = (float*)alloc((size_t)DD*4);
  float* heurA   = (float*)alloc((size_t)NTOK*4);
  float* heurB   = (float*)alloc((size_t)NTOK*4);
  float* heurD   = (float*)alloc((size_t)NTOK*4);
  unsigned short* kbuf = (unsigned short*)alloc((size_t)NTOK*DTD*2);
  unsigned short* vbuf = (unsigned short*)alloc((size_t)NTOK*DTD*2);
  float* qbuf    = (float*)alloc((size_t)BB*2*DTD*4);
  float* qcls    = (float*)alloc((size_t)DTD*4);
  unsigned short* kcls = (unsigned short*)alloc((size_t)DTD*2);
  unsigned short* vcls = (unsigned short*)alloc((size_t)DTD*2);
  float* att_o   = (float*)alloc((size_t)BB*3*DTD*4);
  unsigned short* wqT   = (unsigned short*)alloc((size_t)DTD*DTD*2);
  unsigned short* wkT   = (unsigned short*)alloc((size_t)DTD*DTD*2);
  unsigned short* wvT   = (unsigned short*)alloc((size_t)DTD*DTD*2);
  unsigned short* w2T2  = (unsigned short*)alloc((size_t)DD*DD*2);
  unsigned short* w2T3  = (unsigned short*)alloc((size_t)DD*DD*2);
  unsigned short* sw1aT = (unsigned short*)alloc((size_t)DD*DD*2);
  unsigned short* sw1bT = (unsigned short*)alloc((size_t)DD*DD*2);
  unsigned short* sw2T  = (unsigned short*)alloc((size_t)DD*DD*2);

  hipMemsetAsync(cnt, 0, NN*sizeof(int), stream);

  k_setup  <<<SETUP_GRID, 256, 0, stream>>>(x, proj_w, proj_b, featsb,
                                            wq, wk, wv, enc_w2, sw1, sw2, cls_tok,
                                            wqT, wkT, wvT, w2T2, w2T3, sw1aT, sw1bT, sw2T,
                                            node_idx, srcI, dstI, ppr, drnl,
                                            heurA, heurB, heurD,
                                            adj_rows, adj_cols, adj_vals, cnt, ccv,
                                            enc_b1, enc_b2, sb1, sbias,
                                            qcls, kcls, vcls);
  k_spmm_w <<<NN/4,   256, 0, stream>>>((const unsigned*)featsb, (unsigned*)h1b, cnt, ccv, (const unsigned*)featsb, 0);
  k_spmm_w <<<NN/4,   256, 0, stream>>>((const unsigned*)h1b, (unsigned*)h2b, cnt, ccv, (const unsigned*)featsb, 0);
  k_spmm_w <<<NN/4,   256, 0, stream>>>((const unsigned*)h2b, (unsigned*)rexb, cnt, ccv, (const unsigned*)featsb, 1);
  k_tok_kv <<<NTOK/64,256, 0, stream>>>(node_idx, heurA, heurB, heurD,
                                        enc_w1, enc_b1, w2T2, w2T3, enc_b2,
                                        sw1aT, sw1bT, sbias, sw2T, sb2, rexb,
                                        wkT, wvT, wqT, kbuf, vbuf, qbuf);
  k_att2   <<<BB*HH,  256, 0, stream>>>(qcls, qbuf, kcls, vcls, kbuf, vbuf, att_o);
  k_out    <<<BB*3,   256, 0, stream>>>(att_o, wo, out);
}

// Round 9
// 154.175 us; speedup vs baseline: 2.6995x; 1.0102x over previous
//
#include <hip/hip_runtime.h>
#include <math.h>

#define NN 12288      // nodes
#define FD 128        // input feat dim
#define DD 128        // D
#define EE 393216     // edges
#define BB 64         // batch
#define LL 256        // tokens per sample
#define HH 8          // heads
#define DTD 256       // DT = 2*D
#define NTOK 16384    // B*L
#define CAP 128       // max row degree capacity (mean 32)

// k_setup block ranges
#define PROJ_B0 1536   // scatter: [0,1536)
#define PREP_B0 1728   // proj MFMA: [1536,1728)
#define HEUR_B0 1796   // prep tiles: [1728,1796)
#define SBIAS_B 1860   // heur: [1796,1860); sbias: 1860; cls: 1861
#define CLS_B   1861
#define SETUP_GRID 1862

// LDS strides in u16 — multiples of 8 (16 B) so every s16x8 access is
// 16-B aligned (ds_*_b128).
#define SEQ_ST 272
#define STG_ST 272

typedef float f32x4 __attribute__((ext_vector_type(4)));
typedef short s16x8 __attribute__((ext_vector_type(8)));

__device__ __forceinline__ float relu_(float x){ return fmaxf(x, 0.0f); }

__device__ __forceinline__ unsigned short f2b(float f){
  unsigned int u = __float_as_uint(f);
  u += 0x7FFFu + ((u >> 16) & 1u);
  return (unsigned short)(u >> 16);
}
__device__ __forceinline__ float b2f(unsigned short h){
  return __uint_as_float(((unsigned int)h) << 16);
}

__device__ __forceinline__ f32x4 MF(s16x8 a, s16x8 b, f32x4 c){
  return __builtin_amdgcn_mfma_f32_16x16x32_bf16(a, b, c, 0, 0, 0);
}

// ===== kernel A: scatter | proj(MFMA) | prep-tiles | heur | sbias | cls =====
__global__ void __launch_bounds__(256)
k_setup(const float* __restrict__ x, const float* __restrict__ proj_w,
        const float* __restrict__ proj_b, unsigned short* __restrict__ featsb,
        const float* __restrict__ wq, const float* __restrict__ wk,
        const float* __restrict__ wv,
        const float* __restrict__ enc_w2, const float* __restrict__ sw1,
        const float* __restrict__ sw2, const float* __restrict__ cls_tok,
        unsigned short* __restrict__ wqT, unsigned short* __restrict__ wkT,
        unsigned short* __restrict__ wvT,
        unsigned short* __restrict__ w2T2, unsigned short* __restrict__ w2T3,
        unsigned short* __restrict__ sw1aT, unsigned short* __restrict__ sw1bT,
        unsigned short* __restrict__ sw2T,
        const int* __restrict__ node_idx, const int* __restrict__ srcI,
        const int* __restrict__ dstI, const float* __restrict__ ppr,
        const float* __restrict__ drnl, float* __restrict__ heurA,
        float* __restrict__ heurB, float* __restrict__ heurD,
        const int* __restrict__ adj_rows, const int* __restrict__ adj_cols,
        const float* __restrict__ adj_vals, int* __restrict__ cnt,
        uint2* __restrict__ ccv,
        const float* __restrict__ enc_b1, const float* __restrict__ enc_b2,
        const float* __restrict__ sb1, float* __restrict__ sbias,
        float* __restrict__ qcls, unsigned short* __restrict__ kcls,
        unsigned short* __restrict__ vcls){
  int t = threadIdx.x;
  if(blockIdx.x < PROJ_B0){
    // ---- scatter: bump-allocate edges into row buckets ----
    int e = blockIdx.x*256 + t;
    int r = adj_rows[e];
    int p = atomicAdd(&cnt[r], 1);
    ccv[(size_t)r*CAP + p] = make_uint2((unsigned)adj_cols[e], __float_as_uint(adj_vals[e]));
  } else if(blockIdx.x < PREP_B0){
    // ---- proj via MFMA ----
    int bid = blockIdx.x - PROJ_B0;
    int row0 = bid * 64;
    int lane = t & 63, w = t >> 6;
    int lr = lane & 15, lg = lane >> 4;
    f32x4 acc[4][2];
    #pragma unroll
    for(int nt=0;nt<2;++nt){
      int col = w*32 + nt*16 + lr;
      float bv = proj_b[col];
      #pragma unroll
      for(int rt=0;rt<4;++rt)
        #pragma unroll
        for(int i=0;i<4;++i) acc[rt][nt][i]=bv;
    }
    #pragma unroll
    for(int ks=0; ks<4; ++ks){
      int kb = ks*32 + lg*8;
      s16x8 Bf[2];
      #pragma unroll
      for(int nt=0;nt<2;++nt){
        int col = w*32 + nt*16 + lr;
        #pragma unroll
        for(int i=0;i<8;++i) Bf[nt][i] = (short)f2b(proj_w[(kb+i)*DD + col]);
      }
      #pragma unroll
      for(int rt=0;rt<4;++rt){
        int row = row0 + rt*16 + lr;
        const f32x4* xp = (const f32x4*)(x + (size_t)row*FD + kb);
        f32x4 v0 = xp[0], v1 = xp[1];
        s16x8 Af;
        #pragma unroll
        for(int i=0;i<4;++i){ Af[i] = (short)f2b(v0[i]); Af[4+i] = (short)f2b(v1[i]); }
        #pragma unroll
        for(int nt=0;nt<2;++nt) acc[rt][nt] = MF(Af, Bf[nt], acc[rt][nt]);
      }
    }
    #pragma unroll
    for(int rt=0;rt<4;++rt)
      #pragma unroll
      for(int nt=0;nt<2;++nt)
        #pragma unroll
        for(int i=0;i<4;++i){
          int row = row0 + rt*16 + lg*4 + i;
          int col = w*32 + nt*16 + lr;
          featsb[(size_t)row*DD + col] = f2b(acc[rt][nt][i]);
        }
  } else if(blockIdx.x < HEUR_B0){
    // ---- prep: LDS-tile transpose to bf16 [out][k] (coalesced both sides) --
    int bid = blockIdx.x - PREP_B0;
    const float* s; unsigned short* d; int S, k0, n0;
    if(bid < 48){
      int m = bid >> 4, t16 = bid & 15;
      s = (m==0)? wq : (m==1)? wk : wv;
      d = (m==0)? wqT : (m==1)? wkT : wvT;
      S = 256; k0 = (t16>>2)*64; n0 = (t16&3)*64;
    } else {
      int b2 = bid - 48; int m = b2 >> 2, t4 = b2 & 3;
      if(m==0){ s = enc_w2 + 2*16384; d = w2T2; }
      else if(m==1){ s = enc_w2 + 3*16384; d = w2T3; }
      else if(m==2){ s = sw1 + 256*128; d = sw1aT; }
      else if(m==3){ s = sw1 + 384*128; d = sw1bT; }
      else { s = sw2; d = sw2T; }
      S = 128; k0 = (t4>>1)*64; n0 = (t4&1)*64;
    }
    __shared__ unsigned short tile[64][65];
    #pragma unroll
    for(int it=0; it<16; ++it){
      int idx = t + it*256;
      int i = idx>>6, j = idx&63;
      tile[i][j] = f2b(s[(size_t)(k0+i)*S + n0 + j]);
    }
    __syncthreads();
    #pragma unroll
    for(int it=0; it<16; ++it){
      int idx = t + it*256;
      int i2 = idx>>6, j2 = idx&63;
      d[(size_t)(n0+i2)*S + k0 + j2] = tile[j2][i2];
    }
  } else if(blockIdx.x < SBIAS_B){
    // ---- heur gathers ----
    int tt = (blockIdx.x - HEUR_B0)*256 + t;
    int s = tt >> 8;
    int node = node_idx[tt];
    heurA[tt] = ppr[(size_t)srcI[s]*NN + node];
    heurB[tt] = ppr[(size_t)dstI[s]*NN + node];
    heurD[tt] = drnl[(size_t)s*NN + node];
  } else if(blockIdx.x == SBIAS_B){
    // ---- sbias fold ----
    __shared__ float h0[DD], h1[DD], e0[DD], e1[DD];
    if(t < DD){
      h0[t] = relu_(enc_b1[0*DD+t]);
      h1[t] = relu_(enc_b1[1*DD+t]);
    }
    __syncthreads();
    if(t < DD){
      float a0 = enc_b2[0*DD+t], a1 = enc_b2[1*DD+t];
      for(int d2=0; d2<DD; ++d2){
        a0 += h0[d2]*enc_w2[(0*DD+d2)*DD + t];
        a1 += h1[d2]*enc_w2[(1*DD+d2)*DD + t];
      }
      e0[t]=a0; e1[t]=a1;
    }
    __syncthreads();
    if(t < DD){
      float sv = sb1[t];
      for(int d2=0; d2<DD; ++d2)
        sv += e0[d2]*sw1[d2*DD + t] + e1[d2]*sw1[(DD+d2)*DD + t];
      sbias[t]=sv;
    }
  } else {
    // ---- cls q/k/v (batch-independent, computed once) ----
    __shared__ float scls[DTD];
    scls[t] = cls_tok[t];
    __syncthreads();
    float aq=0.f, ak=0.f, av=0.f;
    for(int d2=0; d2<DTD; ++d2){
      float cv = scls[d2];
      aq += cv*wq[d2*DTD + t];
      ak += cv*wk[d2*DTD + t];
      av += cv*wv[d2*DTD + t];
    }
    qcls[t] = aq;
    kcls[t] = f2b(ak);
    vcls[t] = f2b(av);
  }
}

// ============ pull SpMM: one wave per row, unroll-4, bucketed CSR ==========
__global__ void __launch_bounds__(256)
k_spmm_w(const unsigned int* __restrict__ hin32, unsigned int* __restrict__ hout32,
         const int* __restrict__ cnt, const uint2* __restrict__ ccv,
         const unsigned int* __restrict__ featsb32, int finalpass){
  int lane = threadIdx.x & 63;
  int r = blockIdx.x*4 + (threadIdx.x>>6);
  int deg = cnt[r];
  const uint2* base = ccv + (size_t)r*CAP;
  float a0=0.f,a1=0.f,b0=0.f,b1=0.f,c0=0.f,c1=0.f,d0=0.f,d1=0.f;
  int p = 0;
  for(; p+4 <= deg; p += 4){
    uint2 q0 = base[p], q1 = base[p+1], q2 = base[p+2], q3 = base[p+3];
    unsigned u0 = hin32[(size_t)q0.x*64 + lane];
    unsigned u1 = hin32[(size_t)q1.x*64 + lane];
    unsigned u2 = hin32[(size_t)q2.x*64 + lane];
    unsigned u3 = hin32[(size_t)q3.x*64 + lane];
    float v0=__uint_as_float(q0.y), v1=__uint_as_float(q1.y);
    float v2=__uint_as_float(q2.y), v3=__uint_as_float(q3.y);
    a0 += v0*b2f((unsigned short)(u0&0xffffu)); a1 += v0*b2f((unsigned short)(u0>>16));
    b0 += v1*b2f((unsigned short)(u1&0xffffu)); b1 += v1*b2f((unsigned short)(u1>>16));
    c0 += v2*b2f((unsigned short)(u2&0xffffu)); c1 += v2*b2f((unsigned short)(u2>>16));
    d0 += v3*b2f((unsigned short)(u3&0xffffu)); d1 += v3*b2f((unsigned short)(u3>>16));
  }
  for(; p < deg; ++p){
    uint2 q0 = base[p];
    unsigned u0 = hin32[(size_t)q0.x*64 + lane];
    float v0 = __uint_as_float(q0.y);
    a0 += v0*b2f((unsigned short)(u0&0xffffu)); a1 += v0*b2f((unsigned short)(u0>>16));
  }
  a0 += b0 + c0 + d0;
  a1 += b1 + c1 + d1;
  if(finalpass){
    unsigned f = featsb32[(size_t)r*64 + lane];
    a0 = 0.5f*a0 + 0.5f*b2f((unsigned short)(f & 0xffffu));
    a1 = 0.5f*a1 + 0.5f*b2f((unsigned short)(f >> 16));
  }
  hout32[(size_t)r*64 + lane] = (unsigned)f2b(a0) | ((unsigned)f2b(a1) << 16);
}

// ====== fused token MLP + K/V GEMM + Q: 64 tokens/block, 8 WAVES ==========
__global__ void __launch_bounds__(512)
k_tok_kv(const int* __restrict__ node_idx,
         const float* __restrict__ heurA, const float* __restrict__ heurB,
         const float* __restrict__ heurD,
         const float* __restrict__ enc_w1, const float* __restrict__ enc_b1,
         const unsigned short* __restrict__ w2T2, const unsigned short* __restrict__ w2T3,
         const float* __restrict__ enc_b2,
         const unsigned short* __restrict__ sw1aT, const unsigned short* __restrict__ sw1bT,
         const float* __restrict__ sbias,
         const unsigned short* __restrict__ sw2T, const float* __restrict__ sb2,
         const unsigned short* __restrict__ rexb,
         const unsigned short* __restrict__ wkT, const unsigned short* __restrict__ wvT,
         const unsigned short* __restrict__ wqT,
         unsigned short* __restrict__ kbuf, unsigned short* __restrict__ vbuf,
         float* __restrict__ qbuf){
  __shared__ float sA[64], sB[64], sDV[64];
  __shared__ int sNode[64];
  __shared__ __align__(16) unsigned short hid[64*136];
  // union region: e2[64*136]+e3[64*136] | seq[64*272] | stage[64*272]
  __shared__ __align__(16) unsigned short uni[64*STG_ST];
  unsigned short* pe2 = uni;
  unsigned short* pe3 = uni + 64*136;
  unsigned short* seq = uni;
  unsigned short* stg = uni;

  int tid = threadIdx.x;
  int lane = tid & 63;
  int w = tid >> 6;               // 0..7
  int lr = lane & 15;
  int lg = lane >> 4;
  int t0 = blockIdx.x * 64;
  int bs = t0 >> 8;
  int p0 = t0 & 255;

  if(tid < 64){
    int tt = t0 + tid;
    sNode[tid] = node_idx[tt];
    sA[tid]  = heurA[tt];
    sB[tid]  = heurB[tt];
    sDV[tid] = heurD[tt];
  }
  __syncthreads();

  int colm = w*16 + lr;           // MLP col (N=128, 8 waves x 16)

  // GEMM1: enc2/enc3 (each wave: 16 cols)
  {
    f32x4 acc2[4], acc3[4];
    float b2v = enc_b2[2*DD + colm];
    float b3v = enc_b2[3*DD + colm];
    #pragma unroll
    for(int rt=0;rt<4;++rt)
      #pragma unroll
      for(int i=0;i<4;++i){ acc2[rt][i]=b2v; acc3[rt][i]=b3v; }
    #pragma unroll
    for(int ks=0; ks<4; ++ks){
      int kb = ks*32 + lg*8;
      float w20[8], w21[8], w3s[8], b2c[8], b3c[8];
      #pragma unroll
      for(int i=0;i<8;++i){
        int k = kb + i;
        w20[i] = enc_w1[4*DD + k];
        w21[i] = enc_w1[5*DD + k];
        w3s[i] = enc_w1[6*DD + k] + enc_w1[7*DD + k];
        b2c[i] = enc_b1[2*DD + k];
        b3c[i] = enc_b1[3*DD + k];
      }
      s16x8 B2 = *(const s16x8*)(w2T2 + colm*DD + kb);
      s16x8 B3 = *(const s16x8*)(w2T3 + colm*DD + kb);
      #pragma unroll
      for(int rt=0;rt<4;++rt){
        int row = rt*16 + lr;
        float a = sA[row], b = sB[row], dv = sDV[row];
        s16x8 A2, A3;
        #pragma unroll
        for(int i=0;i<8;++i){
          A2[i] = (short)f2b(relu_(a*w20[i] + b*w21[i] + b2c[i]));
          A3[i] = (short)f2b(relu_(dv*w3s[i] + b3c[i]));
        }
        acc2[rt] = MF(A2, B2, acc2[rt]);
        acc3[rt] = MF(A3, B3, acc3[rt]);
      }
    }
    #pragma unroll
    for(int rt=0;rt<4;++rt)
      #pragma unroll
      for(int i=0;i<4;++i){
        int row = rt*16 + lg*4 + i;
        pe2[row*136 + colm] = f2b(acc2[rt][i]);
        pe3[row*136 + colm] = f2b(acc3[rt][i]);
      }
  }
  __syncthreads();

  // GEMM2: hidden = relu(sbias + e2@SW1a + e3@SW1b)
  {
    f32x4 acc[4];
    float sv = sbias[colm];
    #pragma unroll
    for(int rt=0;rt<4;++rt)
      #pragma unroll
      for(int i=0;i<4;++i) acc[rt][i]=sv;
    #pragma unroll
    for(int ks=0; ks<4; ++ks){
      int kb = ks*32 + lg*8;
      s16x8 Ba = *(const s16x8*)(sw1aT + colm*DD + kb);
      s16x8 Bb = *(const s16x8*)(sw1bT + colm*DD + kb);
      #pragma unroll
      for(int rt=0;rt<4;++rt){
        s16x8 A2 = *(const s16x8*)&pe2[(rt*16+lr)*136 + kb];
        s16x8 A3 = *(const s16x8*)&pe3[(rt*16+lr)*136 + kb];
        acc[rt] = MF(A2, Ba, acc[rt]);
        acc[rt] = MF(A3, Bb, acc[rt]);
      }
    }
    __syncthreads();   // e2/e3 reads complete
    #pragma unroll
    for(int rt=0;rt<4;++rt)
      #pragma unroll
      for(int i=0;i<4;++i){
        int row = rt*16 + lg*4 + i;
        hid[row*136 + colm] = f2b(relu_(acc[rt][i]));
      }
  }
  __syncthreads();

  // GEMM3: struct_out -> seq[:,0:128] ; re_x gather -> seq[:,128:256]
  {
    f32x4 acc[4];
    float bv = sb2[colm];
    #pragma unroll
    for(int rt=0;rt<4;++rt)
      #pragma unroll
      for(int i=0;i<4;++i) acc[rt][i]=bv;
    #pragma unroll
    for(int ks=0; ks<4; ++ks){
      int kb = ks*32 + lg*8;
      s16x8 Bc = *(const s16x8*)(sw2T + colm*DD + kb);
      #pragma unroll
      for(int rt=0;rt<4;++rt){
        s16x8 A = *(const s16x8*)&hid[(rt*16+lr)*136 + kb];
        acc[rt] = MF(A, Bc, acc[rt]);
      }
    }
    #pragma unroll
    for(int rt=0;rt<4;++rt)
      #pragma unroll
      for(int i=0;i<4;++i){
        int row = rt*16 + lg*4 + i;
        seq[row*SEQ_ST + colm] = f2b(acc[rt][i]);
      }
    // re_x gather: 64 rows x 128 cols (u16); 512 thr x 16 u16
    int row = tid >> 3, c = (tid & 7)*16;
    int node = sNode[row];
    const unsigned short* rp = rexb + (size_t)node*DD + c;
    *(s16x8*)(seq + row*SEQ_ST + DD + c)     = *(const s16x8*)(rp);
    *(s16x8*)(seq + row*SEQ_ST + DD + c + 8) = *(const s16x8*)(rp + 8);
  }
  __syncthreads();

  // K,V GEMM from LDS seq (each wave: 32 cols)
  f32x4 accK[4][2], accV[4][2];
  {
    #pragma unroll
    for(int rt=0;rt<4;++rt)
      #pragma unroll
      for(int nt=0;nt<2;++nt)
        #pragma unroll
        for(int i=0;i<4;++i){ accK[rt][nt][i]=0.f; accV[rt][nt][i]=0.f; }
    int col0 = w * 32;
    #pragma unroll
    for(int ks=0; ks<8; ++ks){
      int kb = ks*32 + lg*8;
      s16x8 A[4], Bk[2], Bv[2];
      #pragma unroll
      for(int rt=0;rt<4;++rt)
        A[rt] = *(const s16x8*)&seq[(rt*16+lr)*SEQ_ST + kb];
      #pragma unroll
      for(int nt=0;nt<2;++nt){
        int col = col0 + nt*16 + lr;
        Bk[nt] = *(const s16x8*)(wkT + (size_t)col*DTD + kb);
        Bv[nt] = *(const s16x8*)(wvT + (size_t)col*DTD + kb);
      }
      #pragma unroll
      for(int rt=0;rt<4;++rt)
        #pragma unroll
        for(int nt=0;nt<2;++nt){
          accK[rt][nt] = MF(A[rt], Bk[nt], accK[rt][nt]);
          accV[rt][nt] = MF(A[rt], Bv[nt], accV[rt][nt]);
        }
    }
  }
  if(p0 == 0){
    // Q for src/dst rows: 512 threads = 2 rows x 256 cols
    int qi = tid >> 8, col = tid & 255;
    float acc = 0.f;
    for(int d=0; d<DTD; d+=8){
      s16x8 wv8 = *(const s16x8*)(wqT + (size_t)col*DTD + d);
      #pragma unroll
      for(int j=0;j<8;++j)
        acc += b2f(seq[qi*SEQ_ST + d + j]) * b2f((unsigned short)wv8[j]);
    }
    qbuf[(size_t)(bs*2+qi)*DTD + col] = acc;
  }
  __syncthreads();   // all seq reads done -> stage region reusable

  // stage K -> coalesced store
  {
    int col0 = w * 32;
    #pragma unroll
    for(int rt=0;rt<4;++rt)
      #pragma unroll
      for(int nt=0;nt<2;++nt)
        #pragma unroll
        for(int i=0;i<4;++i)
          stg[(rt*16 + lg*4 + i)*STG_ST + col0 + nt*16 + lr] = f2b(accK[rt][nt][i]);
  }
  __syncthreads();
  {
    int row = tid >> 3, c = (tid & 7)*32;
    #pragma unroll
    for(int j=0;j<4;++j)
      *(s16x8*)(kbuf + (size_t)(t0+row)*DTD + c + j*8) = *(const s16x8*)&stg[row*STG_ST + c + j*8];
  }
  __syncthreads();
  {
    int col0 = w * 32;
    #pragma unroll
    for(int rt=0;rt<4;++rt)
      #pragma unroll
      for(int nt=0;nt<2;++nt)
        #pragma unroll
        for(int i=0;i<4;++i)
          stg[(rt*16 + lg*4 + i)*STG_ST + col0 + nt*16 + lr] = f2b(accV[rt][nt][i]);
  }
  __syncthreads();
  {
    int row = tid >> 3, c = (tid & 7)*32;
    #pragma unroll
    for(int j=0;j<4;++j)
      *(s16x8*)(vbuf + (size_t)(t0+row)*DTD + c + j*8) = *(const s16x8*)&stg[row*STG_ST + c + j*8];
  }
}

// ============ attention: kk=0 is cls (from cls bufs), 1..256 tokens ========
__global__ void __launch_bounds__(256)
k_att2(const float* __restrict__ qcls, const float* __restrict__ qbuf,
       const unsigned short* __restrict__ kcls, const unsigned short* __restrict__ vcls,
       const unsigned short* __restrict__ kbuf, const unsigned short* __restrict__ vbuf,
       float* __restrict__ att_o){
  __shared__ float q_s[3][32];
  __shared__ float sc[3][257];
  __shared__ float ppv[8][3][32];
  int t = threadIdx.x;
  int b = blockIdx.x >> 3, h = blockIdx.x & 7;

  if(t < 96){
    int qi = t>>5, dd = t&31;
    q_s[qi][dd] = (qi==0) ? qcls[h*32 + dd]
                          : qbuf[(size_t)(b*2+qi-1)*DTD + h*32 + dd];
  }
  __syncthreads();
  const float scale = 0.17677669529663687f;  // 1/sqrt(32)
  for(int kk=t; kk<257; kk+=256){
    const unsigned short* kr = (kk==0) ? (kcls + h*32)
                                       : (kbuf + (size_t)(b*256+kk-1)*DTD + h*32);
    float kv[32];
    #pragma unroll
    for(int j=0;j<4;++j){
      s16x8 u = *(const s16x8*)(kr + j*8);
      #pragma unroll
      for(int m2=0;m2<8;++m2) kv[j*8+m2] = b2f((unsigned short)u[m2]);
    }
    float d0=0.f,d1=0.f,d2=0.f;
    #pragma unroll
    for(int dd=0;dd<32;++dd){
      d0 += q_s[0][dd]*kv[dd]; d1 += q_s[1][dd]*kv[dd]; d2 += q_s[2][dd]*kv[dd];
    }
    sc[0][kk]=d0*scale; sc[1][kk]=d1*scale; sc[2][kk]=d2*scale;
  }
  __syncthreads();
  { // softmax: wave w handles qi=w
    int wv = t>>6, lane = t&63;
    if(wv < 3){
      int qi = wv;
      float x0=sc[qi][lane], x1=sc[qi][lane+64], x2=sc[qi][lane+128], x3=sc[qi][lane+192];
      float x4 = (lane==0)? sc[qi][256] : -1e30f;
      float m = fmaxf(fmaxf(fmaxf(x0,x1),fmaxf(x2,x3)),x4);
      #pragma unroll
      for(int off=32; off>0; off>>=1) m = fmaxf(m, __shfl_xor(m, off));
      float e0=expf(x0-m), e1=expf(x1-m), e2v=expf(x2-m), e3v=expf(x3-m);
      float e4=(lane==0)? expf(x4-m) : 0.f;
      float s = e0+e1+e2v+e3v+e4;
      #pragma unroll
      for(int off=32; off>0; off>>=1) s += __shfl_xor(s, off);
      float inv = 1.0f/s;
      sc[qi][lane]=e0*inv; sc[qi][lane+64]=e1*inv;
      sc[qi][lane+128]=e2v*inv; sc[qi][lane+192]=e3v*inv;
      if(lane==0) sc[qi][256]=e4*inv;
    }
  }
  __syncthreads();
  { // PV: 8 kk-groups
    int dd = t & 31, g = t >> 5;
    float a0=0.f, a1=0.f, a2=0.f;
    for(int kk=g; kk<257; kk+=8){
      const unsigned short* vr = (kk==0) ? (vcls + h*32)
                                         : (vbuf + (size_t)(b*256+kk-1)*DTD + h*32);
      float v = b2f(vr[dd]);
      a0 += sc[0][kk]*v; a1 += sc[1][kk]*v; a2 += sc[2][kk]*v;
    }
    ppv[g][0][dd]=a0; ppv[g][1][dd]=a1; ppv[g][2][dd]=a2;
  }
  __syncthreads();
  if(t < 96){
    int qi = t>>5, dd = t&31;
    float s = 0.f;
    #pragma unroll
    for(int gg=0; gg<8; ++gg) s += ppv[gg][qi][dd];
    att_o[(size_t)(b*3+qi)*DTD + h*32 + dd] = s;
  }
}

// ============ output: att_o @ wo, permuted =================================
__global__ void k_out(const float* __restrict__ att_o, const float* __restrict__ wo,
                      float* __restrict__ out){
  __shared__ float srow[DTD];
  int t = threadIdx.x;
  int r = blockIdx.x;
  int b = r/3, qi = r - b*3;
  srow[t] = att_o[(size_t)r*DTD + t];
  __syncthreads();
  float acc = 0.f;
  for(int d=0; d<DTD; ++d) acc += srow[d]*wo[d*DTD + t];
  int off = (qi==1)? 0 : ((qi==2)? DTD : 2*DTD);
  out[(size_t)b*768 + off + t] = acc;
}

extern "C" void kernel_launch(void* const* d_in, const int* in_sizes, int n_in,
                              void* d_out, int out_size, void* d_ws, size_t ws_size,
                              hipStream_t stream){
  const float* x        = (const float*)d_in[0];
  const float* proj_w   = (const float*)d_in[1];
  const float* proj_b   = (const float*)d_in[2];
  const float* adj_vals = (const float*)d_in[3];
  const int*   adj_rows = (const int*)d_in[4];
  const int*   adj_cols = (const int*)d_in[5];
  const float* ppr      = (const float*)d_in[6];
  const float* drnl     = (const float*)d_in[7];
  const int*   srcI     = (const int*)d_in[8];
  const int*   dstI     = (const int*)d_in[9];
  const int*   node_idx   = (const int*)d_in[11];
  const float* enc_w1   = (const float*)d_in[12];
  const float* enc_b1   = (const float*)d_in[13];
  const float* enc_w2   = (const float*)d_in[14];
  const float* enc_b2   = (const float*)d_in[15];
  const float* sw1      = (const float*)d_in[16];
  const float* sb1      = (const float*)d_in[17];
  const float* sw2      = (const float*)d_in[18];
  const float* sb2      = (const float*)d_in[19];
  const float* cls_tok  = (const float*)d_in[20];
  const float* wq       = (const float*)d_in[21];
  const float* wk       = (const float*)d_in[22];
  const float* wv       = (const float*)d_in[23];
  const float* wo       = (const float*)d_in[24];
  float* out = (float*)d_out;

  char* p = (char*)d_ws;
  auto alloc = [&](size_t bytes)->void*{ void* r = (void*)p; p += (bytes + 63) & ~(size_t)63; return r; };
  unsigned short* featsb = (unsigned short*)alloc((size_t)NN*DD*2);
  unsigned short* h1b    = (unsigned short*)alloc((size_t)NN*DD*2);
  unsigned short* h2b    = (unsigned short*)alloc((size_t)NN*DD*2);
  unsigned short* rexb   = (unsigned short*)alloc((size_t)NN*DD*2);
  int*   cnt     = (int*)  alloc((size_t)NN*4);
  uint2* ccv     = (uint2*)alloc((size_t)NN*CAP*8);
  float* sbias   = (float*)alloc((size_t)DD*4);
  float* heurA   = (float*)alloc((size_t)NTOK*4);
  float* heurB   = (float*)alloc((size_t)NTOK*4);
  float* heurD   = (float*)alloc((size_t)NTOK*4);
  unsigned short* kbuf = (unsigned short*)alloc((size_t)NTOK*DTD*2);
  unsigned short* vbuf = (unsigned short*)alloc((size_t)NTOK*DTD*2);
  float* qbuf    = (float*)alloc((size_t)BB*2*DTD*4);
  float* qcls    = (float*)alloc((size_t)DTD*4);
  unsigned short* kcls = (unsigned short*)alloc((size_t)DTD*2);
  unsigned short* vcls = (unsigned short*)alloc((size_t)DTD*2);
  float* att_o   = (float*)alloc((size_t)BB*3*DTD*4);
  unsigned short* wqT   = (unsigned short*)alloc((size_t)DTD*DTD*2);
  unsigned short* wkT   = (unsigned short*)alloc((size_t)DTD*DTD*2);
  unsigned short* wvT   = (unsigned short*)alloc((size_t)DTD*DTD*2);
  unsigned short* w2T2  = (unsigned short*)alloc((size_t)DD*DD*2);
  unsigned short* w2T3  = (unsigned short*)alloc((size_t)DD*DD*2);
  unsigned short* sw1aT = (unsigned short*)alloc((size_t)DD*DD*2);
  unsigned short* sw1bT = (unsigned short*)alloc((size_t)DD*DD*2);
  unsigned short* sw2T  = (unsigned short*)alloc((size_t)DD*DD*2);

  hipMemsetAsync(cnt, 0, NN*sizeof(int), stream);

  k_setup  <<<SETUP_GRID, 256, 0, stream>>>(x, proj_w, proj_b, featsb,
                                            wq, wk, wv, enc_w2, sw1, sw2, cls_tok,
                                            wqT, wkT, wvT, w2T2, w2T3, sw1aT, sw1bT, sw2T,
                                            node_idx, srcI, dstI, ppr, drnl,
                                            heurA, heurB, heurD,
                                            adj_rows, adj_cols, adj_vals, cnt, ccv,
                                            enc_b1, enc_b2, sb1, sbias,
                                            qcls, kcls, vcls);
  k_spmm_w <<<NN/4,   256, 0, stream>>>((const unsigned*)featsb, (unsigned*)h1b, cnt, ccv, (const unsigned*)featsb, 0);
  k_spmm_w <<<NN/4,   256, 0, stream>>>((const unsigned*)h1b, (unsigned*)h2b, cnt, ccv, (const unsigned*)featsb, 0);
  k_spmm_w <<<NN/4,   256, 0, stream>>>((const unsigned*)h2b, (unsigned*)rexb, cnt, ccv, (const unsigned*)featsb, 1);
  k_tok_kv <<<NTOK/64,512, 0, stream>>>(node_idx, heurA, heurB, heurD,
                                        enc_w1, enc_b1, w2T2, w2T3, enc_b2,
                                        sw1aT, sw1bT, sbias, sw2T, sb2, rexb,
                                        wkT, wvT, wqT, kbuf, vbuf, qbuf);
  k_att2   <<<BB*HH,  256, 0, stream>>>(qcls, qbuf, kcls, vcls, kbuf, vbuf, att_o);
  k_out    <<<BB*3,   256, 0, stream>>>(att_o, wo, out);
}